// Round 1
// baseline (1249.682 us; speedup 1.0000x reference)
//
#include <hip/hip_runtime.h>
#include <hip/hip_bf16.h>

typedef __attribute__((ext_vector_type(8))) __bf16 bf16x8;
typedef __attribute__((ext_vector_type(4))) float f32x4;

#define TKN 2048
#define DMODEL 2048
#define NEXP 8
#define FEXP 1408
#define FSH 5632

__device__ __forceinline__ unsigned short f2bf(float f) {
  unsigned u = __float_as_uint(f);
  u += 0x7FFFu + ((u >> 16) & 1u);          // round-to-nearest-even
  return (unsigned short)(u >> 16);
}
__device__ __forceinline__ unsigned pk2(float a, float b) {
  return (unsigned)f2bf(a) | ((unsigned)f2bf(b) << 16);
}

enum { EPI_GATE = 0, EPI_UPMUL = 1, EPI_DOWN = 2, EPI_SDOWN = 3 };

// ---------------------------------------------------------------------------
// Router: logits (fp32, to d_out tail), softmax, top-4 (strict > => lowest
// index wins ties, matching jax.lax.top_k), sigmoid shared gate, and
// per-expert (token, weight) lists built with atomics.
// ---------------------------------------------------------------------------
__global__ __launch_bounds__(256)
void router_k(const float* __restrict__ x, const float* __restrict__ gw,
              const float* __restrict__ sgw, float* __restrict__ logits,
              float* __restrict__ sig, int* __restrict__ cnt,
              int* __restrict__ tokl, float* __restrict__ wls)
{
  const int wv = threadIdx.x >> 6, lane = threadIdx.x & 63;
  const int t = blockIdx.x * 4 + wv;
  const float* xr = x + (long)t * DMODEL;
  float xv[32];
#pragma unroll
  for (int j = 0; j < 32; j++) xv[j] = xr[lane + (j << 6)];

  float lg[8];
#pragma unroll
  for (int e = 0; e < 8; e++) {
    const float* gr = gw + (long)e * DMODEL;
    float acc = 0.f;
#pragma unroll
    for (int j = 0; j < 32; j++) acc += xv[j] * gr[lane + (j << 6)];
#pragma unroll
    for (int s = 1; s < 64; s <<= 1) acc += __shfl_xor(acc, s, 64);
    lg[e] = acc;
  }
  float sgacc = 0.f;
#pragma unroll
  for (int j = 0; j < 32; j++) sgacc += xv[j] * sgw[lane + (j << 6)];
#pragma unroll
  for (int s = 1; s < 64; s <<= 1) sgacc += __shfl_xor(sgacc, s, 64);

  if (lane == 0) {
    float mx = lg[0];
#pragma unroll
    for (int e = 1; e < 8; e++) mx = fmaxf(mx, lg[e]);
    float p[8], se = 0.f;
#pragma unroll
    for (int e = 0; e < 8; e++) { p[e] = expf(lg[e] - mx); se += p[e]; }
    float inv = 1.f / se;
#pragma unroll
    for (int e = 0; e < 8; e++) { p[e] *= inv; logits[t * 8 + e] = lg[e]; }
    sig[t] = 1.f / (1.f + expf(-sgacc));
#pragma unroll
    for (int k = 0; k < 4; k++) {
      int bi = 0; float bv = p[0];
#pragma unroll
      for (int e = 1; e < 8; e++) if (p[e] > bv) { bv = p[e]; bi = e; }
      p[bi] = -1.f;
      int pos = atomicAdd(&cnt[bi], 1);
      tokl[bi * TKN + pos] = t;
      wls[bi * TKN + pos] = bv;
    }
  }
}

__global__ void scan_k(const int* __restrict__ cnt, int* __restrict__ offs) {
  if (threadIdx.x == 0) {
    int s = 0;
    for (int e = 0; e < 8; e++) { offs[e] = s; s += cnt[e]; }
    offs[8] = s;
  }
}

// ---------------------------------------------------------------------------
// Tiled bf16-MFMA GEMM, 128x128 tile, BK=32, 4 waves (2x2), each wave 64x64.
// A,B are fp32 in HBM, converted to bf16 in registers during LDS staging.
// LDS fragment-packed: per (row|col, group g) 16B holding k={4g..4g+3, 16+4g..}
// with 2-bit XOR swizzle for bank spread.
// ---------------------------------------------------------------------------
template<int EPI, bool EXPERT>
__global__ __launch_bounds__(256)
void gemm_k(const float* __restrict__ A, int lda,
            const float* __restrict__ B, long sB, int ldb, int K,
            float* __restrict__ O, int ldo,
            const int* __restrict__ cnt, const int* __restrict__ offs,
            const int* __restrict__ tokl, const float* __restrict__ wls,
            const float* __restrict__ sig)
{
  const int tid = threadIdx.x;
  const int lane = tid & 63;

  int e = 0, rt = blockIdx.y, M = TKN;
  if (EXPERT) {
    e = blockIdx.y >> 4; rt = blockIdx.y & 15;
    M = cnt[e];
    if (rt * 128 >= M) return;
  }
  const int colblk = blockIdx.x * 128;
  const float* Bp = B + (long)e * sB;
  const int obase = EXPERT ? offs[e] : 0;

  __shared__ alignas(16) unsigned char Ab[8192];
  __shared__ alignas(16) unsigned char Bb[8192];
  __shared__ int s_tok[128];
  __shared__ float s_w[128];

  if (EXPERT && tid < 128) {
    int r = rt * 128 + tid;
    int rc = (r < M) ? r : (M - 1);
    s_tok[tid] = tokl[e * TKN + rc];
    if (EPI == EPI_DOWN) s_w[tid] = (r < M) ? wls[e * TKN + r] : 0.f;
  }
  if (EXPERT) __syncthreads();

  // ---- A staging setup: thread -> (row 0..127, half 0..1), 16 fp32 per iter
  const int arowl = tid >> 1;
  const int ahalf = tid & 1;
  long arow;
  if (EPI == EPI_DOWN) {
    int r = rt * 128 + arowl;
    arow = (long)obase + ((r < M) ? r : (M - 1));
  } else if (EXPERT) {
    arow = s_tok[arowl];                 // gathered token row of x
  } else {
    arow = rt * 128 + arowl;
  }
  const float* aptr = A + arow * (long)lda + ahalf * 16;
  int wa[4];
#pragma unroll
  for (int j = 0; j < 4; j++)
    wa[j] = arowl * 64 + ((j ^ ((arowl ^ (arowl >> 3)) & 3)) << 4) + ahalf * 8;

  // ---- B staging setup: thread -> (kg 0..7, ng 0..31), 4x4 transpose
  const int kg = tid >> 5, ng = tid & 31;
  const float* bptr = Bp + (long)(kg * 4) * ldb + colblk + ng * 4;
  int wb[4];
#pragma unroll
  for (int i = 0; i < 4; i++) {
    int c = ng * 4 + i;
    wb[i] = c * 64 + ((((kg & 3) ^ ((c ^ (c >> 3)) & 3))) << 4) + (kg >> 2) * 8;
  }

  // ---- fragment read offsets
  const int wid = tid >> 6, wm = wid >> 1, wn = wid & 1;
  const int g = lane >> 4, l15 = lane & 15;
  int ra[4], rb[4];
#pragma unroll
  for (int m = 0; m < 4; m++) {
    int r = wm * 64 + m * 16 + l15;
    ra[m] = r * 64 + ((g ^ ((r ^ (r >> 3)) & 3)) << 4);
  }
#pragma unroll
  for (int n = 0; n < 4; n++) {
    int c = wn * 64 + n * 16 + l15;
    rb[n] = c * 64 + ((g ^ ((c ^ (c >> 3)) & 3)) << 4);
  }

  f32x4 acc[4][4] = {};

  const int KT = K >> 5;
  for (int kt = 0; kt < KT; ++kt) {
    // stage A (16 fp32 -> 4x b64 bf16 writes)
    const float4* a4 = reinterpret_cast<const float4*>(aptr + kt * 32);
    float4 v0 = a4[0], v1 = a4[1], v2 = a4[2], v3 = a4[3];
    // stage B (4 rows x 4 cols fp32, in-register transpose)
    const float* b0 = bptr + (long)kt * 32 * ldb;
    float4 r0 = *reinterpret_cast<const float4*>(b0);
    float4 r1 = *reinterpret_cast<const float4*>(b0 + ldb);
    float4 r2 = *reinterpret_cast<const float4*>(b0 + 2 * ldb);
    float4 r3 = *reinterpret_cast<const float4*>(b0 + 3 * ldb);

    *reinterpret_cast<uint2*>(Ab + wa[0]) = make_uint2(pk2(v0.x, v0.y), pk2(v0.z, v0.w));
    *reinterpret_cast<uint2*>(Ab + wa[1]) = make_uint2(pk2(v1.x, v1.y), pk2(v1.z, v1.w));
    *reinterpret_cast<uint2*>(Ab + wa[2]) = make_uint2(pk2(v2.x, v2.y), pk2(v2.z, v2.w));
    *reinterpret_cast<uint2*>(Ab + wa[3]) = make_uint2(pk2(v3.x, v3.y), pk2(v3.z, v3.w));
    *reinterpret_cast<uint2*>(Bb + wb[0]) = make_uint2(pk2(r0.x, r1.x), pk2(r2.x, r3.x));
    *reinterpret_cast<uint2*>(Bb + wb[1]) = make_uint2(pk2(r0.y, r1.y), pk2(r2.y, r3.y));
    *reinterpret_cast<uint2*>(Bb + wb[2]) = make_uint2(pk2(r0.z, r1.z), pk2(r2.z, r3.z));
    *reinterpret_cast<uint2*>(Bb + wb[3]) = make_uint2(pk2(r0.w, r1.w), pk2(r2.w, r3.w));
    __syncthreads();

    bf16x8 av[4], bv[4];
#pragma unroll
    for (int m = 0; m < 4; m++) av[m] = *reinterpret_cast<const bf16x8*>(Ab + ra[m]);
#pragma unroll
    for (int n = 0; n < 4; n++) bv[n] = *reinterpret_cast<const bf16x8*>(Bb + rb[n]);
#pragma unroll
    for (int m = 0; m < 4; m++)
#pragma unroll
      for (int n = 0; n < 4; n++)
        acc[m][n] = __builtin_amdgcn_mfma_f32_16x16x32_bf16(av[m], bv[n], acc[m][n], 0, 0, 0);
    __syncthreads();
  }

  // ---- epilogue. C/D frag: col = lane&15, row = (lane>>4)*4 + reg  [m89]
#pragma unroll
  for (int m = 0; m < 4; m++) {
#pragma unroll
    for (int n = 0; n < 4; n++) {
      int col = colblk + wn * 64 + n * 16 + l15;
      f32x4 a = acc[m][n];
#pragma unroll
      for (int q = 0; q < 4; q++) {
        int rl = wm * 64 + m * 16 + (g << 2) + q;   // local row in tile
        int grow = rt * 128 + rl;
        float v = a[q];
        if (EPI == EPI_GATE) {
          if (!EXPERT || grow < M)
            O[(long)(obase + grow) * ldo + col] = v / (1.f + __expf(-v));
        } else if (EPI == EPI_UPMUL) {
          if (!EXPERT || grow < M)
            O[(long)(obase + grow) * ldo + col] *= v;
        } else if (EPI == EPI_DOWN) {
          if (grow < M)
            atomicAdd(&O[(long)s_tok[rl] * ldo + col], s_w[rl] * v);
        } else {  // EPI_SDOWN
          float* p = &O[(long)grow * ldo + col];
          *p += sig[grow] * v;
        }
      }
    }
  }
}

// ---------------------------------------------------------------------------
extern "C" void kernel_launch(void* const* d_in, const int* in_sizes, int n_in,
                              void* d_out, int out_size, void* d_ws, size_t ws_size,
                              hipStream_t stream)
{
  (void)in_sizes; (void)n_in; (void)out_size; (void)ws_size;
  const float* x   = (const float*)d_in[0];
  const float* gw  = (const float*)d_in[1];
  const float* Wg  = (const float*)d_in[2];
  const float* Wu  = (const float*)d_in[3];
  const float* Wd  = (const float*)d_in[4];
  const float* Wsg = (const float*)d_in[5];
  const float* Wsu = (const float*)d_in[6];
  const float* Wsd = (const float*)d_in[7];
  const float* sgw = (const float*)d_in[8];

  float* out    = (float*)d_out;
  float* logits = out + (long)TKN * DMODEL;

  char* w    = (char*)d_ws;
  int*  cnt  = (int*)w;                                   // 32 B
  int*  offs = (int*)(w + 64);                            // 36 B
  float* sig = (float*)(w + 256);                         // 8 KB
  int*  tokl = (int*)(w + 256 + 4 * TKN);                 // 64 KB
  float* wls = (float*)(w + 256 + 4 * TKN + 4 * NEXP * TKN);  // 64 KB
  float* h   = (float*)(w + (1 << 20));                   // 46.1 MB (8192*1408 == 2048*5632)

  hipMemsetAsync(out, 0, (size_t)TKN * DMODEL * 4, stream);
  hipMemsetAsync(cnt, 0, 64, stream);

  router_k<<<dim3(TKN / 4), 256, 0, stream>>>(x, gw, sgw, logits, sig, cnt, tokl, wls);
  scan_k<<<1, 64, 0, stream>>>(cnt, offs);

  // expert gate: h = silu(x_gathered @ Wg[e])
  gemm_k<EPI_GATE, true><<<dim3(FEXP / 128, 128), 256, 0, stream>>>(
      x, DMODEL, Wg, (long)DMODEL * FEXP, FEXP, DMODEL, h, FEXP, cnt, offs, tokl, wls, nullptr);
  // expert up: h *= (x_gathered @ Wu[e])
  gemm_k<EPI_UPMUL, true><<<dim3(FEXP / 128, 128), 256, 0, stream>>>(
      x, DMODEL, Wu, (long)DMODEL * FEXP, FEXP, DMODEL, h, FEXP, cnt, offs, tokl, wls, nullptr);
  // expert down: out[tok] += w * (h @ Wd[e])
  gemm_k<EPI_DOWN, true><<<dim3(DMODEL / 128, 128), 256, 0, stream>>>(
      h, FEXP, Wd, (long)FEXP * DMODEL, DMODEL, FEXP, out, DMODEL, cnt, offs, tokl, wls, nullptr);
  // shared gate: h = silu(x @ Wsg)
  gemm_k<EPI_GATE, false><<<dim3(FSH / 128, TKN / 128), 256, 0, stream>>>(
      x, DMODEL, Wsg, 0, FSH, DMODEL, h, FSH, nullptr, nullptr, nullptr, nullptr, nullptr);
  // shared up: h *= (x @ Wsu)
  gemm_k<EPI_UPMUL, false><<<dim3(FSH / 128, TKN / 128), 256, 0, stream>>>(
      x, DMODEL, Wsu, 0, FSH, DMODEL, h, FSH, nullptr, nullptr, nullptr, nullptr, nullptr);
  // shared down: out += sigmoid(x@sgw) * (h @ Wsd)
  gemm_k<EPI_SDOWN, false><<<dim3(DMODEL / 128, TKN / 128), 256, 0, stream>>>(
      h, FSH, Wsd, 0, DMODEL, FSH, out, DMODEL, nullptr, nullptr, nullptr, nullptr, sig);
}

// Round 2
// 958.058 us; speedup vs baseline: 1.3044x; 1.3044x over previous
//
#include <hip/hip_runtime.h>
#include <hip/hip_bf16.h>

typedef __attribute__((ext_vector_type(8))) __bf16 bf16x8;
typedef __attribute__((ext_vector_type(4))) float f32x4;

#define TKN 2048
#define DMODEL 2048
#define NEXP 8
#define FEXP 1408
#define FSH 5632

__device__ __forceinline__ unsigned short f2bf(float f) {
  unsigned u = __float_as_uint(f);
  u += 0x7FFFu + ((u >> 16) & 1u);          // round-to-nearest-even
  return (unsigned short)(u >> 16);
}
__device__ __forceinline__ unsigned pk2(float a, float b) {
  return (unsigned)f2bf(a) | ((unsigned)f2bf(b) << 16);
}

enum { EPI_GU = 0, EPI_DOWN = 1, EPI_SDOWN = 2 };

// raw barrier: no vmcnt drain (keeps prefetch loads in flight), but full
// lgkm drain (ds_write visibility before barrier / ds_read return before
// LDS reuse). sched_barrier fences stop MFMA/loads drifting across.
__device__ __forceinline__ void block_sync() {
  __builtin_amdgcn_sched_barrier(0);
  asm volatile("s_waitcnt lgkmcnt(0)" ::: "memory");
  __builtin_amdgcn_s_barrier();
  __builtin_amdgcn_sched_barrier(0);
}

// ---------------------------------------------------------------------------
// Router: logits (fp32, to d_out tail), softmax, top-4 (strict > => lowest
// index wins ties, matching jax.lax.top_k), sigmoid shared gate, and
// per-expert (token, weight) lists built with atomics.
// ---------------------------------------------------------------------------
__global__ __launch_bounds__(256)
void router_k(const float* __restrict__ x, const float* __restrict__ gw,
              const float* __restrict__ sgw, float* __restrict__ logits,
              float* __restrict__ sig, int* __restrict__ cnt,
              int* __restrict__ tokl, float* __restrict__ wls)
{
  const int wv = threadIdx.x >> 6, lane = threadIdx.x & 63;
  const int t = blockIdx.x * 4 + wv;
  const float* xr = x + (long)t * DMODEL;
  float xv[32];
#pragma unroll
  for (int j = 0; j < 32; j++) xv[j] = xr[lane + (j << 6)];

  float lg[8];
#pragma unroll
  for (int e = 0; e < 8; e++) {
    const float* gr = gw + (long)e * DMODEL;
    float acc = 0.f;
#pragma unroll
    for (int j = 0; j < 32; j++) acc += xv[j] * gr[lane + (j << 6)];
#pragma unroll
    for (int s = 1; s < 64; s <<= 1) acc += __shfl_xor(acc, s, 64);
    lg[e] = acc;
  }
  float sgacc = 0.f;
#pragma unroll
  for (int j = 0; j < 32; j++) sgacc += xv[j] * sgw[lane + (j << 6)];
#pragma unroll
  for (int s = 1; s < 64; s <<= 1) sgacc += __shfl_xor(sgacc, s, 64);

  if (lane == 0) {
    float mx = lg[0];
#pragma unroll
    for (int e = 1; e < 8; e++) mx = fmaxf(mx, lg[e]);
    float p[8], se = 0.f;
#pragma unroll
    for (int e = 0; e < 8; e++) { p[e] = expf(lg[e] - mx); se += p[e]; }
    float inv = 1.f / se;
#pragma unroll
    for (int e = 0; e < 8; e++) { p[e] *= inv; logits[t * 8 + e] = lg[e]; }
    sig[t] = 1.f / (1.f + expf(-sgacc));
#pragma unroll
    for (int k = 0; k < 4; k++) {
      int bi = 0; float bv = p[0];
#pragma unroll
      for (int e = 1; e < 8; e++) if (p[e] > bv) { bv = p[e]; bi = e; }
      p[bi] = -1.f;
      int pos = atomicAdd(&cnt[bi], 1);
      tokl[bi * TKN + pos] = t;
      wls[bi * TKN + pos] = bv;
    }
  }
}

__global__ void scan_k(const int* __restrict__ cnt, int* __restrict__ offs) {
  if (threadIdx.x == 0) {
    int s = 0;
    for (int e = 0; e < 8; e++) { offs[e] = s; s += cnt[e]; }
    offs[8] = s;
  }
}

// ---------------------------------------------------------------------------
// Tiled bf16-MFMA GEMM, 128x128 tile, BK=32, 4 waves (2x2), 64x64 per wave.
// FUSED (EPI_GU): two B matrices share one A staging; h = silu(g)*u.
// Register double-buffer prefetch: tile k+1 global loads issued before
// tile k's convert+ds_write; raw s_barrier keeps them in flight.
// KSPLIT: split-K via blockIdx.y; epilogue must be atomic.
// ---------------------------------------------------------------------------
template<int EPI, bool EXPERT, int KSPLIT>
__global__ __launch_bounds__(256, 2)
void gemm_k(const float* __restrict__ A, int lda,
            const float* __restrict__ B, const float* __restrict__ B2,
            long sB, int ldb, int Ktot,
            float* __restrict__ O, int ldo,
            const int* __restrict__ cnt, const int* __restrict__ offs,
            const int* __restrict__ tokl, const float* __restrict__ wls,
            const float* __restrict__ sig)
{
  constexpr bool FUSED = (EPI == EPI_GU);
  const int tid = threadIdx.x;
  const int lane = tid & 63;

  int e = 0, rt, kc = 0, M = TKN;
  if (EXPERT) {
    e = blockIdx.y >> 4; rt = blockIdx.y & 15;
    M = cnt[e];
    if (rt * 128 >= M) return;
  } else {
    rt = blockIdx.y & 15; kc = blockIdx.y >> 4;
  }
  const int K = Ktot / KSPLIT;
  const int koff = kc * K;
  const int colblk = blockIdx.x * 128;
  const float* Bp  = B + (EXPERT ? (long)e * sB : 0);
  const float* Bp2 = FUSED ? (B2 + (EXPERT ? (long)e * sB : 0)) : nullptr;
  const int obase = EXPERT ? offs[e] : 0;

  __shared__ alignas(16) unsigned char Ab[8192];
  __shared__ alignas(16) unsigned char Bb[8192];
  __shared__ alignas(16) unsigned char Bb2[FUSED ? 8192 : 16];
  __shared__ int s_tok[128];
  __shared__ float s_w[128];

  if (EXPERT && tid < 128) {
    int r = rt * 128 + tid;
    int rc = (r < M) ? r : (M - 1);
    s_tok[tid] = tokl[e * TKN + rc];
    if (EPI == EPI_DOWN) s_w[tid] = (r < M) ? wls[e * TKN + r] : 0.f;
  }
  if (EXPERT) __syncthreads();

  // ---- A staging setup: thread -> (row 0..127, half 0..1), 16 fp32 per iter
  const int arowl = tid >> 1;
  const int ahalf = tid & 1;
  long arow;
  if (EPI == EPI_DOWN) {
    int r = rt * 128 + arowl;
    arow = (long)obase + ((r < M) ? r : (M - 1));
  } else if (EXPERT) {
    arow = s_tok[arowl];                 // gathered token row of x
  } else {
    arow = rt * 128 + arowl;
  }
  const float* aptr = A + arow * (long)lda + koff + ahalf * 16;
  int wa[4];
#pragma unroll
  for (int j = 0; j < 4; j++)
    wa[j] = arowl * 64 + ((j ^ ((arowl ^ (arowl >> 3)) & 3)) << 4) + ahalf * 8;

  // ---- B staging setup: thread -> (kg 0..7, ng 0..31), 4x4 transpose
  const int kg = tid >> 5, ng = tid & 31;
  const float* bptr  = Bp + (long)(koff + kg * 4) * ldb + colblk + ng * 4;
  const float* bptr2 = FUSED ? (Bp2 + (long)(koff + kg * 4) * ldb + colblk + ng * 4) : nullptr;
  int wb[4];
#pragma unroll
  for (int i = 0; i < 4; i++) {
    int c = ng * 4 + i;
    wb[i] = c * 64 + ((((kg & 3) ^ ((c ^ (c >> 3)) & 3))) << 4) + (kg >> 2) * 8;
  }

  // ---- fragment read offsets
  const int wid = tid >> 6, wm = wid >> 1, wn = wid & 1;
  const int g = lane >> 4, l15 = lane & 15;
  int ra[4], rb[4];
#pragma unroll
  for (int m = 0; m < 4; m++) {
    int r = wm * 64 + m * 16 + l15;
    ra[m] = r * 64 + ((g ^ ((r ^ (r >> 3)) & 3)) << 4);
  }
#pragma unroll
  for (int n = 0; n < 4; n++) {
    int c = wn * 64 + n * 16 + l15;
    rb[n] = c * 64 + ((g ^ ((c ^ (c >> 3)) & 3)) << 4);
  }

  f32x4 acc[4][4] = {};
  f32x4 acc2[4][4] = {};   // only used when FUSED (else dead-code eliminated)

  const int KT = K >> 5;

  float4 ta0[4], tb0[4], tc0[4], ta1[4], tb1[4], tc1[4];

  auto load_tile = [&](float4* ra_, float4* rb_, float4* rc_, int kt) {
    const float4* a4 = reinterpret_cast<const float4*>(aptr + kt * 32);
    ra_[0] = a4[0]; ra_[1] = a4[1]; ra_[2] = a4[2]; ra_[3] = a4[3];
    const float* bb = bptr + (long)kt * 32 * ldb;
    rb_[0] = *reinterpret_cast<const float4*>(bb);
    rb_[1] = *reinterpret_cast<const float4*>(bb + ldb);
    rb_[2] = *reinterpret_cast<const float4*>(bb + 2 * ldb);
    rb_[3] = *reinterpret_cast<const float4*>(bb + 3 * ldb);
    if (FUSED) {
      const float* cc = bptr2 + (long)kt * 32 * ldb;
      rc_[0] = *reinterpret_cast<const float4*>(cc);
      rc_[1] = *reinterpret_cast<const float4*>(cc + ldb);
      rc_[2] = *reinterpret_cast<const float4*>(cc + 2 * ldb);
      rc_[3] = *reinterpret_cast<const float4*>(cc + 3 * ldb);
    }
  };

  auto store_tile = [&](const float4* ra_, const float4* rb_, const float4* rc_) {
#pragma unroll
    for (int j = 0; j < 4; j++)
      *reinterpret_cast<uint2*>(Ab + wa[j]) =
          make_uint2(pk2(ra_[j].x, ra_[j].y), pk2(ra_[j].z, ra_[j].w));
    *reinterpret_cast<uint2*>(Bb + wb[0]) = make_uint2(pk2(rb_[0].x, rb_[1].x), pk2(rb_[2].x, rb_[3].x));
    *reinterpret_cast<uint2*>(Bb + wb[1]) = make_uint2(pk2(rb_[0].y, rb_[1].y), pk2(rb_[2].y, rb_[3].y));
    *reinterpret_cast<uint2*>(Bb + wb[2]) = make_uint2(pk2(rb_[0].z, rb_[1].z), pk2(rb_[2].z, rb_[3].z));
    *reinterpret_cast<uint2*>(Bb + wb[3]) = make_uint2(pk2(rb_[0].w, rb_[1].w), pk2(rb_[2].w, rb_[3].w));
    if (FUSED) {
      *reinterpret_cast<uint2*>(Bb2 + wb[0]) = make_uint2(pk2(rc_[0].x, rc_[1].x), pk2(rc_[2].x, rc_[3].x));
      *reinterpret_cast<uint2*>(Bb2 + wb[1]) = make_uint2(pk2(rc_[0].y, rc_[1].y), pk2(rc_[2].y, rc_[3].y));
      *reinterpret_cast<uint2*>(Bb2 + wb[2]) = make_uint2(pk2(rc_[0].z, rc_[1].z), pk2(rc_[2].z, rc_[3].z));
      *reinterpret_cast<uint2*>(Bb2 + wb[3]) = make_uint2(pk2(rc_[0].w, rc_[1].w), pk2(rc_[2].w, rc_[3].w));
    }
  };

  auto mfma_step = [&]() {
    bf16x8 av[4], bvg[4], bvu[4];
#pragma unroll
    for (int m = 0; m < 4; m++) av[m] = *reinterpret_cast<const bf16x8*>(Ab + ra[m]);
#pragma unroll
    for (int n = 0; n < 4; n++) {
      bvg[n] = *reinterpret_cast<const bf16x8*>(Bb + rb[n]);
      if (FUSED) bvu[n] = *reinterpret_cast<const bf16x8*>(Bb2 + rb[n]);
    }
#pragma unroll
    for (int m = 0; m < 4; m++)
#pragma unroll
      for (int n = 0; n < 4; n++) {
        acc[m][n] = __builtin_amdgcn_mfma_f32_16x16x32_bf16(av[m], bvg[n], acc[m][n], 0, 0, 0);
        if (FUSED)
          acc2[m][n] = __builtin_amdgcn_mfma_f32_16x16x32_bf16(av[m], bvu[n], acc2[m][n], 0, 0, 0);
      }
  };

  load_tile(ta0, tb0, tc0, 0);
#pragma unroll 1
  for (int kt = 0; kt < KT; kt += 2) {
    load_tile(ta1, tb1, tc1, kt + 1);       // prefetch k+1 (in flight over MFMA)
    store_tile(ta0, tb0, tc0);              // counted vmcnt wait on tile k only
    block_sync();
    mfma_step();
    block_sync();
    int k2 = (kt + 2 < KT) ? kt + 2 : 0;    // harmless reload of tile 0 at end
    load_tile(ta0, tb0, tc0, k2);
    store_tile(ta1, tb1, tc1);
    block_sync();
    mfma_step();
    block_sync();
  }

  // ---- epilogue. C/D frag: col = lane&15, row = (lane>>4)*4 + reg  [m89]
#pragma unroll
  for (int m = 0; m < 4; m++) {
#pragma unroll
    for (int n = 0; n < 4; n++) {
      int col = colblk + wn * 64 + n * 16 + l15;
      f32x4 a = acc[m][n];
      f32x4 a2 = acc2[m][n];
#pragma unroll
      for (int q = 0; q < 4; q++) {
        int rl = wm * 64 + m * 16 + (g << 2) + q;   // local row in tile
        int grow = rt * 128 + rl;
        float v = a[q];
        if (EPI == EPI_GU) {
          if (!EXPERT || grow < M) {
            float hv = (v / (1.f + __expf(-v))) * a2[q];
            O[(long)(obase + grow) * ldo + col] = hv;
          }
        } else if (EPI == EPI_DOWN) {
          if (grow < M)
            atomicAdd(&O[(long)s_tok[rl] * ldo + col], s_w[rl] * v);
        } else {  // EPI_SDOWN
          atomicAdd(&O[(long)grow * ldo + col], sig[grow] * v);
        }
      }
    }
  }
}

// ---------------------------------------------------------------------------
extern "C" void kernel_launch(void* const* d_in, const int* in_sizes, int n_in,
                              void* d_out, int out_size, void* d_ws, size_t ws_size,
                              hipStream_t stream)
{
  (void)in_sizes; (void)n_in; (void)out_size; (void)ws_size;
  const float* x   = (const float*)d_in[0];
  const float* gw  = (const float*)d_in[1];
  const float* Wg  = (const float*)d_in[2];
  const float* Wu  = (const float*)d_in[3];
  const float* Wd  = (const float*)d_in[4];
  const float* Wsg = (const float*)d_in[5];
  const float* Wsu = (const float*)d_in[6];
  const float* Wsd = (const float*)d_in[7];
  const float* sgw = (const float*)d_in[8];

  float* out    = (float*)d_out;
  float* logits = out + (long)TKN * DMODEL;

  char* w    = (char*)d_ws;
  int*  cnt  = (int*)w;                                   // 32 B
  int*  offs = (int*)(w + 64);                            // 36 B
  float* sig = (float*)(w + 256);                         // 8 KB
  int*  tokl = (int*)(w + 256 + 4 * TKN);                 // 64 KB
  float* wls = (float*)(w + 256 + 4 * TKN + 4 * NEXP * TKN);  // 64 KB
  float* h   = (float*)(w + (1 << 20));                   // 46.1 MB (8192*1408 == 2048*5632)

  hipMemsetAsync(out, 0, (size_t)TKN * DMODEL * 4, stream);
  hipMemsetAsync(cnt, 0, 64, stream);

  router_k<<<dim3(TKN / 4), 256, 0, stream>>>(x, gw, sgw, logits, sig, cnt, tokl, wls);
  scan_k<<<1, 64, 0, stream>>>(cnt, offs);

  // expert fused gate+up: h = silu(x_g @ Wg[e]) * (x_g @ Wu[e])
  gemm_k<EPI_GU, true, 1><<<dim3(FEXP / 128, 128), 256, 0, stream>>>(
      x, DMODEL, Wg, Wu, (long)DMODEL * FEXP, FEXP, DMODEL, h, FEXP, cnt, offs, tokl, wls, nullptr);
  // expert down: out[tok] += w * (h @ Wd[e])
  gemm_k<EPI_DOWN, true, 1><<<dim3(DMODEL / 128, 128), 256, 0, stream>>>(
      h, FEXP, Wd, nullptr, (long)FEXP * DMODEL, DMODEL, FEXP, out, DMODEL, cnt, offs, tokl, wls, nullptr);
  // shared fused gate+up: h = silu(x @ Wsg) * (x @ Wsu)
  gemm_k<EPI_GU, false, 1><<<dim3(FSH / 128, TKN / 128), 256, 0, stream>>>(
      x, DMODEL, Wsg, Wsu, 0, FSH, DMODEL, h, FSH, nullptr, nullptr, nullptr, nullptr, nullptr);
  // shared down, split-K=4: out += sigmoid(x@sgw) * (h @ Wsd)
  gemm_k<EPI_SDOWN, false, 4><<<dim3(DMODEL / 128, (TKN / 128) * 4), 256, 0, stream>>>(
      h, FSH, Wsd, nullptr, 0, DMODEL, FSH, out, DMODEL, nullptr, nullptr, nullptr, nullptr, sig);
}

// Round 3
// 766.699 us; speedup vs baseline: 1.6300x; 1.2496x over previous
//
#include <hip/hip_runtime.h>
#include <hip/hip_bf16.h>

typedef __attribute__((ext_vector_type(8))) __bf16 bf16x8;
typedef __attribute__((ext_vector_type(4))) float f32x4;

#define TKN 2048
#define DMODEL 2048
#define NEXP 8
#define FEXP 1408
#define FSH 5632

__device__ __forceinline__ unsigned short f2bf(float f) {
  unsigned u = __float_as_uint(f);
  u += 0x7FFFu + ((u >> 16) & 1u);          // round-to-nearest-even
  return (unsigned short)(u >> 16);
}
__device__ __forceinline__ unsigned pk2(float a, float b) {
  return (unsigned)f2bf(a) | ((unsigned)f2bf(b) << 16);
}

// global -> LDS direct copy, 16B per lane. LDS dest must be wave-uniform.
__device__ __forceinline__ void gll16(const void* g, void* l) {
  __builtin_amdgcn_global_load_lds(
      (const __attribute__((address_space(1))) unsigned*)g,
      (__attribute__((address_space(3))) unsigned*)l, 16, 0, 0);
}

enum { EPI_GU = 0, EPI_DOWN = 1, EPI_SDOWN = 2 };

// ---------------------------------------------------------------------------
// Router (fp32-exact logits path) + top-4 + per-expert token lists.
// ---------------------------------------------------------------------------
__global__ __launch_bounds__(256)
void router_k(const float* __restrict__ x, const float* __restrict__ gw,
              const float* __restrict__ sgw, float* __restrict__ logits,
              float* __restrict__ sig, int* __restrict__ cnt,
              int* __restrict__ tokl, float* __restrict__ wls)
{
  const int wv = threadIdx.x >> 6, lane = threadIdx.x & 63;
  const int t = blockIdx.x * 4 + wv;
  const float* xr = x + (long)t * DMODEL;
  float xv[32];
#pragma unroll
  for (int j = 0; j < 32; j++) xv[j] = xr[lane + (j << 6)];

  float lg[8];
#pragma unroll
  for (int e = 0; e < 8; e++) {
    const float* gr = gw + (long)e * DMODEL;
    float acc = 0.f;
#pragma unroll
    for (int j = 0; j < 32; j++) acc += xv[j] * gr[lane + (j << 6)];
#pragma unroll
    for (int s = 1; s < 64; s <<= 1) acc += __shfl_xor(acc, s, 64);
    lg[e] = acc;
  }
  float sgacc = 0.f;
#pragma unroll
  for (int j = 0; j < 32; j++) sgacc += xv[j] * sgw[lane + (j << 6)];
#pragma unroll
  for (int s = 1; s < 64; s <<= 1) sgacc += __shfl_xor(sgacc, s, 64);

  if (lane == 0) {
    float mx = lg[0];
#pragma unroll
    for (int e = 1; e < 8; e++) mx = fmaxf(mx, lg[e]);
    float p[8], se = 0.f;
#pragma unroll
    for (int e = 0; e < 8; e++) { p[e] = expf(lg[e] - mx); se += p[e]; }
    float inv = 1.f / se;
#pragma unroll
    for (int e = 0; e < 8; e++) { p[e] *= inv; logits[t * 8 + e] = lg[e]; }
    sig[t] = 1.f / (1.f + expf(-sgacc));
#pragma unroll
    for (int k = 0; k < 4; k++) {
      int bi = 0; float bv = p[0];
#pragma unroll
      for (int e = 1; e < 8; e++) if (p[e] > bv) { bv = p[e]; bi = e; }
      p[bi] = -1.f;
      int pos = atomicAdd(&cnt[bi], 1);
      tokl[bi * TKN + pos] = t;
      wls[bi * TKN + pos] = bv;
    }
  }
}

__global__ void scan_k(const int* __restrict__ cnt, int* __restrict__ offs) {
  if (threadIdx.x == 0) {
    int s = 0;
    for (int e = 0; e < 8; e++) { offs[e] = s; s += cnt[e]; }
    offs[8] = s;
  }
}

// ---------------------------------------------------------------------------
// x fp32 [2048][2048] -> fragment-packed bf16 rows: per row, unit u=kt*4+j
// (16B) holds k = {kt*32+j*4+0..3, kt*32+16+j*4+0..3}. Row stride 4096 B.
// ---------------------------------------------------------------------------
__global__ __launch_bounds__(256)
void cvt_x_k(const float* __restrict__ x, char* __restrict__ xbf)
{
  long id = (long)blockIdx.x * 256 + threadIdx.x;   // 524288 total
  int row = id >> 8, u = id & 255, kt = u >> 2, j = u & 3;
  const float* p = x + (long)row * 2048 + kt * 32 + j * 4;
  float4 a = *(const float4*)p;
  float4 b = *(const float4*)(p + 16);
  uint4 o;
  o.x = pk2(a.x, a.y); o.y = pk2(a.z, a.w);
  o.z = pk2(b.x, b.y); o.w = pk2(b.z, b.w);
  *(uint4*)(xbf + id * 16) = o;
}

// ---------------------------------------------------------------------------
// Weight fp32 [K][N] -> bf16 panel of 8KB tiles, tile (ct,kt) contiguous at
// ((ct*KT)+kt)*8192. Within tile: unit u = c*4+g holds B[kt*32+g*4+{0..3}][c]
// then B[kt*32+16+g*4+{0..3}][c]. Matches LDS-linear gload_lds + frag reads.
// ---------------------------------------------------------------------------
__global__ __launch_bounds__(256)
void cvt_w_k(const float* __restrict__ W, long sB, int N,
             char* __restrict__ panel, long panStride)
{
  const int ct = blockIdx.x, kt = blockIdx.y, e = blockIdx.z, KT = gridDim.y;
  const float* Wp = W + (long)e * sB + (long)(kt * 32) * N + ct * 128;
  __shared__ float t[32][128];
  const int r = threadIdx.x >> 3, q = threadIdx.x & 7;
  const float* rp = Wp + (long)r * N + q * 16;
  float4 f0 = *(const float4*)(rp + 0);
  float4 f1 = *(const float4*)(rp + 4);
  float4 f2 = *(const float4*)(rp + 8);
  float4 f3 = *(const float4*)(rp + 12);
  *(float4*)&t[r][q * 16 + 0]  = f0;
  *(float4*)&t[r][q * 16 + 4]  = f1;
  *(float4*)&t[r][q * 16 + 8]  = f2;
  *(float4*)&t[r][q * 16 + 12] = f3;
  __syncthreads();
  char* outp = panel + e * panStride + ((long)ct * KT + kt) * 8192;
#pragma unroll
  for (int uu = 0; uu < 2; uu++) {
    int u = threadIdx.x + uu * 256;
    int c = u >> 2, g = u & 3;
    uint4 o;
    o.x = pk2(t[g * 4 + 0][c], t[g * 4 + 1][c]);
    o.y = pk2(t[g * 4 + 2][c], t[g * 4 + 3][c]);
    o.z = pk2(t[16 + g * 4 + 0][c], t[16 + g * 4 + 1][c]);
    o.w = pk2(t[16 + g * 4 + 2][c], t[16 + g * 4 + 3][c]);
    *(uint4*)(outp + u * 16) = o;
  }
}

// ---------------------------------------------------------------------------
// bf16 MFMA GEMM, 128x128 tile, BK=32, 4 waves, double-buffered LDS with
// global_load_lds staging (2-phase T3-min loop). A: fragment-packed bf16 rows
// (per-lane row gather OK). B: pre-tiled 8KB panels. FUSED: B and B2 share A.
// ---------------------------------------------------------------------------
template<int EPI, bool EXPERT, int KSPLIT>
__global__ __launch_bounds__(256, 2)
void gemm2_k(const char* __restrict__ Abf, long strA,
             const char* __restrict__ Bp, const char* __restrict__ Bp2,
             long sBpan, int KTtot,
             void* __restrict__ O, int ldKo,
             const int* __restrict__ cnt, const int* __restrict__ offs,
             const int* __restrict__ tokl, const float* __restrict__ wls,
             const float* __restrict__ sig)
{
  constexpr bool FUSED = (EPI == EPI_GU);
  const int tid = threadIdx.x, lane = tid & 63, w = tid >> 6;

  int e = 0, rt, kc = 0, M = TKN;
  if (EXPERT) {
    e = blockIdx.y >> 4; rt = blockIdx.y & 15;
    M = cnt[e];
    if (rt * 128 >= M) return;
  } else {
    rt = blockIdx.y & 15; kc = blockIdx.y >> 4;
  }
  const int KT = KTtot / KSPLIT;
  const int kt0 = kc * KT;
  const int ct = blockIdx.x;
  const int obase = EXPERT ? offs[e] : 0;

  __shared__ int s_tok[128];
  __shared__ float s_w[128];
  __shared__ alignas(16) char Ab[2][8192];
  __shared__ alignas(16) char Bb[2][8192];
  __shared__ alignas(16) char Bb2[FUSED ? 2 : 1][FUSED ? 8192 : 16];

  if (EXPERT) {
    if (tid < 128) {
      int r = rt * 128 + tid;
      int rc = (r < M) ? r : (M - 1);
      s_tok[tid] = tokl[e * TKN + rc];
      if (EPI == EPI_DOWN) s_w[tid] = (r < M) ? wls[e * TKN + r] : 0.f;
    }
    __syncthreads();
  }

  // ---- staging addresses. A: wave w, issue i covers rows w*32+i*16+(lane>>2)
  const int lrow0 = w * 32 + (lane >> 2);
  const int lrow1 = lrow0 + 16;
  auto rowbyte = [&](int rl) -> long {
    long gr;
    if (EPI == EPI_DOWN) { int r = rt * 128 + rl; gr = obase + ((r < M) ? r : (M - 1)); }
    else if (EXPERT)     { gr = s_tok[rl]; }
    else                 { gr = rt * 128 + rl; }
    return gr * strA;
  };
  const char* gA0 = Abf + rowbyte(lrow0) + (long)kt0 * 64 + (lane & 3) * 16;
  const char* gA1 = Abf + rowbyte(lrow1) + (long)kt0 * 64 + (lane & 3) * 16;
  const long bbase = (EXPERT ? (long)e * sBpan : 0) + ((long)ct * KTtot + kt0) * 8192
                     + w * 2048 + (long)lane * 16;
  const char* gB  = Bp + bbase;
  const char* gB2 = FUSED ? (Bp2 + bbase) : nullptr;

  auto stage = [&](int bf, int kt) {
    long ao = (long)kt * 64, bo = (long)kt * 8192;
    gll16(gA0 + ao, &Ab[bf][w * 2048]);
    gll16(gA1 + ao, &Ab[bf][w * 2048 + 1024]);
    gll16(gB + bo, &Bb[bf][w * 2048]);
    gll16(gB + bo + 1024, &Bb[bf][w * 2048 + 1024]);
    if constexpr (FUSED) {
      gll16(gB2 + bo, &Bb2[bf][w * 2048]);
      gll16(gB2 + bo + 1024, &Bb2[bf][w * 2048 + 1024]);
    }
  };

  // ---- fragment read offsets (linear fragment-packed layout)
  const int wm = w >> 1, wn = w & 1, g = lane >> 4, l15 = lane & 15;
  int raOff[4], rbOff[4];
#pragma unroll
  for (int m = 0; m < 4; m++) raOff[m] = (wm * 64 + m * 16 + l15) * 64 + g * 16;
#pragma unroll
  for (int n = 0; n < 4; n++) rbOff[n] = (wn * 64 + n * 16 + l15) * 64 + g * 16;

  f32x4 acc[4][4] = {};
  f32x4 acc2[4][4] = {};

  stage(0, 0);
  asm volatile("s_waitcnt vmcnt(0)" ::: "memory");
  __builtin_amdgcn_s_barrier();
  __builtin_amdgcn_sched_barrier(0);

  int bf = 0;
#pragma unroll 1
  for (int kt = 0; kt < KT; ++kt) {
    if (kt + 1 < KT) stage(bf ^ 1, kt + 1);   // loads in flight across MFMA
    bf16x8 av[4], bg[4], bu[4];
#pragma unroll
    for (int m = 0; m < 4; m++) av[m] = *(const bf16x8*)&Ab[bf][raOff[m]];
#pragma unroll
    for (int n = 0; n < 4; n++) {
      bg[n] = *(const bf16x8*)&Bb[bf][rbOff[n]];
      if constexpr (FUSED) bu[n] = *(const bf16x8*)&Bb2[bf][rbOff[n]];
    }
    __builtin_amdgcn_s_setprio(1);
#pragma unroll
    for (int m = 0; m < 4; m++)
#pragma unroll
      for (int n = 0; n < 4; n++) {
        acc[m][n] = __builtin_amdgcn_mfma_f32_16x16x32_bf16(av[m], bg[n], acc[m][n], 0, 0, 0);
        if constexpr (FUSED)
          acc2[m][n] = __builtin_amdgcn_mfma_f32_16x16x32_bf16(av[m], bu[n], acc2[m][n], 0, 0, 0);
      }
    __builtin_amdgcn_s_setprio(0);
    __builtin_amdgcn_sched_barrier(0);
    asm volatile("s_waitcnt vmcnt(0)" ::: "memory");
    __builtin_amdgcn_s_barrier();
    __builtin_amdgcn_sched_barrier(0);
    bf ^= 1;
  }

  // ---- epilogue. C/D frag: col = lane&15, row = (lane>>4)*4 + reg  [m89]
#pragma unroll
  for (int m = 0; m < 4; m++) {
#pragma unroll
    for (int n = 0; n < 4; n++) {
      int col = ct * 128 + wn * 64 + n * 16 + l15;
      f32x4 a = acc[m][n];
      f32x4 a2 = acc2[m][n];
#pragma unroll
      for (int q = 0; q < 4; q++) {
        int rl = wm * 64 + m * 16 + (g << 2) + q;
        int grow = rt * 128 + rl;
        float v = a[q];
        if constexpr (EPI == EPI_GU) {
          if (!EXPERT || grow < M) {
            float hv = (v / (1.f + __expf(-v))) * a2[q];
            long byteoff = (long)(obase + grow) * ((long)ldKo * 64)
                         + (col >> 5) * 64 + ((col >> 2) & 3) * 16
                         + ((col & 16) >> 1) + (col & 3) * 2;
            *(unsigned short*)((char*)O + byteoff) = f2bf(hv);
          }
        } else if constexpr (EPI == EPI_DOWN) {
          if (grow < M)
            atomicAdd((float*)O + (long)s_tok[rl] * DMODEL + col, s_w[rl] * v);
        } else {
          atomicAdd((float*)O + (long)grow * DMODEL + col, sig[grow] * v);
        }
      }
    }
  }
}

// ---------------------------------------------------------------------------
// FALLBACK (ws too small): R1 reg-staged GEMM, fp32 sources.
// ---------------------------------------------------------------------------
__device__ __forceinline__ void block_sync_fb() {
  __builtin_amdgcn_sched_barrier(0);
  asm volatile("s_waitcnt lgkmcnt(0)" ::: "memory");
  __builtin_amdgcn_s_barrier();
  __builtin_amdgcn_sched_barrier(0);
}

template<int EPI, bool EXPERT, int KSPLIT>
__global__ __launch_bounds__(256, 2)
void gemm_fb_k(const float* __restrict__ A, int lda,
               const float* __restrict__ B, const float* __restrict__ B2,
               long sB, int ldb, int Ktot,
               float* __restrict__ O, int ldo,
               const int* __restrict__ cnt, const int* __restrict__ offs,
               const int* __restrict__ tokl, const float* __restrict__ wls,
               const float* __restrict__ sig)
{
  constexpr bool FUSED = (EPI == EPI_GU);
  const int tid = threadIdx.x;
  const int lane = tid & 63;

  int e = 0, rt, kc = 0, M = TKN;
  if (EXPERT) {
    e = blockIdx.y >> 4; rt = blockIdx.y & 15;
    M = cnt[e];
    if (rt * 128 >= M) return;
  } else {
    rt = blockIdx.y & 15; kc = blockIdx.y >> 4;
  }
  const int K = Ktot / KSPLIT;
  const int koff = kc * K;
  const int colblk = blockIdx.x * 128;
  const float* Bp  = B + (EXPERT ? (long)e * sB : 0);
  const float* Bp2 = FUSED ? (B2 + (EXPERT ? (long)e * sB : 0)) : nullptr;
  const int obase = EXPERT ? offs[e] : 0;

  __shared__ alignas(16) unsigned char Ab[8192];
  __shared__ alignas(16) unsigned char Bb[8192];
  __shared__ alignas(16) unsigned char Bb2[FUSED ? 8192 : 16];
  __shared__ int s_tok[128];
  __shared__ float s_w[128];

  if (EXPERT && tid < 128) {
    int r = rt * 128 + tid;
    int rc = (r < M) ? r : (M - 1);
    s_tok[tid] = tokl[e * TKN + rc];
    if (EPI == EPI_DOWN) s_w[tid] = (r < M) ? wls[e * TKN + r] : 0.f;
  }
  if (EXPERT) __syncthreads();

  const int arowl = tid >> 1;
  const int ahalf = tid & 1;
  long arow;
  if (EPI == EPI_DOWN) {
    int r = rt * 128 + arowl;
    arow = (long)obase + ((r < M) ? r : (M - 1));
  } else if (EXPERT) {
    arow = s_tok[arowl];
  } else {
    arow = rt * 128 + arowl;
  }
  const float* aptr = A + arow * (long)lda + koff + ahalf * 16;
  int wa[4];
#pragma unroll
  for (int j = 0; j < 4; j++)
    wa[j] = arowl * 64 + ((j ^ ((arowl ^ (arowl >> 3)) & 3)) << 4) + ahalf * 8;

  const int kg = tid >> 5, ng = tid & 31;
  const float* bptr  = Bp + (long)(koff + kg * 4) * ldb + colblk + ng * 4;
  const float* bptr2 = FUSED ? (Bp2 + (long)(koff + kg * 4) * ldb + colblk + ng * 4) : nullptr;
  int wb[4];
#pragma unroll
  for (int i = 0; i < 4; i++) {
    int c = ng * 4 + i;
    wb[i] = c * 64 + ((((kg & 3) ^ ((c ^ (c >> 3)) & 3))) << 4) + (kg >> 2) * 8;
  }

  const int wid = tid >> 6, wm = wid >> 1, wn = wid & 1;
  const int g = lane >> 4, l15 = lane & 15;
  int ra[4], rb[4];
#pragma unroll
  for (int m = 0; m < 4; m++) {
    int r = wm * 64 + m * 16 + l15;
    ra[m] = r * 64 + ((g ^ ((r ^ (r >> 3)) & 3)) << 4);
  }
#pragma unroll
  for (int n = 0; n < 4; n++) {
    int c = wn * 64 + n * 16 + l15;
    rb[n] = c * 64 + ((g ^ ((c ^ (c >> 3)) & 3)) << 4);
  }

  f32x4 acc[4][4] = {};
  f32x4 acc2[4][4] = {};

  const int KT = K >> 5;
  float4 ta0[4], tb0[4], tc0[4], ta1[4], tb1[4], tc1[4];

  auto load_tile = [&](float4* ra_, float4* rb_, float4* rc_, int kt) {
    const float4* a4 = reinterpret_cast<const float4*>(aptr + kt * 32);
    ra_[0] = a4[0]; ra_[1] = a4[1]; ra_[2] = a4[2]; ra_[3] = a4[3];
    const float* bb = bptr + (long)kt * 32 * ldb;
    rb_[0] = *reinterpret_cast<const float4*>(bb);
    rb_[1] = *reinterpret_cast<const float4*>(bb + ldb);
    rb_[2] = *reinterpret_cast<const float4*>(bb + 2 * ldb);
    rb_[3] = *reinterpret_cast<const float4*>(bb + 3 * ldb);
    if (FUSED) {
      const float* cc = bptr2 + (long)kt * 32 * ldb;
      rc_[0] = *reinterpret_cast<const float4*>(cc);
      rc_[1] = *reinterpret_cast<const float4*>(cc + ldb);
      rc_[2] = *reinterpret_cast<const float4*>(cc + 2 * ldb);
      rc_[3] = *reinterpret_cast<const float4*>(cc + 3 * ldb);
    }
  };

  auto store_tile = [&](const float4* ra_, const float4* rb_, const float4* rc_) {
#pragma unroll
    for (int j = 0; j < 4; j++)
      *reinterpret_cast<uint2*>(Ab + wa[j]) =
          make_uint2(pk2(ra_[j].x, ra_[j].y), pk2(ra_[j].z, ra_[j].w));
    *reinterpret_cast<uint2*>(Bb + wb[0]) = make_uint2(pk2(rb_[0].x, rb_[1].x), pk2(rb_[2].x, rb_[3].x));
    *reinterpret_cast<uint2*>(Bb + wb[1]) = make_uint2(pk2(rb_[0].y, rb_[1].y), pk2(rb_[2].y, rb_[3].y));
    *reinterpret_cast<uint2*>(Bb + wb[2]) = make_uint2(pk2(rb_[0].z, rb_[1].z), pk2(rb_[2].z, rb_[3].z));
    *reinterpret_cast<uint2*>(Bb + wb[3]) = make_uint2(pk2(rb_[0].w, rb_[1].w), pk2(rb_[2].w, rb_[3].w));
    if (FUSED) {
      *reinterpret_cast<uint2*>(Bb2 + wb[0]) = make_uint2(pk2(rc_[0].x, rc_[1].x), pk2(rc_[2].x, rc_[3].x));
      *reinterpret_cast<uint2*>(Bb2 + wb[1]) = make_uint2(pk2(rc_[0].y, rc_[1].y), pk2(rc_[2].y, rc_[3].y));
      *reinterpret_cast<uint2*>(Bb2 + wb[2]) = make_uint2(pk2(rc_[0].z, rc_[1].z), pk2(rc_[2].z, rc_[3].z));
      *reinterpret_cast<uint2*>(Bb2 + wb[3]) = make_uint2(pk2(rc_[0].w, rc_[1].w), pk2(rc_[2].w, rc_[3].w));
    }
  };

  auto mfma_step = [&]() {
    bf16x8 av[4], bvg[4], bvu[4];
#pragma unroll
    for (int m = 0; m < 4; m++) av[m] = *reinterpret_cast<const bf16x8*>(Ab + ra[m]);
#pragma unroll
    for (int n = 0; n < 4; n++) {
      bvg[n] = *reinterpret_cast<const bf16x8*>(Bb + rb[n]);
      if (FUSED) bvu[n] = *reinterpret_cast<const bf16x8*>(Bb2 + rb[n]);
    }
#pragma unroll
    for (int m = 0; m < 4; m++)
#pragma unroll
      for (int n = 0; n < 4; n++) {
        acc[m][n] = __builtin_amdgcn_mfma_f32_16x16x32_bf16(av[m], bvg[n], acc[m][n], 0, 0, 0);
        if (FUSED)
          acc2[m][n] = __builtin_amdgcn_mfma_f32_16x16x32_bf16(av[m], bvu[n], acc2[m][n], 0, 0, 0);
      }
  };

  load_tile(ta0, tb0, tc0, 0);
#pragma unroll 1
  for (int kt = 0; kt < KT; kt += 2) {
    load_tile(ta1, tb1, tc1, kt + 1);
    store_tile(ta0, tb0, tc0);
    block_sync_fb();
    mfma_step();
    block_sync_fb();
    int k2 = (kt + 2 < KT) ? kt + 2 : 0;
    load_tile(ta0, tb0, tc0, k2);
    store_tile(ta1, tb1, tc1);
    block_sync_fb();
    mfma_step();
    block_sync_fb();
  }

#pragma unroll
  for (int m = 0; m < 4; m++) {
#pragma unroll
    for (int n = 0; n < 4; n++) {
      int col = colblk + wn * 64 + n * 16 + l15;
      f32x4 a = acc[m][n];
      f32x4 a2 = acc2[m][n];
#pragma unroll
      for (int q = 0; q < 4; q++) {
        int rl = wm * 64 + m * 16 + (g << 2) + q;
        int grow = rt * 128 + rl;
        float v = a[q];
        if (EPI == EPI_GU) {
          if (!EXPERT || grow < M) {
            float hv = (v / (1.f + __expf(-v))) * a2[q];
            O[(long)(obase + grow) * ldo + col] = hv;
          }
        } else if (EPI == EPI_DOWN) {
          if (grow < M)
            atomicAdd(&O[(long)s_tok[rl] * ldo + col], s_w[rl] * v);
        } else {
          atomicAdd(&O[(long)grow * ldo + col], sig[grow] * v);
        }
      }
    }
  }
}

// ---------------------------------------------------------------------------
extern "C" void kernel_launch(void* const* d_in, const int* in_sizes, int n_in,
                              void* d_out, int out_size, void* d_ws, size_t ws_size,
                              hipStream_t stream)
{
  (void)in_sizes; (void)n_in; (void)out_size;
  const float* x   = (const float*)d_in[0];
  const float* gw  = (const float*)d_in[1];
  const float* Wg  = (const float*)d_in[2];
  const float* Wu  = (const float*)d_in[3];
  const float* Wd  = (const float*)d_in[4];
  const float* Wsg = (const float*)d_in[5];
  const float* Wsu = (const float*)d_in[6];
  const float* Wsd = (const float*)d_in[7];
  const float* sgw = (const float*)d_in[8];

  float* out    = (float*)d_out;
  float* logits = out + (long)TKN * DMODEL;

  char* w    = (char*)d_ws;
  int*  cnt  = (int*)w;
  int*  offs = (int*)(w + 64);
  float* sig = (float*)(w + 1024);
  int*  tokl = (int*)(w + 16384);
  float* wls = (float*)(w + 81920);

  hipMemsetAsync(out, 0, (size_t)TKN * DMODEL * 4, stream);
  hipMemsetAsync(cnt, 0, 64, stream);

  router_k<<<dim3(TKN / 4), 256, 0, stream>>>(x, gw, sgw, logits, sig, cnt, tokl, wls);
  scan_k<<<1, 64, 0, stream>>>(cnt, offs);

  const size_t NEED = 241172480ull;   // 230 MB: bf16 x + h + weight panels
  if (ws_size >= NEED) {
    char* xbf   = w + 262144;          // 8 MB, frag-packed rows (stride 4096 B)
    char* h     = w + 8650752;         // 23 MB bf16 (expert: [8192] ldK=44; shared: [2048] ldK=176)
    char* pan   = w + 33554432;
    char* panWg  = pan;                      // 8 x 5767168
    char* panWu  = pan + 46137344;
    char* panWd  = pan + 92274688;           // 8 x 5767168
    char* panWsg = pan + 138412032;          // 23068672
    char* panWsu = pan + 161480704;
    char* panWsd = pan + 184549376;
    const long sPan = 5767168;

    cvt_x_k<<<dim3(2048), 256, 0, stream>>>(x, xbf);
    cvt_w_k<<<dim3(11, 64, 8), 256, 0, stream>>>(Wg, (long)DMODEL * FEXP, FEXP, panWg, sPan);
    cvt_w_k<<<dim3(11, 64, 8), 256, 0, stream>>>(Wu, (long)DMODEL * FEXP, FEXP, panWu, sPan);
    cvt_w_k<<<dim3(16, 44, 8), 256, 0, stream>>>(Wd, (long)FEXP * DMODEL, DMODEL, panWd, sPan);
    cvt_w_k<<<dim3(44, 64, 1), 256, 0, stream>>>(Wsg, 0, FSH, panWsg, 0);
    cvt_w_k<<<dim3(44, 64, 1), 256, 0, stream>>>(Wsu, 0, FSH, panWsu, 0);
    cvt_w_k<<<dim3(16, 176, 1), 256, 0, stream>>>(Wsd, 0, DMODEL, panWsd, 0);

    // expert fused gate+up -> h (bf16, ldK=44)
    gemm2_k<EPI_GU, true, 1><<<dim3(11, 128), 256, 0, stream>>>(
        xbf, 4096, panWg, panWu, sPan, 64, h, 44, cnt, offs, tokl, wls, nullptr);
    // expert down -> out (atomic fp32)
    gemm2_k<EPI_DOWN, true, 1><<<dim3(16, 128), 256, 0, stream>>>(
        h, 2816, panWd, nullptr, sPan, 44, out, 0, cnt, offs, tokl, wls, nullptr);
    // shared fused gate+up -> h (bf16, ldK=176)
    gemm2_k<EPI_GU, false, 1><<<dim3(44, 16), 256, 0, stream>>>(
        xbf, 4096, panWsg, panWsu, 0, 64, h, 176, nullptr, nullptr, nullptr, nullptr, nullptr);
    // shared down, split-K=4 -> out (atomic fp32)
    gemm2_k<EPI_SDOWN, false, 4><<<dim3(16, 64), 256, 0, stream>>>(
        h, 11264, panWsd, nullptr, 0, 176, out, 0, nullptr, nullptr, nullptr, nullptr, sig);
  } else {
    // fallback: R1 path (fp32 reg-staged GEMMs)
    float* h = (float*)(w + (1 << 20));
    gemm_fb_k<EPI_GU, true, 1><<<dim3(FEXP / 128, 128), 256, 0, stream>>>(
        x, DMODEL, Wg, Wu, (long)DMODEL * FEXP, FEXP, DMODEL, h, FEXP, cnt, offs, tokl, wls, nullptr);
    gemm_fb_k<EPI_DOWN, true, 1><<<dim3(DMODEL / 128, 128), 256, 0, stream>>>(
        h, FEXP, Wd, nullptr, (long)FEXP * DMODEL, DMODEL, FEXP, out, DMODEL, cnt, offs, tokl, wls, nullptr);
    gemm_fb_k<EPI_GU, false, 1><<<dim3(FSH / 128, TKN / 128), 256, 0, stream>>>(
        x, DMODEL, Wsg, Wsu, 0, FSH, DMODEL, h, FSH, nullptr, nullptr, nullptr, nullptr, nullptr);
    gemm_fb_k<EPI_SDOWN, false, 4><<<dim3(DMODEL / 128, (TKN / 128) * 4), 256, 0, stream>>>(
        h, FSH, Wsd, nullptr, 0, DMODEL, FSH, out, DMODEL, nullptr, nullptr, nullptr, nullptr, sig);
  }
}

// Round 4
// 695.885 us; speedup vs baseline: 1.7958x; 1.1018x over previous
//
#include <hip/hip_runtime.h>
#include <hip/hip_bf16.h>

typedef __attribute__((ext_vector_type(8))) __bf16 bf16x8;
typedef __attribute__((ext_vector_type(4))) float f32x4;

#define TKN 2048
#define DMODEL 2048
#define NEXP 8
#define FEXP 1408
#define FSH 5632

__device__ __forceinline__ unsigned short f2bf(float f) {
  unsigned u = __float_as_uint(f);
  u += 0x7FFFu + ((u >> 16) & 1u);          // round-to-nearest-even
  return (unsigned short)(u >> 16);
}
__device__ __forceinline__ unsigned pk2(float a, float b) {
  return (unsigned)f2bf(a) | ((unsigned)f2bf(b) << 16);
}

// global -> LDS direct copy, 16B per lane. LDS dest must be wave-uniform.
__device__ __forceinline__ void gll16(const void* g, void* l) {
  __builtin_amdgcn_global_load_lds(
      (const __attribute__((address_space(1))) unsigned*)g,
      (__attribute__((address_space(3))) unsigned*)l, 16, 0, 0);
}

enum { EPI_GU = 0, EPI_DOWN = 1, EPI_SDOWN = 2 };

// ---------------------------------------------------------------------------
// Router (fp32-exact logits path) + top-4 + per-expert token lists.
// ---------------------------------------------------------------------------
__global__ __launch_bounds__(256)
void router_k(const float* __restrict__ x, const float* __restrict__ gw,
              const float* __restrict__ sgw, float* __restrict__ logits,
              float* __restrict__ sig, int* __restrict__ cnt,
              int* __restrict__ tokl, float* __restrict__ wls)
{
  const int wv = threadIdx.x >> 6, lane = threadIdx.x & 63;
  const int t = blockIdx.x * 4 + wv;
  const float* xr = x + (long)t * DMODEL;
  float xv[32];
#pragma unroll
  for (int j = 0; j < 32; j++) xv[j] = xr[lane + (j << 6)];

  float lg[8];
#pragma unroll
  for (int e = 0; e < 8; e++) {
    const float* gr = gw + (long)e * DMODEL;
    float acc = 0.f;
#pragma unroll
    for (int j = 0; j < 32; j++) acc += xv[j] * gr[lane + (j << 6)];
#pragma unroll
    for (int s = 1; s < 64; s <<= 1) acc += __shfl_xor(acc, s, 64);
    lg[e] = acc;
  }
  float sgacc = 0.f;
#pragma unroll
  for (int j = 0; j < 32; j++) sgacc += xv[j] * sgw[lane + (j << 6)];
#pragma unroll
  for (int s = 1; s < 64; s <<= 1) sgacc += __shfl_xor(sgacc, s, 64);

  if (lane == 0) {
    float mx = lg[0];
#pragma unroll
    for (int e = 1; e < 8; e++) mx = fmaxf(mx, lg[e]);
    float p[8], se = 0.f;
#pragma unroll
    for (int e = 0; e < 8; e++) { p[e] = expf(lg[e] - mx); se += p[e]; }
    float inv = 1.f / se;
#pragma unroll
    for (int e = 0; e < 8; e++) { p[e] *= inv; logits[t * 8 + e] = lg[e]; }
    sig[t] = 1.f / (1.f + expf(-sgacc));
#pragma unroll
    for (int k = 0; k < 4; k++) {
      int bi = 0; float bv = p[0];
#pragma unroll
      for (int e = 1; e < 8; e++) if (p[e] > bv) { bv = p[e]; bi = e; }
      p[bi] = -1.f;
      int pos = atomicAdd(&cnt[bi], 1);
      tokl[bi * TKN + pos] = t;
      wls[bi * TKN + pos] = bv;
    }
  }
}

__global__ void scan_k(const int* __restrict__ cnt, int* __restrict__ offs) {
  if (threadIdx.x == 0) {
    int s = 0;
    for (int e = 0; e < 8; e++) { offs[e] = s; s += cnt[e]; }
    offs[8] = s;
  }
}

// ---------------------------------------------------------------------------
// x fp32 [2048][2048] -> fragment-packed bf16 rows: per row, unit u=kt*4+j
// (16B) holds k = {kt*32+j*4+0..3, kt*32+16+j*4+0..3}. Row stride 4096 B.
// ---------------------------------------------------------------------------
__global__ __launch_bounds__(256)
void cvt_x_k(const float* __restrict__ x, char* __restrict__ xbf)
{
  long id = (long)blockIdx.x * 256 + threadIdx.x;   // 524288 total
  int row = id >> 8, u = id & 255, kt = u >> 2, j = u & 3;
  const float* p = x + (long)row * 2048 + kt * 32 + j * 4;
  float4 a = *(const float4*)p;
  float4 b = *(const float4*)(p + 16);
  uint4 o;
  o.x = pk2(a.x, a.y); o.y = pk2(a.z, a.w);
  o.z = pk2(b.x, b.y); o.w = pk2(b.z, b.w);
  *(uint4*)(xbf + id * 16) = o;
}

// ---------------------------------------------------------------------------
// Weight fp32 [K][N] -> bf16 panel of 8KB tiles, tile (ct,kt) contiguous at
// ((ct*KT)+kt)*8192. Within tile: unit u = c*4+g holds B[kt*32+g*4+{0..3}][c]
// then B[kt*32+16+g*4+{0..3}][c]. Matches LDS-linear gload_lds + frag reads.
// ---------------------------------------------------------------------------
__global__ __launch_bounds__(256)
void cvt_w_k(const float* __restrict__ W, long sB, int N,
             char* __restrict__ panel, long panStride)
{
  const int ct = blockIdx.x, kt = blockIdx.y, e = blockIdx.z, KT = gridDim.y;
  const float* Wp = W + (long)e * sB + (long)(kt * 32) * N + ct * 128;
  __shared__ float t[32][128];
  const int r = threadIdx.x >> 3, q = threadIdx.x & 7;
  const float* rp = Wp + (long)r * N + q * 16;
  float4 f0 = *(const float4*)(rp + 0);
  float4 f1 = *(const float4*)(rp + 4);
  float4 f2 = *(const float4*)(rp + 8);
  float4 f3 = *(const float4*)(rp + 12);
  *(float4*)&t[r][q * 16 + 0]  = f0;
  *(float4*)&t[r][q * 16 + 4]  = f1;
  *(float4*)&t[r][q * 16 + 8]  = f2;
  *(float4*)&t[r][q * 16 + 12] = f3;
  __syncthreads();
  char* outp = panel + e * panStride + ((long)ct * KT + kt) * 8192;
#pragma unroll
  for (int uu = 0; uu < 2; uu++) {
    int u = threadIdx.x + uu * 256;
    int c = u >> 2, g = u & 3;
    uint4 o;
    o.x = pk2(t[g * 4 + 0][c], t[g * 4 + 1][c]);
    o.y = pk2(t[g * 4 + 2][c], t[g * 4 + 3][c]);
    o.z = pk2(t[16 + g * 4 + 0][c], t[16 + g * 4 + 1][c]);
    o.w = pk2(t[16 + g * 4 + 2][c], t[16 + g * 4 + 3][c]);
    *(uint4*)(outp + u * 16) = o;
  }
}

// ---------------------------------------------------------------------------
// bf16 MFMA GEMM, 128x128 tile, BK=32, 4 waves. Depth-2 pipelined staging:
// 3 LDS buffers, counted vmcnt (T4 - never 0 in main loop), raw s_barrier.
// 1-D grid with locality decode: expert kernels pin e = wg&7 (XCD-pinned
// under round-robin dispatch); shared kernels are rt-fastest for B reuse.
// ---------------------------------------------------------------------------
template<int EPI, bool EXPERT, int KSPLIT>
__global__ __launch_bounds__(256, 2)
void gemm2_k(const char* __restrict__ Abf, long strA,
             const char* __restrict__ Bp, const char* __restrict__ Bp2,
             long sBpan, int KTtot, int NCT,
             void* __restrict__ O, int ldKo,
             const int* __restrict__ cnt, const int* __restrict__ offs,
             const int* __restrict__ tokl, const float* __restrict__ wls,
             const float* __restrict__ sig)
{
  constexpr bool FUSED = (EPI == EPI_GU);
  const int tid = threadIdx.x, lane = tid & 63, w = tid >> 6;
  const int wg = blockIdx.x;

  int e = 0, rt, ct, kc = 0, M = TKN;
  if (EXPERT) {
    e = wg & 7; int q = wg >> 3; rt = q & 15; ct = q >> 4;
    M = cnt[e];
    if (rt * 128 >= M) return;
  } else {
    rt = wg & 15; int q = wg >> 4; ct = q % NCT; kc = q / NCT;
  }
  const int KT = KTtot / KSPLIT;
  const int kt0 = kc * KT;
  const int obase = EXPERT ? offs[e] : 0;

  __shared__ int s_tok[128];
  __shared__ float s_w[128];
  __shared__ alignas(16) char Ab[3][8192];
  __shared__ alignas(16) char Bb[3][8192];
  __shared__ alignas(16) char Bb2[FUSED ? 3 : 1][FUSED ? 8192 : 16];

  if (EXPERT) {
    if (tid < 128) {
      int r = rt * 128 + tid;
      int rc = (r < M) ? r : (M - 1);
      s_tok[tid] = tokl[e * TKN + rc];
      if (EPI == EPI_DOWN) s_w[tid] = (r < M) ? wls[e * TKN + r] : 0.f;
    }
    __syncthreads();
  }

  // ---- staging addresses. A: wave w, issue i covers rows w*32+i*16+(lane>>2)
  const int lrow0 = w * 32 + (lane >> 2);
  const int lrow1 = lrow0 + 16;
  auto rowbyte = [&](int rl) -> long {
    long gr;
    if (EPI == EPI_DOWN) { int r = rt * 128 + rl; gr = obase + ((r < M) ? r : (M - 1)); }
    else if (EXPERT)     { gr = s_tok[rl]; }
    else                 { gr = rt * 128 + rl; }
    return gr * strA;
  };
  const char* gA0 = Abf + rowbyte(lrow0) + (long)kt0 * 64 + (lane & 3) * 16;
  const char* gA1 = Abf + rowbyte(lrow1) + (long)kt0 * 64 + (lane & 3) * 16;
  const long bbase = (EXPERT ? (long)e * sBpan : 0) + ((long)ct * KTtot + kt0) * 8192
                     + w * 2048 + (long)lane * 16;
  const char* gB  = Bp + bbase;
  const char* gB2 = FUSED ? (Bp2 + bbase) : nullptr;

  auto stage = [&](int bf, int kt) {
    long ao = (long)kt * 64, bo = (long)kt * 8192;
    gll16(gA0 + ao, &Ab[bf][w * 2048]);
    gll16(gA1 + ao, &Ab[bf][w * 2048 + 1024]);
    gll16(gB + bo, &Bb[bf][w * 2048]);
    gll16(gB + bo + 1024, &Bb[bf][w * 2048 + 1024]);
    if constexpr (FUSED) {
      gll16(gB2 + bo, &Bb2[bf][w * 2048]);
      gll16(gB2 + bo + 1024, &Bb2[bf][w * 2048 + 1024]);
    }
  };

  // ---- fragment read offsets (linear fragment-packed layout)
  const int wm = w >> 1, wn = w & 1, g = lane >> 4, l15 = lane & 15;
  int raOff[4], rbOff[4];
#pragma unroll
  for (int m = 0; m < 4; m++) raOff[m] = (wm * 64 + m * 16 + l15) * 64 + g * 16;
#pragma unroll
  for (int n = 0; n < 4; n++) rbOff[n] = (wn * 64 + n * 16 + l15) * 64 + g * 16;

  f32x4 acc[4][4] = {};
  f32x4 acc2[4][4] = {};

  // ---- depth-2 pipeline prologue: tiles 0 and 1 in flight
  stage(0, 0);
  stage(1, 1);

  int rd = 0;
#pragma unroll 1
  for (int kt = 0; kt < KT; ++kt) {
    // wait for tile kt only (one tile's loads remain in flight), T4-counted
    if (kt + 1 < KT) {
      if constexpr (FUSED) asm volatile("s_waitcnt vmcnt(6)" ::: "memory");
      else                 asm volatile("s_waitcnt vmcnt(4)" ::: "memory");
    } else {
      asm volatile("s_waitcnt vmcnt(0)" ::: "memory");
    }
    __builtin_amdgcn_s_barrier();
    __builtin_amdgcn_sched_barrier(0);

    bf16x8 av[4], bg[4], bu[4];
#pragma unroll
    for (int m = 0; m < 4; m++) av[m] = *(const bf16x8*)&Ab[rd][raOff[m]];
#pragma unroll
    for (int n = 0; n < 4; n++) {
      bg[n] = *(const bf16x8*)&Bb[rd][rbOff[n]];
      if constexpr (FUSED) bu[n] = *(const bf16x8*)&Bb2[rd][rbOff[n]];
    }

    // stage tile kt+2 into the buffer whose reads completed before this
    // barrier (tile kt-1's buffer): (rd+2)%3
    int wr = rd + 2; if (wr >= 3) wr -= 3;
    if (kt + 2 < KT) stage(wr, kt + 2);

    __builtin_amdgcn_s_setprio(1);
#pragma unroll
    for (int m = 0; m < 4; m++)
#pragma unroll
      for (int n = 0; n < 4; n++) {
        acc[m][n] = __builtin_amdgcn_mfma_f32_16x16x32_bf16(av[m], bg[n], acc[m][n], 0, 0, 0);
        if constexpr (FUSED)
          acc2[m][n] = __builtin_amdgcn_mfma_f32_16x16x32_bf16(av[m], bu[n], acc2[m][n], 0, 0, 0);
      }
    __builtin_amdgcn_s_setprio(0);
    __builtin_amdgcn_sched_barrier(0);
    rd = (rd == 2) ? 0 : rd + 1;
  }

  // ---- epilogue. C/D frag: col = lane&15, row = (lane>>4)*4 + reg  [m89]
#pragma unroll
  for (int m = 0; m < 4; m++) {
#pragma unroll
    for (int n = 0; n < 4; n++) {
      int col = ct * 128 + wn * 64 + n * 16 + l15;
      f32x4 a = acc[m][n];
      f32x4 a2 = acc2[m][n];
#pragma unroll
      for (int q = 0; q < 4; q++) {
        int rl = wm * 64 + m * 16 + (g << 2) + q;
        int grow = rt * 128 + rl;
        float v = a[q];
        if constexpr (EPI == EPI_GU) {
          if (!EXPERT || grow < M) {
            float hv = (v / (1.f + __expf(-v))) * a2[q];
            long byteoff = (long)(obase + grow) * ((long)ldKo * 64)
                         + (col >> 5) * 64 + ((col >> 2) & 3) * 16
                         + ((col & 16) >> 1) + (col & 3) * 2;
            *(unsigned short*)((char*)O + byteoff) = f2bf(hv);
          }
        } else if constexpr (EPI == EPI_DOWN) {
          if (grow < M)
            atomicAdd((float*)O + (long)s_tok[rl] * DMODEL + col, s_w[rl] * v);
        } else {
          atomicAdd((float*)O + (long)grow * DMODEL + col, sig[grow] * v);
        }
      }
    }
  }
}

// ---------------------------------------------------------------------------
// FALLBACK (ws too small): R1 reg-staged GEMM, fp32 sources.
// ---------------------------------------------------------------------------
__device__ __forceinline__ void block_sync_fb() {
  __builtin_amdgcn_sched_barrier(0);
  asm volatile("s_waitcnt lgkmcnt(0)" ::: "memory");
  __builtin_amdgcn_s_barrier();
  __builtin_amdgcn_sched_barrier(0);
}

template<int EPI, bool EXPERT, int KSPLIT>
__global__ __launch_bounds__(256, 2)
void gemm_fb_k(const float* __restrict__ A, int lda,
               const float* __restrict__ B, const float* __restrict__ B2,
               long sB, int ldb, int Ktot,
               float* __restrict__ O, int ldo,
               const int* __restrict__ cnt, const int* __restrict__ offs,
               const int* __restrict__ tokl, const float* __restrict__ wls,
               const float* __restrict__ sig)
{
  constexpr bool FUSED = (EPI == EPI_GU);
  const int tid = threadIdx.x;
  const int lane = tid & 63;

  int e = 0, rt, kc = 0, M = TKN;
  if (EXPERT) {
    e = blockIdx.y >> 4; rt = blockIdx.y & 15;
    M = cnt[e];
    if (rt * 128 >= M) return;
  } else {
    rt = blockIdx.y & 15; kc = blockIdx.y >> 4;
  }
  const int K = Ktot / KSPLIT;
  const int koff = kc * K;
  const int colblk = blockIdx.x * 128;
  const float* Bp  = B + (EXPERT ? (long)e * sB : 0);
  const float* Bp2 = FUSED ? (B2 + (EXPERT ? (long)e * sB : 0)) : nullptr;
  const int obase = EXPERT ? offs[e] : 0;

  __shared__ alignas(16) unsigned char Ab[8192];
  __shared__ alignas(16) unsigned char Bb[8192];
  __shared__ alignas(16) unsigned char Bb2[FUSED ? 8192 : 16];
  __shared__ int s_tok[128];
  __shared__ float s_w[128];

  if (EXPERT && tid < 128) {
    int r = rt * 128 + tid;
    int rc = (r < M) ? r : (M - 1);
    s_tok[tid] = tokl[e * TKN + rc];
    if (EPI == EPI_DOWN) s_w[tid] = (r < M) ? wls[e * TKN + r] : 0.f;
  }
  if (EXPERT) __syncthreads();

  const int arowl = tid >> 1;
  const int ahalf = tid & 1;
  long arow;
  if (EPI == EPI_DOWN) {
    int r = rt * 128 + arowl;
    arow = (long)obase + ((r < M) ? r : (M - 1));
  } else if (EXPERT) {
    arow = s_tok[arowl];
  } else {
    arow = rt * 128 + arowl;
  }
  const float* aptr = A + arow * (long)lda + koff + ahalf * 16;
  int wa[4];
#pragma unroll
  for (int j = 0; j < 4; j++)
    wa[j] = arowl * 64 + ((j ^ ((arowl ^ (arowl >> 3)) & 3)) << 4) + ahalf * 8;

  const int kg = tid >> 5, ng = tid & 31;
  const float* bptr  = Bp + (long)(koff + kg * 4) * ldb + colblk + ng * 4;
  const float* bptr2 = FUSED ? (Bp2 + (long)(koff + kg * 4) * ldb + colblk + ng * 4) : nullptr;
  int wb[4];
#pragma unroll
  for (int i = 0; i < 4; i++) {
    int c = ng * 4 + i;
    wb[i] = c * 64 + ((((kg & 3) ^ ((c ^ (c >> 3)) & 3))) << 4) + (kg >> 2) * 8;
  }

  const int wid = tid >> 6, wm = wid >> 1, wn = wid & 1;
  const int g = lane >> 4, l15 = lane & 15;
  int ra[4], rb[4];
#pragma unroll
  for (int m = 0; m < 4; m++) {
    int r = wm * 64 + m * 16 + l15;
    ra[m] = r * 64 + ((g ^ ((r ^ (r >> 3)) & 3)) << 4);
  }
#pragma unroll
  for (int n = 0; n < 4; n++) {
    int c = wn * 64 + n * 16 + l15;
    rb[n] = c * 64 + ((g ^ ((c ^ (c >> 3)) & 3)) << 4);
  }

  f32x4 acc[4][4] = {};
  f32x4 acc2[4][4] = {};

  const int KT = K >> 5;
  float4 ta0[4], tb0[4], tc0[4], ta1[4], tb1[4], tc1[4];

  auto load_tile = [&](float4* ra_, float4* rb_, float4* rc_, int kt) {
    const float4* a4 = reinterpret_cast<const float4*>(aptr + kt * 32);
    ra_[0] = a4[0]; ra_[1] = a4[1]; ra_[2] = a4[2]; ra_[3] = a4[3];
    const float* bb = bptr + (long)kt * 32 * ldb;
    rb_[0] = *reinterpret_cast<const float4*>(bb);
    rb_[1] = *reinterpret_cast<const float4*>(bb + ldb);
    rb_[2] = *reinterpret_cast<const float4*>(bb + 2 * ldb);
    rb_[3] = *reinterpret_cast<const float4*>(bb + 3 * ldb);
    if (FUSED) {
      const float* cc = bptr2 + (long)kt * 32 * ldb;
      rc_[0] = *reinterpret_cast<const float4*>(cc);
      rc_[1] = *reinterpret_cast<const float4*>(cc + ldb);
      rc_[2] = *reinterpret_cast<const float4*>(cc + 2 * ldb);
      rc_[3] = *reinterpret_cast<const float4*>(cc + 3 * ldb);
    }
  };

  auto store_tile = [&](const float4* ra_, const float4* rb_, const float4* rc_) {
#pragma unroll
    for (int j = 0; j < 4; j++)
      *reinterpret_cast<uint2*>(Ab + wa[j]) =
          make_uint2(pk2(ra_[j].x, ra_[j].y), pk2(ra_[j].z, ra_[j].w));
    *reinterpret_cast<uint2*>(Bb + wb[0]) = make_uint2(pk2(rb_[0].x, rb_[1].x), pk2(rb_[2].x, rb_[3].x));
    *reinterpret_cast<uint2*>(Bb + wb[1]) = make_uint2(pk2(rb_[0].y, rb_[1].y), pk2(rb_[2].y, rb_[3].y));
    *reinterpret_cast<uint2*>(Bb + wb[2]) = make_uint2(pk2(rb_[0].z, rb_[1].z), pk2(rb_[2].z, rb_[3].z));
    *reinterpret_cast<uint2*>(Bb + wb[3]) = make_uint2(pk2(rb_[0].w, rb_[1].w), pk2(rb_[2].w, rb_[3].w));
    if (FUSED) {
      *reinterpret_cast<uint2*>(Bb2 + wb[0]) = make_uint2(pk2(rc_[0].x, rc_[1].x), pk2(rc_[2].x, rc_[3].x));
      *reinterpret_cast<uint2*>(Bb2 + wb[1]) = make_uint2(pk2(rc_[0].y, rc_[1].y), pk2(rc_[2].y, rc_[3].y));
      *reinterpret_cast<uint2*>(Bb2 + wb[2]) = make_uint2(pk2(rc_[0].z, rc_[1].z), pk2(rc_[2].z, rc_[3].z));
      *reinterpret_cast<uint2*>(Bb2 + wb[3]) = make_uint2(pk2(rc_[0].w, rc_[1].w), pk2(rc_[2].w, rc_[3].w));
    }
  };

  auto mfma_step = [&]() {
    bf16x8 av[4], bvg[4], bvu[4];
#pragma unroll
    for (int m = 0; m < 4; m++) av[m] = *reinterpret_cast<const bf16x8*>(Ab + ra[m]);
#pragma unroll
    for (int n = 0; n < 4; n++) {
      bvg[n] = *reinterpret_cast<const bf16x8*>(Bb + rb[n]);
      if (FUSED) bvu[n] = *reinterpret_cast<const bf16x8*>(Bb2 + rb[n]);
    }
#pragma unroll
    for (int m = 0; m < 4; m++)
#pragma unroll
      for (int n = 0; n < 4; n++) {
        acc[m][n] = __builtin_amdgcn_mfma_f32_16x16x32_bf16(av[m], bvg[n], acc[m][n], 0, 0, 0);
        if (FUSED)
          acc2[m][n] = __builtin_amdgcn_mfma_f32_16x16x32_bf16(av[m], bvu[n], acc2[m][n], 0, 0, 0);
      }
  };

  load_tile(ta0, tb0, tc0, 0);
#pragma unroll 1
  for (int kt = 0; kt < KT; kt += 2) {
    load_tile(ta1, tb1, tc1, kt + 1);
    store_tile(ta0, tb0, tc0);
    block_sync_fb();
    mfma_step();
    block_sync_fb();
    int k2 = (kt + 2 < KT) ? kt + 2 : 0;
    load_tile(ta0, tb0, tc0, k2);
    store_tile(ta1, tb1, tc1);
    block_sync_fb();
    mfma_step();
    block_sync_fb();
  }

#pragma unroll
  for (int m = 0; m < 4; m++) {
#pragma unroll
    for (int n = 0; n < 4; n++) {
      int col = colblk + wn * 64 + n * 16 + l15;
      f32x4 a = acc[m][n];
      f32x4 a2 = acc2[m][n];
#pragma unroll
      for (int q = 0; q < 4; q++) {
        int rl = wm * 64 + m * 16 + (g << 2) + q;
        int grow = rt * 128 + rl;
        float v = a[q];
        if (EPI == EPI_GU) {
          if (!EXPERT || grow < M) {
            float hv = (v / (1.f + __expf(-v))) * a2[q];
            O[(long)(obase + grow) * ldo + col] = hv;
          }
        } else if (EPI == EPI_DOWN) {
          if (grow < M)
            atomicAdd(&O[(long)s_tok[rl] * ldo + col], s_w[rl] * v);
        } else {
          atomicAdd(&O[(long)grow * ldo + col], sig[grow] * v);
        }
      }
    }
  }
}

// ---------------------------------------------------------------------------
extern "C" void kernel_launch(void* const* d_in, const int* in_sizes, int n_in,
                              void* d_out, int out_size, void* d_ws, size_t ws_size,
                              hipStream_t stream)
{
  (void)in_sizes; (void)n_in; (void)out_size;
  const float* x   = (const float*)d_in[0];
  const float* gw  = (const float*)d_in[1];
  const float* Wg  = (const float*)d_in[2];
  const float* Wu  = (const float*)d_in[3];
  const float* Wd  = (const float*)d_in[4];
  const float* Wsg = (const float*)d_in[5];
  const float* Wsu = (const float*)d_in[6];
  const float* Wsd = (const float*)d_in[7];
  const float* sgw = (const float*)d_in[8];

  float* out    = (float*)d_out;
  float* logits = out + (long)TKN * DMODEL;

  char* w    = (char*)d_ws;
  int*  cnt  = (int*)w;
  int*  offs = (int*)(w + 64);
  float* sig = (float*)(w + 1024);
  int*  tokl = (int*)(w + 16384);
  float* wls = (float*)(w + 81920);

  hipMemsetAsync(out, 0, (size_t)TKN * DMODEL * 4, stream);
  hipMemsetAsync(cnt, 0, 64, stream);

  router_k<<<dim3(TKN / 4), 256, 0, stream>>>(x, gw, sgw, logits, sig, cnt, tokl, wls);
  scan_k<<<1, 64, 0, stream>>>(cnt, offs);

  const size_t NEED = 241172480ull;   // 230 MB: bf16 x + h + weight panels
  if (ws_size >= NEED) {
    char* xbf   = w + 262144;          // 8 MB, frag-packed rows (stride 4096 B)
    char* h     = w + 8650752;         // 23 MB bf16 (expert: [8192] ldK=44; shared: [2048] ldK=176)
    char* pan   = w + 33554432;
    char* panWg  = pan;                      // 8 x 5767168
    char* panWu  = pan + 46137344;
    char* panWd  = pan + 92274688;           // 8 x 5767168
    char* panWsg = pan + 138412032;          // 23068672
    char* panWsu = pan + 161480704;
    char* panWsd = pan + 184549376;
    const long sPan = 5767168;

    cvt_x_k<<<dim3(2048), 256, 0, stream>>>(x, xbf);
    cvt_w_k<<<dim3(11, 64, 8), 256, 0, stream>>>(Wg, (long)DMODEL * FEXP, FEXP, panWg, sPan);
    cvt_w_k<<<dim3(11, 64, 8), 256, 0, stream>>>(Wu, (long)DMODEL * FEXP, FEXP, panWu, sPan);
    cvt_w_k<<<dim3(16, 44, 8), 256, 0, stream>>>(Wd, (long)FEXP * DMODEL, DMODEL, panWd, sPan);
    cvt_w_k<<<dim3(44, 64, 1), 256, 0, stream>>>(Wsg, 0, FSH, panWsg, 0);
    cvt_w_k<<<dim3(44, 64, 1), 256, 0, stream>>>(Wsu, 0, FSH, panWsu, 0);
    cvt_w_k<<<dim3(16, 176, 1), 256, 0, stream>>>(Wsd, 0, DMODEL, panWsd, 0);

    // expert fused gate+up -> h (bf16, ldK=44). grid: e=wg&7, rt=(wg>>3)&15, ct=wg>>7
    gemm2_k<EPI_GU, true, 1><<<dim3(8 * 16 * 11), 256, 0, stream>>>(
        xbf, 4096, panWg, panWu, sPan, 64, 11, h, 44, cnt, offs, tokl, wls, nullptr);
    // expert down -> out (atomic fp32)
    gemm2_k<EPI_DOWN, true, 1><<<dim3(8 * 16 * 16), 256, 0, stream>>>(
        h, 2816, panWd, nullptr, sPan, 44, 16, out, 0, cnt, offs, tokl, wls, nullptr);
    // shared fused gate+up -> h (bf16, ldK=176). rt-fastest for B-tile reuse
    gemm2_k<EPI_GU, false, 1><<<dim3(16 * 44), 256, 0, stream>>>(
        xbf, 4096, panWsg, panWsu, 0, 64, 44, h, 176, nullptr, nullptr, nullptr, nullptr, nullptr);
    // shared down, split-K=4 -> out (atomic fp32)
    gemm2_k<EPI_SDOWN, false, 4><<<dim3(16 * 16 * 4), 256, 0, stream>>>(
        h, 11264, panWsd, nullptr, 0, 176, 16, out, 0, nullptr, nullptr, nullptr, nullptr, sig);
  } else {
    // fallback: R1 path (fp32 reg-staged GEMMs)
    float* h = (float*)(w + (1 << 20));
    gemm_fb_k<EPI_GU, true, 1><<<dim3(FEXP / 128, 128), 256, 0, stream>>>(
        x, DMODEL, Wg, Wu, (long)DMODEL * FEXP, FEXP, DMODEL, h, FEXP, cnt, offs, tokl, wls, nullptr);
    gemm_fb_k<EPI_DOWN, true, 1><<<dim3(DMODEL / 128, 128), 256, 0, stream>>>(
        h, FEXP, Wd, nullptr, (long)FEXP * DMODEL, DMODEL, FEXP, out, DMODEL, cnt, offs, tokl, wls, nullptr);
    gemm_fb_k<EPI_GU, false, 1><<<dim3(FSH / 128, TKN / 128), 256, 0, stream>>>(
        x, DMODEL, Wsg, Wsu, 0, FSH, DMODEL, h, FSH, nullptr, nullptr, nullptr, nullptr, nullptr);
    gemm_fb_k<EPI_SDOWN, false, 4><<<dim3(DMODEL / 128, (TKN / 128) * 4), 256, 0, stream>>>(
        h, FSH, Wsd, nullptr, 0, DMODEL, FSH, out, DMODEL, nullptr, nullptr, nullptr, nullptr, sig);
  }
}

// Round 5
// 691.115 us; speedup vs baseline: 1.8082x; 1.0069x over previous
//
#include <hip/hip_runtime.h>
#include <hip/hip_bf16.h>

typedef __attribute__((ext_vector_type(8))) __bf16 bf16x8;
typedef __attribute__((ext_vector_type(4))) float f32x4;

#define TKN 2048
#define DMODEL 2048
#define NEXP 8
#define FEXP 1408
#define FSH 5632

__device__ __forceinline__ unsigned short f2bf(float f) {
  unsigned u = __float_as_uint(f);
  u += 0x7FFFu + ((u >> 16) & 1u);          // round-to-nearest-even
  return (unsigned short)(u >> 16);
}
__device__ __forceinline__ unsigned pk2(float a, float b) {
  return (unsigned)f2bf(a) | ((unsigned)f2bf(b) << 16);
}

// global -> LDS direct copy, 16B per lane. LDS dest must be wave-uniform.
__device__ __forceinline__ void gll16(const void* g, void* l) {
  __builtin_amdgcn_global_load_lds(
      (const __attribute__((address_space(1))) unsigned*)g,
      (__attribute__((address_space(3))) unsigned*)l, 16, 0, 0);
}

enum { EPI_GU = 0, EPI_DOWN = 1, EPI_SDOWN = 2 };

// ---------------------------------------------------------------------------
// Router (fp32-exact logits path) + top-4 + per-expert token lists.
// ---------------------------------------------------------------------------
__global__ __launch_bounds__(256)
void router_k(const float* __restrict__ x, const float* __restrict__ gw,
              const float* __restrict__ sgw, float* __restrict__ logits,
              float* __restrict__ sig, int* __restrict__ cnt,
              int* __restrict__ tokl, float* __restrict__ wls)
{
  const int wv = threadIdx.x >> 6, lane = threadIdx.x & 63;
  const int t = blockIdx.x * 4 + wv;
  const float* xr = x + (long)t * DMODEL;
  float xv[32];
#pragma unroll
  for (int j = 0; j < 32; j++) xv[j] = xr[lane + (j << 6)];

  float lg[8];
#pragma unroll
  for (int e = 0; e < 8; e++) {
    const float* gr = gw + (long)e * DMODEL;
    float acc = 0.f;
#pragma unroll
    for (int j = 0; j < 32; j++) acc += xv[j] * gr[lane + (j << 6)];
#pragma unroll
    for (int s = 1; s < 64; s <<= 1) acc += __shfl_xor(acc, s, 64);
    lg[e] = acc;
  }
  float sgacc = 0.f;
#pragma unroll
  for (int j = 0; j < 32; j++) sgacc += xv[j] * sgw[lane + (j << 6)];
#pragma unroll
  for (int s = 1; s < 64; s <<= 1) sgacc += __shfl_xor(sgacc, s, 64);

  if (lane == 0) {
    float mx = lg[0];
#pragma unroll
    for (int e = 1; e < 8; e++) mx = fmaxf(mx, lg[e]);
    float p[8], se = 0.f;
#pragma unroll
    for (int e = 0; e < 8; e++) { p[e] = expf(lg[e] - mx); se += p[e]; }
    float inv = 1.f / se;
#pragma unroll
    for (int e = 0; e < 8; e++) { p[e] *= inv; logits[t * 8 + e] = lg[e]; }
    sig[t] = 1.f / (1.f + expf(-sgacc));
#pragma unroll
    for (int k = 0; k < 4; k++) {
      int bi = 0; float bv = p[0];
#pragma unroll
      for (int e = 1; e < 8; e++) if (p[e] > bv) { bv = p[e]; bi = e; }
      p[bi] = -1.f;
      int pos = atomicAdd(&cnt[bi], 1);
      tokl[bi * TKN + pos] = t;
      wls[bi * TKN + pos] = bv;
    }
  }
}

__global__ void scan_k(const int* __restrict__ cnt, int* __restrict__ offs) {
  if (threadIdx.x == 0) {
    int s = 0;
    for (int e = 0; e < 8; e++) { offs[e] = s; s += cnt[e]; }
    offs[8] = s;
  }
}

// ---------------------------------------------------------------------------
// x fp32 [2048][2048] -> fragment-packed bf16 rows: per row, unit u=kt*4+j
// (16B) holds k = {kt*32+j*4+0..3, kt*32+16+j*4+0..3}. Row stride 4096 B.
// (Linear frag layout; the T2 unit swizzle is applied at GEMM staging time
// via per-lane source unit selection.)
// ---------------------------------------------------------------------------
__global__ __launch_bounds__(256)
void cvt_x_k(const float* __restrict__ x, char* __restrict__ xbf)
{
  long id = (long)blockIdx.x * 256 + threadIdx.x;   // 524288 total
  int row = id >> 8, u = id & 255, kt = u >> 2, j = u & 3;
  const float* p = x + (long)row * 2048 + kt * 32 + j * 4;
  float4 a = *(const float4*)p;
  float4 b = *(const float4*)(p + 16);
  uint4 o;
  o.x = pk2(a.x, a.y); o.y = pk2(a.z, a.w);
  o.z = pk2(b.x, b.y); o.w = pk2(b.z, b.w);
  *(uint4*)(xbf + id * 16) = o;
}

// ---------------------------------------------------------------------------
// Weight fp32 [K][N] -> bf16 panel of 8KB tiles, tile (ct,kt) contiguous at
// ((ct*KT)+kt)*8192. Within tile: position u = c*4+up holds frag unit
// g = up ^ ((c>>1)&3)  (T2 bank swizzle pre-baked; LDS copy is linear).
// Frag unit g of col c = B[kt*32+g*4+{0..3}][c] then B[kt*32+16+g*4+{0..3}][c].
// ---------------------------------------------------------------------------
__global__ __launch_bounds__(256)
void cvt_w_k(const float* __restrict__ W, long sB, int N,
             char* __restrict__ panel, long panStride)
{
  const int ct = blockIdx.x, kt = blockIdx.y, e = blockIdx.z, KT = gridDim.y;
  const float* Wp = W + (long)e * sB + (long)(kt * 32) * N + ct * 128;
  __shared__ float t[32][128];
  const int r = threadIdx.x >> 3, q = threadIdx.x & 7;
  const float* rp = Wp + (long)r * N + q * 16;
  float4 f0 = *(const float4*)(rp + 0);
  float4 f1 = *(const float4*)(rp + 4);
  float4 f2 = *(const float4*)(rp + 8);
  float4 f3 = *(const float4*)(rp + 12);
  *(float4*)&t[r][q * 16 + 0]  = f0;
  *(float4*)&t[r][q * 16 + 4]  = f1;
  *(float4*)&t[r][q * 16 + 8]  = f2;
  *(float4*)&t[r][q * 16 + 12] = f3;
  __syncthreads();
  char* outp = panel + e * panStride + ((long)ct * KT + kt) * 8192;
#pragma unroll
  for (int uu = 0; uu < 2; uu++) {
    int u = threadIdx.x + uu * 256;
    int c = u >> 2;
    int g = (u & 3) ^ ((c >> 1) & 3);        // T2 swizzle baked into panel
    uint4 o;
    o.x = pk2(t[g * 4 + 0][c], t[g * 4 + 1][c]);
    o.y = pk2(t[g * 4 + 2][c], t[g * 4 + 3][c]);
    o.z = pk2(t[16 + g * 4 + 0][c], t[16 + g * 4 + 1][c]);
    o.w = pk2(t[16 + g * 4 + 2][c], t[16 + g * 4 + 3][c]);
    *(uint4*)(outp + u * 16) = o;
  }
}

// ---------------------------------------------------------------------------
// bf16 MFMA GEMM, 128x128 tile, BK=32, 4 waves. Depth-2 pipelined staging
// (3 LDS buffers, counted vmcnt), XCD-pinned grid decode, and T2 unit-XOR
// LDS swizzle: LDS[row][u] holds frag u ^ ((row>>1)&3); reads XOR back.
// ---------------------------------------------------------------------------
template<int EPI, bool EXPERT, int KSPLIT>
__global__ __launch_bounds__(256, 2)
void gemm2_k(const char* __restrict__ Abf, long strA,
             const char* __restrict__ Bp, const char* __restrict__ Bp2,
             long sBpan, int KTtot, int NCT,
             void* __restrict__ O, int ldKo,
             const int* __restrict__ cnt, const int* __restrict__ offs,
             const int* __restrict__ tokl, const float* __restrict__ wls,
             const float* __restrict__ sig)
{
  constexpr bool FUSED = (EPI == EPI_GU);
  const int tid = threadIdx.x, lane = tid & 63, w = tid >> 6;
  const int wg = blockIdx.x;

  int e = 0, rt, ct, kc = 0, M = TKN;
  if (EXPERT) {
    e = wg & 7; int q = wg >> 3; rt = q & 15; ct = q >> 4;
    M = cnt[e];
    if (rt * 128 >= M) return;
  } else {
    rt = wg & 15; int q = wg >> 4; ct = q % NCT; kc = q / NCT;
  }
  const int KT = KTtot / KSPLIT;
  const int kt0 = kc * KT;
  const int obase = EXPERT ? offs[e] : 0;

  __shared__ int s_tok[128];
  __shared__ float s_w[128];
  __shared__ alignas(16) char Ab[3][8192];
  __shared__ alignas(16) char Bb[3][8192];
  __shared__ alignas(16) char Bb2[FUSED ? 3 : 1][FUSED ? 8192 : 16];

  if (EXPERT) {
    if (tid < 128) {
      int r = rt * 128 + tid;
      int rc = (r < M) ? r : (M - 1);
      s_tok[tid] = tokl[e * TKN + rc];
      if (EPI == EPI_DOWN) s_w[tid] = (r < M) ? wls[e * TKN + r] : 0.f;
    }
    __syncthreads();
  }

  // ---- staging addresses. A: wave w, issue i covers rows w*32+i*16+(lane>>2)
  // T2: lane (local row lr, unit u) fetches global frag unit u ^ ((lr>>1)&3)
  // so the linear gload_lds write leaves LDS[lr][u] = frag u ^ ((lr>>1)&3).
  const int lrow0 = w * 32 + (lane >> 2);
  const int lrow1 = lrow0 + 16;
  auto rowbyte = [&](int rl) -> long {
    long gr;
    if (EPI == EPI_DOWN) { int r = rt * 128 + rl; gr = obase + ((r < M) ? r : (M - 1)); }
    else if (EXPERT)     { gr = s_tok[rl]; }
    else                 { gr = rt * 128 + rl; }
    return gr * strA;
  };
  const int au0 = (lane & 3) ^ ((lrow0 >> 1) & 3);
  const int au1 = (lane & 3) ^ ((lrow1 >> 1) & 3);
  const char* gA0 = Abf + rowbyte(lrow0) + (long)kt0 * 64 + au0 * 16;
  const char* gA1 = Abf + rowbyte(lrow1) + (long)kt0 * 64 + au1 * 16;
  const long bbase = (EXPERT ? (long)e * sBpan : 0) + ((long)ct * KTtot + kt0) * 8192
                     + w * 2048 + (long)lane * 16;
  const char* gB  = Bp + bbase;
  const char* gB2 = FUSED ? (Bp2 + bbase) : nullptr;

  auto stage = [&](int bf, int kt) {
    long ao = (long)kt * 64, bo = (long)kt * 8192;
    gll16(gA0 + ao, &Ab[bf][w * 2048]);
    gll16(gA1 + ao, &Ab[bf][w * 2048 + 1024]);
    gll16(gB + bo, &Bb[bf][w * 2048]);
    gll16(gB + bo + 1024, &Bb[bf][w * 2048 + 1024]);
    if constexpr (FUSED) {
      gll16(gB2 + bo, &Bb2[bf][w * 2048]);
      gll16(gB2 + bo + 1024, &Bb2[bf][w * 2048 + 1024]);
    }
  };

  // ---- fragment read offsets (T2: unit = g ^ ((row>>1)&3))
  const int wm = w >> 1, wn = w & 1, g = lane >> 4, l15 = lane & 15;
  int raOff[4], rbOff[4];
#pragma unroll
  for (int m = 0; m < 4; m++) {
    int row = wm * 64 + m * 16 + l15;
    raOff[m] = row * 64 + ((g ^ ((row >> 1) & 3)) << 4);
  }
#pragma unroll
  for (int n = 0; n < 4; n++) {
    int col = wn * 64 + n * 16 + l15;
    rbOff[n] = col * 64 + ((g ^ ((col >> 1) & 3)) << 4);
  }

  f32x4 acc[4][4] = {};
  f32x4 acc2[4][4] = {};

  // ---- depth-2 pipeline prologue: tiles 0 and 1 in flight
  stage(0, 0);
  stage(1, 1);

  int rd = 0;
#pragma unroll 1
  for (int kt = 0; kt < KT; ++kt) {
    // wait for tile kt only (one tile's loads remain in flight), T4-counted
    if (kt + 1 < KT) {
      if constexpr (FUSED) asm volatile("s_waitcnt vmcnt(6)" ::: "memory");
      else                 asm volatile("s_waitcnt vmcnt(4)" ::: "memory");
    } else {
      asm volatile("s_waitcnt vmcnt(0)" ::: "memory");
    }
    __builtin_amdgcn_s_barrier();
    __builtin_amdgcn_sched_barrier(0);

    bf16x8 av[4], bg[4], bu[4];
#pragma unroll
    for (int m = 0; m < 4; m++) av[m] = *(const bf16x8*)&Ab[rd][raOff[m]];
#pragma unroll
    for (int n = 0; n < 4; n++) {
      bg[n] = *(const bf16x8*)&Bb[rd][rbOff[n]];
      if constexpr (FUSED) bu[n] = *(const bf16x8*)&Bb2[rd][rbOff[n]];
    }

    // stage tile kt+2 into the buffer whose reads completed before this
    // barrier (tile kt-1's buffer): (rd+2)%3
    int wr = rd + 2; if (wr >= 3) wr -= 3;
    if (kt + 2 < KT) stage(wr, kt + 2);

    __builtin_amdgcn_s_setprio(1);
#pragma unroll
    for (int m = 0; m < 4; m++)
#pragma unroll
      for (int n = 0; n < 4; n++) {
        acc[m][n] = __builtin_amdgcn_mfma_f32_16x16x32_bf16(av[m], bg[n], acc[m][n], 0, 0, 0);
        if constexpr (FUSED)
          acc2[m][n] = __builtin_amdgcn_mfma_f32_16x16x32_bf16(av[m], bu[n], acc2[m][n], 0, 0, 0);
      }
    __builtin_amdgcn_s_setprio(0);
    __builtin_amdgcn_sched_barrier(0);
    rd = (rd == 2) ? 0 : rd + 1;
  }

  // ---- epilogue. C/D frag: col = lane&15, row = (lane>>4)*4 + reg  [m89]
#pragma unroll
  for (int m = 0; m < 4; m++) {
#pragma unroll
    for (int n = 0; n < 4; n++) {
      int col = ct * 128 + wn * 64 + n * 16 + l15;
      f32x4 a = acc[m][n];
      f32x4 a2 = acc2[m][n];
#pragma unroll
      for (int q = 0; q < 4; q++) {
        int rl = wm * 64 + m * 16 + (g << 2) + q;
        int grow = rt * 128 + rl;
        float v = a[q];
        if constexpr (EPI == EPI_GU) {
          if (!EXPERT || grow < M) {
            float hv = (v / (1.f + __expf(-v))) * a2[q];
            long byteoff = (long)(obase + grow) * ((long)ldKo * 64)
                         + (col >> 5) * 64 + ((col >> 2) & 3) * 16
                         + ((col & 16) >> 1) + (col & 3) * 2;
            *(unsigned short*)((char*)O + byteoff) = f2bf(hv);
          }
        } else if constexpr (EPI == EPI_DOWN) {
          if (grow < M)
            atomicAdd((float*)O + (long)s_tok[rl] * DMODEL + col, s_w[rl] * v);
        } else {
          atomicAdd((float*)O + (long)grow * DMODEL + col, sig[grow] * v);
        }
      }
    }
  }
}

// ---------------------------------------------------------------------------
// FALLBACK (ws too small): R1 reg-staged GEMM, fp32 sources.
// ---------------------------------------------------------------------------
__device__ __forceinline__ void block_sync_fb() {
  __builtin_amdgcn_sched_barrier(0);
  asm volatile("s_waitcnt lgkmcnt(0)" ::: "memory");
  __builtin_amdgcn_s_barrier();
  __builtin_amdgcn_sched_barrier(0);
}

template<int EPI, bool EXPERT, int KSPLIT>
__global__ __launch_bounds__(256, 2)
void gemm_fb_k(const float* __restrict__ A, int lda,
               const float* __restrict__ B, const float* __restrict__ B2,
               long sB, int ldb, int Ktot,
               float* __restrict__ O, int ldo,
               const int* __restrict__ cnt, const int* __restrict__ offs,
               const int* __restrict__ tokl, const float* __restrict__ wls,
               const float* __restrict__ sig)
{
  constexpr bool FUSED = (EPI == EPI_GU);
  const int tid = threadIdx.x;
  const int lane = tid & 63;

  int e = 0, rt, kc = 0, M = TKN;
  if (EXPERT) {
    e = blockIdx.y >> 4; rt = blockIdx.y & 15;
    M = cnt[e];
    if (rt * 128 >= M) return;
  } else {
    rt = blockIdx.y & 15; kc = blockIdx.y >> 4;
  }
  const int K = Ktot / KSPLIT;
  const int koff = kc * K;
  const int colblk = blockIdx.x * 128;
  const float* Bp  = B + (EXPERT ? (long)e * sB : 0);
  const float* Bp2 = FUSED ? (B2 + (EXPERT ? (long)e * sB : 0)) : nullptr;
  const int obase = EXPERT ? offs[e] : 0;

  __shared__ alignas(16) unsigned char Ab[8192];
  __shared__ alignas(16) unsigned char Bb[8192];
  __shared__ alignas(16) unsigned char Bb2[FUSED ? 8192 : 16];
  __shared__ int s_tok[128];
  __shared__ float s_w[128];

  if (EXPERT && tid < 128) {
    int r = rt * 128 + tid;
    int rc = (r < M) ? r : (M - 1);
    s_tok[tid] = tokl[e * TKN + rc];
    if (EPI == EPI_DOWN) s_w[tid] = (r < M) ? wls[e * TKN + r] : 0.f;
  }
  if (EXPERT) __syncthreads();

  const int arowl = tid >> 1;
  const int ahalf = tid & 1;
  long arow;
  if (EPI == EPI_DOWN) {
    int r = rt * 128 + arowl;
    arow = (long)obase + ((r < M) ? r : (M - 1));
  } else if (EXPERT) {
    arow = s_tok[arowl];
  } else {
    arow = rt * 128 + arowl;
  }
  const float* aptr = A + arow * (long)lda + koff + ahalf * 16;
  int wa[4];
#pragma unroll
  for (int j = 0; j < 4; j++)
    wa[j] = arowl * 64 + ((j ^ ((arowl ^ (arowl >> 3)) & 3)) << 4) + ahalf * 8;

  const int kg = tid >> 5, ng = tid & 31;
  const float* bptr  = Bp + (long)(koff + kg * 4) * ldb + colblk + ng * 4;
  const float* bptr2 = FUSED ? (Bp2 + (long)(koff + kg * 4) * ldb + colblk + ng * 4) : nullptr;
  int wb[4];
#pragma unroll
  for (int i = 0; i < 4; i++) {
    int c = ng * 4 + i;
    wb[i] = c * 64 + ((((kg & 3) ^ ((c ^ (c >> 3)) & 3))) << 4) + (kg >> 2) * 8;
  }

  const int wid = tid >> 6, wm = wid >> 1, wn = wid & 1;
  const int g = lane >> 4, l15 = lane & 15;
  int ra[4], rb[4];
#pragma unroll
  for (int m = 0; m < 4; m++) {
    int r = wm * 64 + m * 16 + l15;
    ra[m] = r * 64 + ((g ^ ((r ^ (r >> 3)) & 3)) << 4);
  }
#pragma unroll
  for (int n = 0; n < 4; n++) {
    int c = wn * 64 + n * 16 + l15;
    rb[n] = c * 64 + ((g ^ ((c ^ (c >> 3)) & 3)) << 4);
  }

  f32x4 acc[4][4] = {};
  f32x4 acc2[4][4] = {};

  const int KT = K >> 5;
  float4 ta0[4], tb0[4], tc0[4], ta1[4], tb1[4], tc1[4];

  auto load_tile = [&](float4* ra_, float4* rb_, float4* rc_, int kt) {
    const float4* a4 = reinterpret_cast<const float4*>(aptr + kt * 32);
    ra_[0] = a4[0]; ra_[1] = a4[1]; ra_[2] = a4[2]; ra_[3] = a4[3];
    const float* bb = bptr + (long)kt * 32 * ldb;
    rb_[0] = *reinterpret_cast<const float4*>(bb);
    rb_[1] = *reinterpret_cast<const float4*>(bb + ldb);
    rb_[2] = *reinterpret_cast<const float4*>(bb + 2 * ldb);
    rb_[3] = *reinterpret_cast<const float4*>(bb + 3 * ldb);
    if (FUSED) {
      const float* cc = bptr2 + (long)kt * 32 * ldb;
      rc_[0] = *reinterpret_cast<const float4*>(cc);
      rc_[1] = *reinterpret_cast<const float4*>(cc + ldb);
      rc_[2] = *reinterpret_cast<const float4*>(cc + 2 * ldb);
      rc_[3] = *reinterpret_cast<const float4*>(cc + 3 * ldb);
    }
  };

  auto store_tile = [&](const float4* ra_, const float4* rb_, const float4* rc_) {
#pragma unroll
    for (int j = 0; j < 4; j++)
      *reinterpret_cast<uint2*>(Ab + wa[j]) =
          make_uint2(pk2(ra_[j].x, ra_[j].y), pk2(ra_[j].z, ra_[j].w));
    *reinterpret_cast<uint2*>(Bb + wb[0]) = make_uint2(pk2(rb_[0].x, rb_[1].x), pk2(rb_[2].x, rb_[3].x));
    *reinterpret_cast<uint2*>(Bb + wb[1]) = make_uint2(pk2(rb_[0].y, rb_[1].y), pk2(rb_[2].y, rb_[3].y));
    *reinterpret_cast<uint2*>(Bb + wb[2]) = make_uint2(pk2(rb_[0].z, rb_[1].z), pk2(rb_[2].z, rb_[3].z));
    *reinterpret_cast<uint2*>(Bb + wb[3]) = make_uint2(pk2(rb_[0].w, rb_[1].w), pk2(rb_[2].w, rb_[3].w));
    if (FUSED) {
      *reinterpret_cast<uint2*>(Bb2 + wb[0]) = make_uint2(pk2(rc_[0].x, rc_[1].x), pk2(rc_[2].x, rc_[3].x));
      *reinterpret_cast<uint2*>(Bb2 + wb[1]) = make_uint2(pk2(rc_[0].y, rc_[1].y), pk2(rc_[2].y, rc_[3].y));
      *reinterpret_cast<uint2*>(Bb2 + wb[2]) = make_uint2(pk2(rc_[0].z, rc_[1].z), pk2(rc_[2].z, rc_[3].z));
      *reinterpret_cast<uint2*>(Bb2 + wb[3]) = make_uint2(pk2(rc_[0].w, rc_[1].w), pk2(rc_[2].w, rc_[3].w));
    }
  };

  auto mfma_step = [&]() {
    bf16x8 av[4], bvg[4], bvu[4];
#pragma unroll
    for (int m = 0; m < 4; m++) av[m] = *reinterpret_cast<const bf16x8*>(Ab + ra[m]);
#pragma unroll
    for (int n = 0; n < 4; n++) {
      bvg[n] = *reinterpret_cast<const bf16x8*>(Bb + rb[n]);
      if (FUSED) bvu[n] = *reinterpret_cast<const bf16x8*>(Bb2 + rb[n]);
    }
#pragma unroll
    for (int m = 0; m < 4; m++)
#pragma unroll
      for (int n = 0; n < 4; n++) {
        acc[m][n] = __builtin_amdgcn_mfma_f32_16x16x32_bf16(av[m], bvg[n], acc[m][n], 0, 0, 0);
        if (FUSED)
          acc2[m][n] = __builtin_amdgcn_mfma_f32_16x16x32_bf16(av[m], bvu[n], acc2[m][n], 0, 0, 0);
      }
  };

  load_tile(ta0, tb0, tc0, 0);
#pragma unroll 1
  for (int kt = 0; kt < KT; kt += 2) {
    load_tile(ta1, tb1, tc1, kt + 1);
    store_tile(ta0, tb0, tc0);
    block_sync_fb();
    mfma_step();
    block_sync_fb();
    int k2 = (kt + 2 < KT) ? kt + 2 : 0;
    load_tile(ta0, tb0, tc0, k2);
    store_tile(ta1, tb1, tc1);
    block_sync_fb();
    mfma_step();
    block_sync_fb();
  }

#pragma unroll
  for (int m = 0; m < 4; m++) {
#pragma unroll
    for (int n = 0; n < 4; n++) {
      int col = colblk + wn * 64 + n * 16 + l15;
      f32x4 a = acc[m][n];
      f32x4 a2 = acc2[m][n];
#pragma unroll
      for (int q = 0; q < 4; q++) {
        int rl = wm * 64 + m * 16 + (g << 2) + q;
        int grow = rt * 128 + rl;
        float v = a[q];
        if (EPI == EPI_GU) {
          if (!EXPERT || grow < M) {
            float hv = (v / (1.f + __expf(-v))) * a2[q];
            O[(long)(obase + grow) * ldo + col] = hv;
          }
        } else if (EPI == EPI_DOWN) {
          if (grow < M)
            atomicAdd(&O[(long)s_tok[rl] * ldo + col], s_w[rl] * v);
        } else {
          atomicAdd(&O[(long)grow * ldo + col], sig[grow] * v);
        }
      }
    }
  }
}

// ---------------------------------------------------------------------------
extern "C" void kernel_launch(void* const* d_in, const int* in_sizes, int n_in,
                              void* d_out, int out_size, void* d_ws, size_t ws_size,
                              hipStream_t stream)
{
  (void)in_sizes; (void)n_in; (void)out_size;
  const float* x   = (const float*)d_in[0];
  const float* gw  = (const float*)d_in[1];
  const float* Wg  = (const float*)d_in[2];
  const float* Wu  = (const float*)d_in[3];
  const float* Wd  = (const float*)d_in[4];
  const float* Wsg = (const float*)d_in[5];
  const float* Wsu = (const float*)d_in[6];
  const float* Wsd = (const float*)d_in[7];
  const float* sgw = (const float*)d_in[8];

  float* out    = (float*)d_out;
  float* logits = out + (long)TKN * DMODEL;

  char* w    = (char*)d_ws;
  int*  cnt  = (int*)w;
  int*  offs = (int*)(w + 64);
  float* sig = (float*)(w + 1024);
  int*  tokl = (int*)(w + 16384);
  float* wls = (float*)(w + 81920);

  hipMemsetAsync(out, 0, (size_t)TKN * DMODEL * 4, stream);
  hipMemsetAsync(cnt, 0, 64, stream);

  router_k<<<dim3(TKN / 4), 256, 0, stream>>>(x, gw, sgw, logits, sig, cnt, tokl, wls);
  scan_k<<<1, 64, 0, stream>>>(cnt, offs);

  const size_t NEED = 241172480ull;   // 230 MB: bf16 x + h + weight panels
  if (ws_size >= NEED) {
    char* xbf   = w + 262144;          // 8 MB, frag-packed rows (stride 4096 B)
    char* h     = w + 8650752;         // 23 MB bf16 (expert: [8192] ldK=44; shared: [2048] ldK=176)
    char* pan   = w + 33554432;
    char* panWg  = pan;                      // 8 x 5767168
    char* panWu  = pan + 46137344;
    char* panWd  = pan + 92274688;           // 8 x 5767168
    char* panWsg = pan + 138412032;          // 23068672
    char* panWsu = pan + 161480704;
    char* panWsd = pan + 184549376;
    const long sPan = 5767168;

    cvt_x_k<<<dim3(2048), 256, 0, stream>>>(x, xbf);
    cvt_w_k<<<dim3(11, 64, 8), 256, 0, stream>>>(Wg, (long)DMODEL * FEXP, FEXP, panWg, sPan);
    cvt_w_k<<<dim3(11, 64, 8), 256, 0, stream>>>(Wu, (long)DMODEL * FEXP, FEXP, panWu, sPan);
    cvt_w_k<<<dim3(16, 44, 8), 256, 0, stream>>>(Wd, (long)FEXP * DMODEL, DMODEL, panWd, sPan);
    cvt_w_k<<<dim3(44, 64, 1), 256, 0, stream>>>(Wsg, 0, FSH, panWsg, 0);
    cvt_w_k<<<dim3(44, 64, 1), 256, 0, stream>>>(Wsu, 0, FSH, panWsu, 0);
    cvt_w_k<<<dim3(16, 176, 1), 256, 0, stream>>>(Wsd, 0, DMODEL, panWsd, 0);

    // expert fused gate+up -> h (bf16, ldK=44). grid: e=wg&7, rt=(wg>>3)&15, ct=wg>>7
    gemm2_k<EPI_GU, true, 1><<<dim3(8 * 16 * 11), 256, 0, stream>>>(
        xbf, 4096, panWg, panWu, sPan, 64, 11, h, 44, cnt, offs, tokl, wls, nullptr);
    // expert down -> out (atomic fp32)
    gemm2_k<EPI_DOWN, true, 1><<<dim3(8 * 16 * 16), 256, 0, stream>>>(
        h, 2816, panWd, nullptr, sPan, 44, 16, out, 0, cnt, offs, tokl, wls, nullptr);
    // shared fused gate+up -> h (bf16, ldK=176). rt-fastest for B-tile reuse
    gemm2_k<EPI_GU, false, 1><<<dim3(16 * 44), 256, 0, stream>>>(
        xbf, 4096, panWsg, panWsu, 0, 64, 44, h, 176, nullptr, nullptr, nullptr, nullptr, nullptr);
    // shared down, split-K=4 -> out (atomic fp32)
    gemm2_k<EPI_SDOWN, false, 4><<<dim3(16 * 16 * 4), 256, 0, stream>>>(
        h, 11264, panWsd, nullptr, 0, 176, 16, out, 0, nullptr, nullptr, nullptr, nullptr, sig);
  } else {
    // fallback: R1 path (fp32 reg-staged GEMMs)
    float* h = (float*)(w + (1 << 20));
    gemm_fb_k<EPI_GU, true, 1><<<dim3(FEXP / 128, 128), 256, 0, stream>>>(
        x, DMODEL, Wg, Wu, (long)DMODEL * FEXP, FEXP, DMODEL, h, FEXP, cnt, offs, tokl, wls, nullptr);
    gemm_fb_k<EPI_DOWN, true, 1><<<dim3(DMODEL / 128, 128), 256, 0, stream>>>(
        h, FEXP, Wd, nullptr, (long)FEXP * DMODEL, DMODEL, FEXP, out, DMODEL, cnt, offs, tokl, wls, nullptr);
    gemm_fb_k<EPI_GU, false, 1><<<dim3(FSH / 128, TKN / 128), 256, 0, stream>>>(
        x, DMODEL, Wsg, Wsu, 0, FSH, DMODEL, h, FSH, nullptr, nullptr, nullptr, nullptr, nullptr);
    gemm_fb_k<EPI_SDOWN, false, 4><<<dim3(DMODEL / 128, (TKN / 128) * 4), 256, 0, stream>>>(
        h, FSH, Wsd, nullptr, 0, DMODEL, FSH, out, DMODEL, nullptr, nullptr, nullptr, nullptr, sig);
  }
}

// Round 6
// 682.205 us; speedup vs baseline: 1.8318x; 1.0131x over previous
//
#include <hip/hip_runtime.h>
#include <hip/hip_bf16.h>

typedef __attribute__((ext_vector_type(8))) __bf16 bf16x8;
typedef __attribute__((ext_vector_type(4))) float f32x4;

#define TKN 2048
#define DMODEL 2048
#define NEXP 8
#define FEXP 1408
#define FSH 5632

__device__ __forceinline__ unsigned short f2bf(float f) {
  unsigned u = __float_as_uint(f);
  u += 0x7FFFu + ((u >> 16) & 1u);          // round-to-nearest-even
  return (unsigned short)(u >> 16);
}
__device__ __forceinline__ unsigned pk2(float a, float b) {
  return (unsigned)f2bf(a) | ((unsigned)f2bf(b) << 16);
}

// global -> LDS direct copy, 16B per lane. LDS dest must be wave-uniform.
__device__ __forceinline__ void gll16(const void* g, void* l) {
  __builtin_amdgcn_global_load_lds(
      (const __attribute__((address_space(1))) unsigned*)g,
      (__attribute__((address_space(3))) unsigned*)l, 16, 0, 0);
}

enum { EPI_GU = 0, EPI_DOWN = 1, EPI_SDOWN = 2 };

// ---------------------------------------------------------------------------
// Router (fp32-exact logits path) + top-4 + per-expert token lists.
// ---------------------------------------------------------------------------
__global__ __launch_bounds__(256)
void router_k(const float* __restrict__ x, const float* __restrict__ gw,
              const float* __restrict__ sgw, float* __restrict__ logits,
              float* __restrict__ sig, int* __restrict__ cnt,
              int* __restrict__ tokl, float* __restrict__ wls)
{
  const int wv = threadIdx.x >> 6, lane = threadIdx.x & 63;
  const int t = blockIdx.x * 4 + wv;
  const float* xr = x + (long)t * DMODEL;
  float xv[32];
#pragma unroll
  for (int j = 0; j < 32; j++) xv[j] = xr[lane + (j << 6)];

  float lg[8];
#pragma unroll
  for (int e = 0; e < 8; e++) {
    const float* gr = gw + (long)e * DMODEL;
    float acc = 0.f;
#pragma unroll
    for (int j = 0; j < 32; j++) acc += xv[j] * gr[lane + (j << 6)];
#pragma unroll
    for (int s = 1; s < 64; s <<= 1) acc += __shfl_xor(acc, s, 64);
    lg[e] = acc;
  }
  float sgacc = 0.f;
#pragma unroll
  for (int j = 0; j < 32; j++) sgacc += xv[j] * sgw[lane + (j << 6)];
#pragma unroll
  for (int s = 1; s < 64; s <<= 1) sgacc += __shfl_xor(sgacc, s, 64);

  if (lane == 0) {
    float mx = lg[0];
#pragma unroll
    for (int e = 1; e < 8; e++) mx = fmaxf(mx, lg[e]);
    float p[8], se = 0.f;
#pragma unroll
    for (int e = 0; e < 8; e++) { p[e] = expf(lg[e] - mx); se += p[e]; }
    float inv = 1.f / se;
#pragma unroll
    for (int e = 0; e < 8; e++) { p[e] *= inv; logits[t * 8 + e] = lg[e]; }
    sig[t] = 1.f / (1.f + expf(-sgacc));
#pragma unroll
    for (int k = 0; k < 4; k++) {
      int bi = 0; float bv = p[0];
#pragma unroll
      for (int e = 1; e < 8; e++) if (p[e] > bv) { bv = p[e]; bi = e; }
      p[bi] = -1.f;
      int pos = atomicAdd(&cnt[bi], 1);
      tokl[bi * TKN + pos] = t;
      wls[bi * TKN + pos] = bv;
    }
  }
}

__global__ void scan_k(const int* __restrict__ cnt, int* __restrict__ offs) {
  if (threadIdx.x == 0) {
    int s = 0;
    for (int e = 0; e < 8; e++) { offs[e] = s; s += cnt[e]; }
    offs[8] = s;
  }
}

// ---------------------------------------------------------------------------
// x fp32 [2048][2048] -> fragment-packed bf16 rows: per row, unit u=kt*4+j
// (16B) holds k = {kt*32+j*4+0..3, kt*32+16+j*4+0..3}. Row stride 4096 B.
// ---------------------------------------------------------------------------
__global__ __launch_bounds__(256)
void cvt_x_k(const float* __restrict__ x, char* __restrict__ xbf)
{
  long id = (long)blockIdx.x * 256 + threadIdx.x;   // 524288 total
  int row = id >> 8, u = id & 255, kt = u >> 2, j = u & 3;
  const float* p = x + (long)row * 2048 + kt * 32 + j * 4;
  float4 a = *(const float4*)p;
  float4 b = *(const float4*)(p + 16);
  uint4 o;
  o.x = pk2(a.x, a.y); o.y = pk2(a.z, a.w);
  o.z = pk2(b.x, b.y); o.w = pk2(b.z, b.w);
  *(uint4*)(xbf + id * 16) = o;
}

// ---------------------------------------------------------------------------
// Plain weight fp32 [K][N] -> bf16 panel of 8KB tiles, tile (ct,kt) at
// ((ct*KT)+kt)*8192. Position u = c*4+up holds frag unit g = up^((c>>1)&3)
// (T2 swizzle pre-baked). Frag unit g of col c = B[kt*32+g*4+{0..3}][c] then
// B[kt*32+16+g*4+{0..3}][c].
// ---------------------------------------------------------------------------
__global__ __launch_bounds__(256)
void cvt_w_k(const float* __restrict__ W, long sB, int N,
             char* __restrict__ panel, long panStride)
{
  const int ct = blockIdx.x, kt = blockIdx.y, e = blockIdx.z, KT = gridDim.y;
  const float* Wp = W + (long)e * sB + (long)(kt * 32) * N + ct * 128;
  __shared__ float t[32][128];
  const int r = threadIdx.x >> 3, q = threadIdx.x & 7;
  const float* rp = Wp + (long)r * N + q * 16;
  float4 f0 = *(const float4*)(rp + 0);
  float4 f1 = *(const float4*)(rp + 4);
  float4 f2 = *(const float4*)(rp + 8);
  float4 f3 = *(const float4*)(rp + 12);
  *(float4*)&t[r][q * 16 + 0]  = f0;
  *(float4*)&t[r][q * 16 + 4]  = f1;
  *(float4*)&t[r][q * 16 + 8]  = f2;
  *(float4*)&t[r][q * 16 + 12] = f3;
  __syncthreads();
  char* outp = panel + e * panStride + ((long)ct * KT + kt) * 8192;
#pragma unroll
  for (int uu = 0; uu < 2; uu++) {
    int u = threadIdx.x + uu * 256;
    int c = u >> 2;
    int g = (u & 3) ^ ((c >> 1) & 3);
    uint4 o;
    o.x = pk2(t[g * 4 + 0][c], t[g * 4 + 1][c]);
    o.y = pk2(t[g * 4 + 2][c], t[g * 4 + 3][c]);
    o.z = pk2(t[16 + g * 4 + 0][c], t[16 + g * 4 + 1][c]);
    o.w = pk2(t[16 + g * 4 + 2][c], t[16 + g * 4 + 3][c]);
    *(uint4*)(outp + u * 16) = o;
  }
}

// ---------------------------------------------------------------------------
// GU combined panel: interleaves Wg/Wu columns at 32-col granularity.
// Physical 128-col tile ct covers LOGICAL cols [ct*64, ct*64+64):
//   phys p: matrix = (p>>5)&1 (0=gate,1=up), logical col = ct*64+((p>>6)<<5)+(p&31).
// Same 8KB-tile packing + T2 swizzle as cvt_w_k.
// ---------------------------------------------------------------------------
__global__ __launch_bounds__(256)
void cvt_gu_k(const float* __restrict__ Wg, const float* __restrict__ Wu,
              long sB, int N, char* __restrict__ panel, long panStride)
{
  const int ct = blockIdx.x, kt = blockIdx.y, e = blockIdx.z, KT = gridDim.y;
  __shared__ float t[32][128];
  const int r = threadIdx.x >> 3, q = threadIdx.x & 7;
  const float* src = ((q >> 1) & 1) ? Wu : Wg;
  const int scol = ct * 64 + ((q >> 2) << 5) + ((q & 1) << 4);
  const float* rp = src + (long)e * sB + (long)(kt * 32 + r) * N + scol;
  float4 f0 = *(const float4*)(rp + 0);
  float4 f1 = *(const float4*)(rp + 4);
  float4 f2 = *(const float4*)(rp + 8);
  float4 f3 = *(const float4*)(rp + 12);
  *(float4*)&t[r][q * 16 + 0]  = f0;
  *(float4*)&t[r][q * 16 + 4]  = f1;
  *(float4*)&t[r][q * 16 + 8]  = f2;
  *(float4*)&t[r][q * 16 + 12] = f3;
  __syncthreads();
  char* outp = panel + e * panStride + ((long)ct * KT + kt) * 8192;
#pragma unroll
  for (int uu = 0; uu < 2; uu++) {
    int u = threadIdx.x + uu * 256;
    int c = u >> 2;
    int g = (u & 3) ^ ((c >> 1) & 3);
    uint4 o;
    o.x = pk2(t[g * 4 + 0][c], t[g * 4 + 1][c]);
    o.y = pk2(t[g * 4 + 2][c], t[g * 4 + 3][c]);
    o.z = pk2(t[16 + g * 4 + 0][c], t[16 + g * 4 + 1][c]);
    o.w = pk2(t[16 + g * 4 + 2][c], t[16 + g * 4 + 3][c]);
    *(uint4*)(outp + u * 16) = o;
  }
}

// ---------------------------------------------------------------------------
// bf16 MFMA GEMM, 128x128 tile, BK=32, 4 waves, depth-2 pipeline (3 LDS
// buffers, counted vmcnt(4)), XCD-pinned decode, T2 unit-XOR swizzle.
// EPI_GU consumes the interleaved g/u panel: acc[m][n] (n<2) = gate,
// acc[m][n+2] = up for the SAME logical cols -> h = silu(g)*u.
// ---------------------------------------------------------------------------
template<int EPI, bool EXPERT, int KSPLIT>
__global__ __launch_bounds__(256, 2)
void gemm2_k(const char* __restrict__ Abf, long strA,
             const char* __restrict__ Bp, long sBpan, int KTtot, int NCT,
             void* __restrict__ O, int ldKo,
             const int* __restrict__ cnt, const int* __restrict__ offs,
             const int* __restrict__ tokl, const float* __restrict__ wls,
             const float* __restrict__ sig)
{
  const int tid = threadIdx.x, lane = tid & 63, w = tid >> 6;
  const int wg = blockIdx.x;

  int e = 0, rt, ct, kc = 0, M = TKN;
  if (EXPERT) {
    e = wg & 7; int q = wg >> 3; rt = q & 15; ct = q >> 4;
    M = cnt[e];
    if (rt * 128 >= M) return;
  } else {
    rt = wg & 15; int q = wg >> 4; ct = q % NCT; kc = q / NCT;
  }
  const int KT = KTtot / KSPLIT;
  const int kt0 = kc * KT;
  const int obase = EXPERT ? offs[e] : 0;

  __shared__ int s_tok[128];
  __shared__ float s_w[128];
  __shared__ alignas(16) char Ab[3][8192];
  __shared__ alignas(16) char Bb[3][8192];

  if (EXPERT) {
    if (tid < 128) {
      int r = rt * 128 + tid;
      int rc = (r < M) ? r : (M - 1);
      s_tok[tid] = tokl[e * TKN + rc];
      if (EPI == EPI_DOWN) s_w[tid] = (r < M) ? wls[e * TKN + r] : 0.f;
    }
    __syncthreads();
  }

  // ---- staging addresses. A: wave w, issue i covers rows w*32+i*16+(lane>>2)
  // T2: lane (local row lr, unit u) fetches global frag unit u ^ ((lr>>1)&3).
  const int lrow0 = w * 32 + (lane >> 2);
  const int lrow1 = lrow0 + 16;
  auto rowbyte = [&](int rl) -> long {
    long gr;
    if (EPI == EPI_DOWN) { int r = rt * 128 + rl; gr = obase + ((r < M) ? r : (M - 1)); }
    else if (EXPERT)     { gr = s_tok[rl]; }
    else                 { gr = rt * 128 + rl; }
    return gr * strA;
  };
  const int au0 = (lane & 3) ^ ((lrow0 >> 1) & 3);
  const int au1 = (lane & 3) ^ ((lrow1 >> 1) & 3);
  const char* gA0 = Abf + rowbyte(lrow0) + (long)kt0 * 64 + au0 * 16;
  const char* gA1 = Abf + rowbyte(lrow1) + (long)kt0 * 64 + au1 * 16;
  const long bbase = (EXPERT ? (long)e * sBpan : 0) + ((long)ct * KTtot + kt0) * 8192
                     + w * 2048 + (long)lane * 16;
  const char* gB = Bp + bbase;

  auto stage = [&](int bf, int kt) {
    long ao = (long)kt * 64, bo = (long)kt * 8192;
    gll16(gA0 + ao, &Ab[bf][w * 2048]);
    gll16(gA1 + ao, &Ab[bf][w * 2048 + 1024]);
    gll16(gB + bo, &Bb[bf][w * 2048]);
    gll16(gB + bo + 1024, &Bb[bf][w * 2048 + 1024]);
  };

  // ---- fragment read offsets (T2: unit = g ^ ((row>>1)&3))
  const int wm = w >> 1, wn = w & 1, g = lane >> 4, l15 = lane & 15;
  int raOff[4], rbOff[4];
#pragma unroll
  for (int m = 0; m < 4; m++) {
    int row = wm * 64 + m * 16 + l15;
    raOff[m] = row * 64 + ((g ^ ((row >> 1) & 3)) << 4);
  }
#pragma unroll
  for (int n = 0; n < 4; n++) {
    int col = wn * 64 + n * 16 + l15;
    rbOff[n] = col * 64 + ((g ^ ((col >> 1) & 3)) << 4);
  }

  f32x4 acc[4][4] = {};

  // ---- depth-2 pipeline prologue: tiles 0 and 1 in flight
  stage(0, 0);
  stage(1, 1);

  int rd = 0;
#pragma unroll 1
  for (int kt = 0; kt < KT; ++kt) {
    // wait for tile kt only (tile kt+1's 4 loads stay in flight), T4-counted
    if (kt + 1 < KT) asm volatile("s_waitcnt vmcnt(4)" ::: "memory");
    else             asm volatile("s_waitcnt vmcnt(0)" ::: "memory");
    __builtin_amdgcn_s_barrier();
    __builtin_amdgcn_sched_barrier(0);

    bf16x8 av[4], bv[4];
#pragma unroll
    for (int m = 0; m < 4; m++) av[m] = *(const bf16x8*)&Ab[rd][raOff[m]];
#pragma unroll
    for (int n = 0; n < 4; n++) bv[n] = *(const bf16x8*)&Bb[rd][rbOff[n]];

    // stage tile kt+2 into the buffer read in iteration kt-1: (rd+2)%3
    int wr = rd + 2; if (wr >= 3) wr -= 3;
    if (kt + 2 < KT) stage(wr, kt + 2);

    __builtin_amdgcn_s_setprio(1);
#pragma unroll
    for (int m = 0; m < 4; m++)
#pragma unroll
      for (int n = 0; n < 4; n++)
        acc[m][n] = __builtin_amdgcn_mfma_f32_16x16x32_bf16(av[m], bv[n], acc[m][n], 0, 0, 0);
    __builtin_amdgcn_s_setprio(0);
    __builtin_amdgcn_sched_barrier(0);
    rd = (rd == 2) ? 0 : rd + 1;
  }

  // ---- epilogue. C/D frag: col = lane&15, row = (lane>>4)*4 + reg  [m89]
  if constexpr (EPI == EPI_GU) {
#pragma unroll
    for (int m = 0; m < 4; m++) {
#pragma unroll
      for (int n = 0; n < 2; n++) {
        int lc = ct * 64 + wn * 32 + n * 16 + l15;   // logical gu column
        f32x4 ga = acc[m][n];
        f32x4 ua = acc[m][n + 2];
#pragma unroll
        for (int q = 0; q < 4; q++) {
          int rl = wm * 64 + m * 16 + (g << 2) + q;
          int grow = rt * 128 + rl;
          if (!EXPERT || grow < M) {
            float gv = ga[q];
            float hv = (gv / (1.f + __expf(-gv))) * ua[q];
            long byteoff = (long)(obase + grow) * ((long)ldKo * 64)
                         + (lc >> 5) * 64 + ((lc >> 2) & 3) * 16
                         + ((lc & 16) >> 1) + (lc & 3) * 2;
            *(unsigned short*)((char*)O + byteoff) = f2bf(hv);
          }
        }
      }
    }
  } else {
#pragma unroll
    for (int m = 0; m < 4; m++) {
#pragma unroll
      for (int n = 0; n < 4; n++) {
        int col = ct * 128 + wn * 64 + n * 16 + l15;
        f32x4 a = acc[m][n];
#pragma unroll
        for (int q = 0; q < 4; q++) {
          int rl = wm * 64 + m * 16 + (g << 2) + q;
          int grow = rt * 128 + rl;
          float v = a[q];
          if constexpr (EPI == EPI_DOWN) {
            if (grow < M)
              atomicAdd((float*)O + (long)s_tok[rl] * DMODEL + col, s_w[rl] * v);
          } else {
            atomicAdd((float*)O + (long)grow * DMODEL + col, sig[grow] * v);
          }
        }
      }
    }
  }
}

// ---------------------------------------------------------------------------
// FALLBACK (ws too small): R1 reg-staged GEMM, fp32 sources.
// ---------------------------------------------------------------------------
__device__ __forceinline__ void block_sync_fb() {
  __builtin_amdgcn_sched_barrier(0);
  asm volatile("s_waitcnt lgkmcnt(0)" ::: "memory");
  __builtin_amdgcn_s_barrier();
  __builtin_amdgcn_sched_barrier(0);
}

template<int EPI, bool EXPERT, int KSPLIT>
__global__ __launch_bounds__(256, 2)
void gemm_fb_k(const float* __restrict__ A, int lda,
               const float* __restrict__ B, const float* __restrict__ B2,
               long sB, int ldb, int Ktot,
               float* __restrict__ O, int ldo,
               const int* __restrict__ cnt, const int* __restrict__ offs,
               const int* __restrict__ tokl, const float* __restrict__ wls,
               const float* __restrict__ sig)
{
  constexpr bool FUSED = (EPI == EPI_GU);
  const int tid = threadIdx.x;
  const int lane = tid & 63;

  int e = 0, rt, kc = 0, M = TKN;
  if (EXPERT) {
    e = blockIdx.y >> 4; rt = blockIdx.y & 15;
    M = cnt[e];
    if (rt * 128 >= M) return;
  } else {
    rt = blockIdx.y & 15; kc = blockIdx.y >> 4;
  }
  const int K = Ktot / KSPLIT;
  const int koff = kc * K;
  const int colblk = blockIdx.x * 128;
  const float* Bp  = B + (EXPERT ? (long)e * sB : 0);
  const float* Bp2 = FUSED ? (B2 + (EXPERT ? (long)e * sB : 0)) : nullptr;
  const int obase = EXPERT ? offs[e] : 0;

  __shared__ alignas(16) unsigned char Ab[8192];
  __shared__ alignas(16) unsigned char Bb[8192];
  __shared__ alignas(16) unsigned char Bb2[FUSED ? 8192 : 16];
  __shared__ int s_tok[128];
  __shared__ float s_w[128];

  if (EXPERT && tid < 128) {
    int r = rt * 128 + tid;
    int rc = (r < M) ? r : (M - 1);
    s_tok[tid] = tokl[e * TKN + rc];
    if (EPI == EPI_DOWN) s_w[tid] = (r < M) ? wls[e * TKN + r] : 0.f;
  }
  if (EXPERT) __syncthreads();

  const int arowl = tid >> 1;
  const int ahalf = tid & 1;
  long arow;
  if (EPI == EPI_DOWN) {
    int r = rt * 128 + arowl;
    arow = (long)obase + ((r < M) ? r : (M - 1));
  } else if (EXPERT) {
    arow = s_tok[arowl];
  } else {
    arow = rt * 128 + arowl;
  }
  const float* aptr = A + arow * (long)lda + koff + ahalf * 16;
  int wa[4];
#pragma unroll
  for (int j = 0; j < 4; j++)
    wa[j] = arowl * 64 + ((j ^ ((arowl ^ (arowl >> 3)) & 3)) << 4) + ahalf * 8;

  const int kg = tid >> 5, ng = tid & 31;
  const float* bptr  = Bp + (long)(koff + kg * 4) * ldb + colblk + ng * 4;
  const float* bptr2 = FUSED ? (Bp2 + (long)(koff + kg * 4) * ldb + colblk + ng * 4) : nullptr;
  int wb[4];
#pragma unroll
  for (int i = 0; i < 4; i++) {
    int c = ng * 4 + i;
    wb[i] = c * 64 + ((((kg & 3) ^ ((c ^ (c >> 3)) & 3))) << 4) + (kg >> 2) * 8;
  }

  const int wid = tid >> 6, wm = wid >> 1, wn = wid & 1;
  const int g = lane >> 4, l15 = lane & 15;
  int ra[4], rb[4];
#pragma unroll
  for (int m = 0; m < 4; m++) {
    int r = wm * 64 + m * 16 + l15;
    ra[m] = r * 64 + ((g ^ ((r ^ (r >> 3)) & 3)) << 4);
  }
#pragma unroll
  for (int n = 0; n < 4; n++) {
    int c = wn * 64 + n * 16 + l15;
    rb[n] = c * 64 + ((g ^ ((c ^ (c >> 3)) & 3)) << 4);
  }

  f32x4 acc[4][4] = {};
  f32x4 acc2[4][4] = {};

  const int KT = K >> 5;
  float4 ta0[4], tb0[4], tc0[4], ta1[4], tb1[4], tc1[4];

  auto load_tile = [&](float4* ra_, float4* rb_, float4* rc_, int kt) {
    const float4* a4 = reinterpret_cast<const float4*>(aptr + kt * 32);
    ra_[0] = a4[0]; ra_[1] = a4[1]; ra_[2] = a4[2]; ra_[3] = a4[3];
    const float* bb = bptr + (long)kt * 32 * ldb;
    rb_[0] = *reinterpret_cast<const float4*>(bb);
    rb_[1] = *reinterpret_cast<const float4*>(bb + ldb);
    rb_[2] = *reinterpret_cast<const float4*>(bb + 2 * ldb);
    rb_[3] = *reinterpret_cast<const float4*>(bb + 3 * ldb);
    if (FUSED) {
      const float* cc = bptr2 + (long)kt * 32 * ldb;
      rc_[0] = *reinterpret_cast<const float4*>(cc);
      rc_[1] = *reinterpret_cast<const float4*>(cc + ldb);
      rc_[2] = *reinterpret_cast<const float4*>(cc + 2 * ldb);
      rc_[3] = *reinterpret_cast<const float4*>(cc + 3 * ldb);
    }
  };

  auto store_tile = [&](const float4* ra_, const float4* rb_, const float4* rc_) {
#pragma unroll
    for (int j = 0; j < 4; j++)
      *reinterpret_cast<uint2*>(Ab + wa[j]) =
          make_uint2(pk2(ra_[j].x, ra_[j].y), pk2(ra_[j].z, ra_[j].w));
    *reinterpret_cast<uint2*>(Bb + wb[0]) = make_uint2(pk2(rb_[0].x, rb_[1].x), pk2(rb_[2].x, rb_[3].x));
    *reinterpret_cast<uint2*>(Bb + wb[1]) = make_uint2(pk2(rb_[0].y, rb_[1].y), pk2(rb_[2].y, rb_[3].y));
    *reinterpret_cast<uint2*>(Bb + wb[2]) = make_uint2(pk2(rb_[0].z, rb_[1].z), pk2(rb_[2].z, rb_[3].z));
    *reinterpret_cast<uint2*>(Bb + wb[3]) = make_uint2(pk2(rb_[0].w, rb_[1].w), pk2(rb_[2].w, rb_[3].w));
    if (FUSED) {
      *reinterpret_cast<uint2*>(Bb2 + wb[0]) = make_uint2(pk2(rc_[0].x, rc_[1].x), pk2(rc_[2].x, rc_[3].x));
      *reinterpret_cast<uint2*>(Bb2 + wb[1]) = make_uint2(pk2(rc_[0].y, rc_[1].y), pk2(rc_[2].y, rc_[3].y));
      *reinterpret_cast<uint2*>(Bb2 + wb[2]) = make_uint2(pk2(rc_[0].z, rc_[1].z), pk2(rc_[2].z, rc_[3].z));
      *reinterpret_cast<uint2*>(Bb2 + wb[3]) = make_uint2(pk2(rc_[0].w, rc_[1].w), pk2(rc_[2].w, rc_[3].w));
    }
  };

  auto mfma_step = [&]() {
    bf16x8 av[4], bvg[4], bvu[4];
#pragma unroll
    for (int m = 0; m < 4; m++) av[m] = *reinterpret_cast<const bf16x8*>(Ab + ra[m]);
#pragma unroll
    for (int n = 0; n < 4; n++) {
      bvg[n] = *reinterpret_cast<const bf16x8*>(Bb + rb[n]);
      if (FUSED) bvu[n] = *reinterpret_cast<const bf16x8*>(Bb2 + rb[n]);
    }
#pragma unroll
    for (int m = 0; m < 4; m++)
#pragma unroll
      for (int n = 0; n < 4; n++) {
        acc[m][n] = __builtin_amdgcn_mfma_f32_16x16x32_bf16(av[m], bvg[n], acc[m][n], 0, 0, 0);
        if (FUSED)
          acc2[m][n] = __builtin_amdgcn_mfma_f32_16x16x32_bf16(av[m], bvu[n], acc2[m][n], 0, 0, 0);
      }
  };

  load_tile(ta0, tb0, tc0, 0);
#pragma unroll 1
  for (int kt = 0; kt < KT; kt += 2) {
    load_tile(ta1, tb1, tc1, kt + 1);
    store_tile(ta0, tb0, tc0);
    block_sync_fb();
    mfma_step();
    block_sync_fb();
    int k2 = (kt + 2 < KT) ? kt + 2 : 0;
    load_tile(ta0, tb0, tc0, k2);
    store_tile(ta1, tb1, tc1);
    block_sync_fb();
    mfma_step();
    block_sync_fb();
  }

#pragma unroll
  for (int m = 0; m < 4; m++) {
#pragma unroll
    for (int n = 0; n < 4; n++) {
      int col = colblk + wn * 64 + n * 16 + l15;
      f32x4 a = acc[m][n];
      f32x4 a2 = acc2[m][n];
#pragma unroll
      for (int q = 0; q < 4; q++) {
        int rl = wm * 64 + m * 16 + (g << 2) + q;
        int grow = rt * 128 + rl;
        float v = a[q];
        if (EPI == EPI_GU) {
          if (!EXPERT || grow < M) {
            float hv = (v / (1.f + __expf(-v))) * a2[q];
            O[(long)(obase + grow) * ldo + col] = hv;
          }
        } else if (EPI == EPI_DOWN) {
          if (grow < M)
            atomicAdd(&O[(long)s_tok[rl] * ldo + col], s_w[rl] * v);
        } else {
          atomicAdd(&O[(long)grow * ldo + col], sig[grow] * v);
        }
      }
    }
  }
}

// ---------------------------------------------------------------------------
extern "C" void kernel_launch(void* const* d_in, const int* in_sizes, int n_in,
                              void* d_out, int out_size, void* d_ws, size_t ws_size,
                              hipStream_t stream)
{
  (void)in_sizes; (void)n_in; (void)out_size;
  const float* x   = (const float*)d_in[0];
  const float* gw  = (const float*)d_in[1];
  const float* Wg  = (const float*)d_in[2];
  const float* Wu  = (const float*)d_in[3];
  const float* Wd  = (const float*)d_in[4];
  const float* Wsg = (const float*)d_in[5];
  const float* Wsu = (const float*)d_in[6];
  const float* Wsd = (const float*)d_in[7];
  const float* sgw = (const float*)d_in[8];

  float* out    = (float*)d_out;
  float* logits = out + (long)TKN * DMODEL;

  char* w    = (char*)d_ws;
  int*  cnt  = (int*)w;
  int*  offs = (int*)(w + 64);
  float* sig = (float*)(w + 1024);
  int*  tokl = (int*)(w + 16384);
  float* wls = (float*)(w + 81920);

  hipMemsetAsync(out, 0, (size_t)TKN * DMODEL * 4, stream);
  hipMemsetAsync(cnt, 0, 64, stream);

  router_k<<<dim3(TKN / 4), 256, 0, stream>>>(x, gw, sgw, logits, sig, cnt, tokl, wls);
  scan_k<<<1, 64, 0, stream>>>(cnt, offs);

  const size_t NEED = 241172480ull;   // 230 MB (proven to fit in R2-R4)
  if (ws_size >= NEED) {
    char* xbf     = w + 262144;            // 8 MB frag-packed x rows (stride 4096 B)
    char* h       = w + 8650752;           // 23 MB bf16 (ex ldK=44 / sh ldK=176, reused)
    char* panGUex = w + 33554432;          // 8 x 11534336 = 92.3 MB (g/u interleaved)
    char* panWd   = w + 125829120;         // 8 x 5767168 = 46.1 MB
    char* panGUsh = w + 171966464;         // 46.1 MB (g/u interleaved)
    char* panWsd  = w + 218103808;         // 23.1 MB -> ends 241172480
    const long sPanGU = 11534336;
    const long sPanWd = 5767168;

    cvt_x_k<<<dim3(2048), 256, 0, stream>>>(x, xbf);
    // expert gate+up interleaved panel: 22 phys col-tiles x 64 kt x 8 experts
    cvt_gu_k<<<dim3(22, 64, 8), 256, 0, stream>>>(Wg, Wu, (long)DMODEL * FEXP, FEXP, panGUex, sPanGU);
    cvt_w_k<<<dim3(16, 44, 8), 256, 0, stream>>>(Wd, (long)FEXP * DMODEL, DMODEL, panWd, sPanWd);
    cvt_gu_k<<<dim3(88, 64, 1), 256, 0, stream>>>(Wsg, Wsu, 0, FSH, panGUsh, 0);
    cvt_w_k<<<dim3(16, 176, 1), 256, 0, stream>>>(Wsd, 0, DMODEL, panWsd, 0);

    // expert fused gate+up -> h (bf16, ldK=44). e=wg&7, rt=(wg>>3)&15, ct=wg>>7 (<22)
    gemm2_k<EPI_GU, true, 1><<<dim3(8 * 16 * 22), 256, 0, stream>>>(
        xbf, 4096, panGUex, sPanGU, 64, 22, h, 44, cnt, offs, tokl, wls, nullptr);
    // expert down -> out (atomic fp32)
    gemm2_k<EPI_DOWN, true, 1><<<dim3(8 * 16 * 16), 256, 0, stream>>>(
        h, 2816, panWd, sPanWd, 44, 16, out, 0, cnt, offs, tokl, wls, nullptr);
    // shared fused gate+up -> h (bf16, ldK=176), rt-fastest
    gemm2_k<EPI_GU, false, 1><<<dim3(16 * 88), 256, 0, stream>>>(
        xbf, 4096, panGUsh, 0, 64, 88, h, 176, nullptr, nullptr, nullptr, nullptr, nullptr);
    // shared down, split-K=4 -> out (atomic fp32)
    gemm2_k<EPI_SDOWN, false, 4><<<dim3(16 * 16 * 4), 256, 0, stream>>>(
        h, 11264, panWsd, 0, 176, 16, out, 0, nullptr, nullptr, nullptr, nullptr, sig);
  } else {
    // fallback: R1 path (fp32 reg-staged GEMMs)
    float* h = (float*)(w + (1 << 20));
    gemm_fb_k<EPI_GU, true, 1><<<dim3(FEXP / 128, 128), 256, 0, stream>>>(
        x, DMODEL, Wg, Wu, (long)DMODEL * FEXP, FEXP, DMODEL, h, FEXP, cnt, offs, tokl, wls, nullptr);
    gemm_fb_k<EPI_DOWN, true, 1><<<dim3(DMODEL / 128, 128), 256, 0, stream>>>(
        h, FEXP, Wd, nullptr, (long)FEXP * DMODEL, DMODEL, FEXP, out, DMODEL, cnt, offs, tokl, wls, nullptr);
    gemm_fb_k<EPI_GU, false, 1><<<dim3(FSH / 128, TKN / 128), 256, 0, stream>>>(
        x, DMODEL, Wsg, Wsu, 0, FSH, DMODEL, h, FSH, nullptr, nullptr, nullptr, nullptr, nullptr);
    gemm_fb_k<EPI_SDOWN, false, 4><<<dim3(DMODEL / 128, (TKN / 128) * 4), 256, 0, stream>>>(
        h, FSH, Wsd, nullptr, 0, DMODEL, FSH, out, DMODEL, nullptr, nullptr, nullptr, nullptr, sig);
  }
}

// Round 7
// 678.687 us; speedup vs baseline: 1.8413x; 1.0052x over previous
//
#include <hip/hip_runtime.h>
#include <hip/hip_bf16.h>

typedef __attribute__((ext_vector_type(8))) __bf16 bf16x8;
typedef __attribute__((ext_vector_type(4))) float f32x4;

#define TKN 2048
#define DMODEL 2048
#define NEXP 8
#define FEXP 1408
#define FSH 5632

__device__ __forceinline__ unsigned short f2bf(float f) {
  unsigned u = __float_as_uint(f);
  u += 0x7FFFu + ((u >> 16) & 1u);          // round-to-nearest-even
  return (unsigned short)(u >> 16);
}
__device__ __forceinline__ unsigned pk2(float a, float b) {
  return (unsigned)f2bf(a) | ((unsigned)f2bf(b) << 16);
}

// global -> LDS direct copy, 16B per lane. LDS dest must be wave-uniform.
__device__ __forceinline__ void gll16(const void* g, void* l) {
  __builtin_amdgcn_global_load_lds(
      (const __attribute__((address_space(1))) unsigned*)g,
      (__attribute__((address_space(3))) unsigned*)l, 16, 0, 0);
}

enum { EPI_GU = 0, EPI_DOWN = 1, EPI_SDOWN = 2 };

// ---------------------------------------------------------------------------
// Router (fp32-exact logits path) + top-4 + per-expert token lists.
// ---------------------------------------------------------------------------
__global__ __launch_bounds__(256)
void router_k(const float* __restrict__ x, const float* __restrict__ gw,
              const float* __restrict__ sgw, float* __restrict__ logits,
              float* __restrict__ sig, int* __restrict__ cnt,
              int* __restrict__ tokl, float* __restrict__ wls)
{
  const int wv = threadIdx.x >> 6, lane = threadIdx.x & 63;
  const int t = blockIdx.x * 4 + wv;
  const float* xr = x + (long)t * DMODEL;
  float xv[32];
#pragma unroll
  for (int j = 0; j < 32; j++) xv[j] = xr[lane + (j << 6)];

  float lg[8];
#pragma unroll
  for (int e = 0; e < 8; e++) {
    const float* gr = gw + (long)e * DMODEL;
    float acc = 0.f;
#pragma unroll
    for (int j = 0; j < 32; j++) acc += xv[j] * gr[lane + (j << 6)];
#pragma unroll
    for (int s = 1; s < 64; s <<= 1) acc += __shfl_xor(acc, s, 64);
    lg[e] = acc;
  }
  float sgacc = 0.f;
#pragma unroll
  for (int j = 0; j < 32; j++) sgacc += xv[j] * sgw[lane + (j << 6)];
#pragma unroll
  for (int s = 1; s < 64; s <<= 1) sgacc += __shfl_xor(sgacc, s, 64);

  if (lane == 0) {
    float mx = lg[0];
#pragma unroll
    for (int e = 1; e < 8; e++) mx = fmaxf(mx, lg[e]);
    float p[8], se = 0.f;
#pragma unroll
    for (int e = 0; e < 8; e++) { p[e] = expf(lg[e] - mx); se += p[e]; }
    float inv = 1.f / se;
#pragma unroll
    for (int e = 0; e < 8; e++) { p[e] *= inv; logits[t * 8 + e] = lg[e]; }
    sig[t] = 1.f / (1.f + expf(-sgacc));
#pragma unroll
    for (int k = 0; k < 4; k++) {
      int bi = 0; float bv = p[0];
#pragma unroll
      for (int e = 1; e < 8; e++) if (p[e] > bv) { bv = p[e]; bi = e; }
      p[bi] = -1.f;
      int pos = atomicAdd(&cnt[bi], 1);
      tokl[bi * TKN + pos] = t;
      wls[bi * TKN + pos] = bv;
    }
  }
}

__global__ void scan_k(const int* __restrict__ cnt, int* __restrict__ offs) {
  if (threadIdx.x == 0) {
    int s = 0;
    for (int e = 0; e < 8; e++) { offs[e] = s; s += cnt[e]; }
    offs[8] = s;
  }
}

// ---------------------------------------------------------------------------
// x fp32 [2048][2048] -> fragment-packed bf16 rows: per row, unit u=kt*4+j
// (16B) holds k = {kt*32+j*4+0..3, kt*32+16+j*4+0..3}. Row stride 4096 B.
// ---------------------------------------------------------------------------
__global__ __launch_bounds__(256)
void cvt_x_k(const float* __restrict__ x, char* __restrict__ xbf)
{
  long id = (long)blockIdx.x * 256 + threadIdx.x;   // 524288 total
  int row = id >> 8, u = id & 255, kt = u >> 2, j = u & 3;
  const float* p = x + (long)row * 2048 + kt * 32 + j * 4;
  float4 a = *(const float4*)p;
  float4 b = *(const float4*)(p + 16);
  uint4 o;
  o.x = pk2(a.x, a.y); o.y = pk2(a.z, a.w);
  o.z = pk2(b.x, b.y); o.w = pk2(b.z, b.w);
  *(uint4*)(xbf + id * 16) = o;
}

// ---------------------------------------------------------------------------
// Plain weight fp32 [K][N] -> bf16 panel of 8KB tiles, tile (ct,kt) at
// ((ct*KT)+kt)*8192. Position u = c*4+up holds frag unit g = up^((c>>1)&3)
// (T2 swizzle pre-baked). Frag unit g of col c = B[kt*32+g*4+{0..3}][c] then
// B[kt*32+16+g*4+{0..3}][c].
// ---------------------------------------------------------------------------
__global__ __launch_bounds__(256)
void cvt_w_k(const float* __restrict__ W, long sB, int N,
             char* __restrict__ panel, long panStride)
{
  const int ct = blockIdx.x, kt = blockIdx.y, e = blockIdx.z, KT = gridDim.y;
  const float* Wp = W + (long)e * sB + (long)(kt * 32) * N + ct * 128;
  __shared__ float t[32][128];
  const int r = threadIdx.x >> 3, q = threadIdx.x & 7;
  const float* rp = Wp + (long)r * N + q * 16;
  float4 f0 = *(const float4*)(rp + 0);
  float4 f1 = *(const float4*)(rp + 4);
  float4 f2 = *(const float4*)(rp + 8);
  float4 f3 = *(const float4*)(rp + 12);
  *(float4*)&t[r][q * 16 + 0]  = f0;
  *(float4*)&t[r][q * 16 + 4]  = f1;
  *(float4*)&t[r][q * 16 + 8]  = f2;
  *(float4*)&t[r][q * 16 + 12] = f3;
  __syncthreads();
  char* outp = panel + e * panStride + ((long)ct * KT + kt) * 8192;
#pragma unroll
  for (int uu = 0; uu < 2; uu++) {
    int u = threadIdx.x + uu * 256;
    int c = u >> 2;
    int g = (u & 3) ^ ((c >> 1) & 3);
    uint4 o;
    o.x = pk2(t[g * 4 + 0][c], t[g * 4 + 1][c]);
    o.y = pk2(t[g * 4 + 2][c], t[g * 4 + 3][c]);
    o.z = pk2(t[16 + g * 4 + 0][c], t[16 + g * 4 + 1][c]);
    o.w = pk2(t[16 + g * 4 + 2][c], t[16 + g * 4 + 3][c]);
    *(uint4*)(outp + u * 16) = o;
  }
}

// ---------------------------------------------------------------------------
// GU combined panel: interleaves Wg/Wu columns at 32-col granularity.
// Physical 128-col tile ct covers LOGICAL cols [ct*64, ct*64+64):
//   phys p: matrix = (p>>5)&1 (0=gate,1=up), logical col = ct*64+((p>>6)<<5)+(p&31).
// Same 8KB-tile packing + T2 swizzle as cvt_w_k.
// ---------------------------------------------------------------------------
__global__ __launch_bounds__(256)
void cvt_gu_k(const float* __restrict__ Wg, const float* __restrict__ Wu,
              long sB, int N, char* __restrict__ panel, long panStride)
{
  const int ct = blockIdx.x, kt = blockIdx.y, e = blockIdx.z, KT = gridDim.y;
  __shared__ float t[32][128];
  const int r = threadIdx.x >> 3, q = threadIdx.x & 7;
  const float* src = ((q >> 1) & 1) ? Wu : Wg;
  const int scol = ct * 64 + ((q >> 2) << 5) + ((q & 1) << 4);
  const float* rp = src + (long)e * sB + (long)(kt * 32 + r) * N + scol;
  float4 f0 = *(const float4*)(rp + 0);
  float4 f1 = *(const float4*)(rp + 4);
  float4 f2 = *(const float4*)(rp + 8);
  float4 f3 = *(const float4*)(rp + 12);
  *(float4*)&t[r][q * 16 + 0]  = f0;
  *(float4*)&t[r][q * 16 + 4]  = f1;
  *(float4*)&t[r][q * 16 + 8]  = f2;
  *(float4*)&t[r][q * 16 + 12] = f3;
  __syncthreads();
  char* outp = panel + e * panStride + ((long)ct * KT + kt) * 8192;
#pragma unroll
  for (int uu = 0; uu < 2; uu++) {
    int u = threadIdx.x + uu * 256;
    int c = u >> 2;
    int g = (u & 3) ^ ((c >> 1) & 3);
    uint4 o;
    o.x = pk2(t[g * 4 + 0][c], t[g * 4 + 1][c]);
    o.y = pk2(t[g * 4 + 2][c], t[g * 4 + 3][c]);
    o.z = pk2(t[16 + g * 4 + 0][c], t[16 + g * 4 + 1][c]);
    o.w = pk2(t[16 + g * 4 + 2][c], t[16 + g * 4 + 3][c]);
    *(uint4*)(outp + u * 16) = o;
  }
}

// ---------------------------------------------------------------------------
// bf16 MFMA GEMM, 128x128 tile, BK=32, 4 waves, depth-2 pipeline (3 LDS
// buffers, counted vmcnt(4)), XCD-pinned decode, T2 unit-XOR swizzle.
// EPI_GU consumes the interleaved g/u panel: acc[m][n] (n<2) = gate,
// acc[m][n+2] = up for the SAME logical cols -> h = silu(g)*u.
// ---------------------------------------------------------------------------
template<int EPI, bool EXPERT, int KSPLIT>
__global__ __launch_bounds__(256, 2)
void gemm2_k(const char* __restrict__ Abf, long strA,
             const char* __restrict__ Bp, long sBpan, int KTtot, int NCT,
             void* __restrict__ O, int ldKo,
             const int* __restrict__ cnt, const int* __restrict__ offs,
             const int* __restrict__ tokl, const float* __restrict__ wls,
             const float* __restrict__ sig)
{
  const int tid = threadIdx.x, lane = tid & 63, w = tid >> 6;
  const int wg = blockIdx.x;

  int e = 0, rt, ct, kc = 0, M = TKN;
  if (EXPERT) {
    e = wg & 7; int q = wg >> 3; rt = q & 15; ct = q >> 4;
    M = cnt[e];
    if (rt * 128 >= M) return;
  } else {
    rt = wg & 15; int q = wg >> 4; ct = q % NCT; kc = q / NCT;
  }
  const int KT = KTtot / KSPLIT;
  const int kt0 = kc * KT;
  const int obase = EXPERT ? offs[e] : 0;

  __shared__ int s_tok[128];
  __shared__ float s_w[128];
  __shared__ alignas(16) char Ab[3][8192];
  __shared__ alignas(16) char Bb[3][8192];

  if (EXPERT) {
    if (tid < 128) {
      int r = rt * 128 + tid;
      int rc = (r < M) ? r : (M - 1);
      s_tok[tid] = tokl[e * TKN + rc];
      if (EPI == EPI_DOWN) s_w[tid] = (r < M) ? wls[e * TKN + r] : 0.f;
    }
    __syncthreads();
  }

  // ---- staging addresses. A: wave w, issue i covers rows w*32+i*16+(lane>>2)
  // T2: lane (local row lr, unit u) fetches global frag unit u ^ ((lr>>1)&3).
  const int lrow0 = w * 32 + (lane >> 2);
  const int lrow1 = lrow0 + 16;
  auto rowbyte = [&](int rl) -> long {
    long gr;
    if (EPI == EPI_DOWN) { int r = rt * 128 + rl; gr = obase + ((r < M) ? r : (M - 1)); }
    else if (EXPERT)     { gr = s_tok[rl]; }
    else                 { gr = rt * 128 + rl; }
    return gr * strA;
  };
  const int au0 = (lane & 3) ^ ((lrow0 >> 1) & 3);
  const int au1 = (lane & 3) ^ ((lrow1 >> 1) & 3);
  const char* gA0 = Abf + rowbyte(lrow0) + (long)kt0 * 64 + au0 * 16;
  const char* gA1 = Abf + rowbyte(lrow1) + (long)kt0 * 64 + au1 * 16;
  const long bbase = (EXPERT ? (long)e * sBpan : 0) + ((long)ct * KTtot + kt0) * 8192
                     + w * 2048 + (long)lane * 16;
  const char* gB = Bp + bbase;

  auto stage = [&](int bf, int kt) {
    long ao = (long)kt * 64, bo = (long)kt * 8192;
    gll16(gA0 + ao, &Ab[bf][w * 2048]);
    gll16(gA1 + ao, &Ab[bf][w * 2048 + 1024]);
    gll16(gB + bo, &Bb[bf][w * 2048]);
    gll16(gB + bo + 1024, &Bb[bf][w * 2048 + 1024]);
  };

  // ---- fragment read offsets (T2: unit = g ^ ((row>>1)&3))
  const int wm = w >> 1, wn = w & 1, g = lane >> 4, l15 = lane & 15;
  int raOff[4], rbOff[4];
#pragma unroll
  for (int m = 0; m < 4; m++) {
    int row = wm * 64 + m * 16 + l15;
    raOff[m] = row * 64 + ((g ^ ((row >> 1) & 3)) << 4);
  }
#pragma unroll
  for (int n = 0; n < 4; n++) {
    int col = wn * 64 + n * 16 + l15;
    rbOff[n] = col * 64 + ((g ^ ((col >> 1) & 3)) << 4);
  }

  f32x4 acc[4][4] = {};

  // ---- depth-2 pipeline prologue: tiles 0 and 1 in flight
  stage(0, 0);
  stage(1, 1);

  int rd = 0;
#pragma unroll 1
  for (int kt = 0; kt < KT; ++kt) {
    // wait for tile kt only (tile kt+1's 4 loads stay in flight), T4-counted
    if (kt + 1 < KT) asm volatile("s_waitcnt vmcnt(4)" ::: "memory");
    else             asm volatile("s_waitcnt vmcnt(0)" ::: "memory");
    __builtin_amdgcn_s_barrier();
    __builtin_amdgcn_sched_barrier(0);

    bf16x8 av[4], bv[4];
#pragma unroll
    for (int m = 0; m < 4; m++) av[m] = *(const bf16x8*)&Ab[rd][raOff[m]];
#pragma unroll
    for (int n = 0; n < 4; n++) bv[n] = *(const bf16x8*)&Bb[rd][rbOff[n]];

    // stage tile kt+2 into the buffer read in iteration kt-1: (rd+2)%3
    int wr = rd + 2; if (wr >= 3) wr -= 3;
    if (kt + 2 < KT) stage(wr, kt + 2);

    __builtin_amdgcn_s_setprio(1);
#pragma unroll
    for (int m = 0; m < 4; m++)
#pragma unroll
      for (int n = 0; n < 4; n++)
        acc[m][n] = __builtin_amdgcn_mfma_f32_16x16x32_bf16(av[m], bv[n], acc[m][n], 0, 0, 0);
    __builtin_amdgcn_s_setprio(0);
    __builtin_amdgcn_sched_barrier(0);
    rd = (rd == 2) ? 0 : rd + 1;
  }

  // ---- epilogue. C/D frag: col = lane&15, row = (lane>>4)*4 + reg  [m89]
  if constexpr (EPI == EPI_GU) {
#pragma unroll
    for (int m = 0; m < 4; m++) {
#pragma unroll
      for (int n = 0; n < 2; n++) {
        int lc = ct * 64 + wn * 32 + n * 16 + l15;   // logical gu column
        f32x4 ga = acc[m][n];
        f32x4 ua = acc[m][n + 2];
#pragma unroll
        for (int q = 0; q < 4; q++) {
          int rl = wm * 64 + m * 16 + (g << 2) + q;
          int grow = rt * 128 + rl;
          if (!EXPERT || grow < M) {
            float gv = ga[q];
            float hv = (gv / (1.f + __expf(-gv))) * ua[q];
            long byteoff = (long)(obase + grow) * ((long)ldKo * 64)
                         + (lc >> 5) * 64 + ((lc >> 2) & 3) * 16
                         + ((lc & 16) >> 1) + (lc & 3) * 2;
            *(unsigned short*)((char*)O + byteoff) = f2bf(hv);
          }
        }
      }
    }
  } else {
#pragma unroll
    for (int m = 0; m < 4; m++) {
#pragma unroll
      for (int n = 0; n < 4; n++) {
        int col = ct * 128 + wn * 64 + n * 16 + l15;
        f32x4 a = acc[m][n];
#pragma unroll
        for (int q = 0; q < 4; q++) {
          int rl = wm * 64 + m * 16 + (g << 2) + q;
          int grow = rt * 128 + rl;
          float v = a[q];
          if constexpr (EPI == EPI_DOWN) {
            if (grow < M)
              atomicAdd((float*)O + (long)s_tok[rl] * DMODEL + col, s_w[rl] * v);
          } else {
            atomicAdd((float*)O + (long)grow * DMODEL + col, sig[grow] * v);
          }
        }
      }
    }
  }
}

// ---------------------------------------------------------------------------
// FALLBACK (ws too small): R1 reg-staged GEMM, fp32 sources.
// ---------------------------------------------------------------------------
__device__ __forceinline__ void block_sync_fb() {
  __builtin_amdgcn_sched_barrier(0);
  asm volatile("s_waitcnt lgkmcnt(0)" ::: "memory");
  __builtin_amdgcn_s_barrier();
  __builtin_amdgcn_sched_barrier(0);
}

template<int EPI, bool EXPERT, int KSPLIT>
__global__ __launch_bounds__(256, 2)
void gemm_fb_k(const float* __restrict__ A, int lda,
               const float* __restrict__ B, const float* __restrict__ B2,
               long sB, int ldb, int Ktot,
               float* __restrict__ O, int ldo,
               const int* __restrict__ cnt, const int* __restrict__ offs,
               const int* __restrict__ tokl, const float* __restrict__ wls,
               const float* __restrict__ sig)
{
  constexpr bool FUSED = (EPI == EPI_GU);
  const int tid = threadIdx.x;
  const int lane = tid & 63;

  int e = 0, rt, kc = 0, M = TKN;
  if (EXPERT) {
    e = blockIdx.y >> 4; rt = blockIdx.y & 15;
    M = cnt[e];
    if (rt * 128 >= M) return;
  } else {
    rt = blockIdx.y & 15; kc = blockIdx.y >> 4;
  }
  const int K = Ktot / KSPLIT;
  const int koff = kc * K;
  const int colblk = blockIdx.x * 128;
  const float* Bp  = B + (EXPERT ? (long)e * sB : 0);
  const float* Bp2 = FUSED ? (B2 + (EXPERT ? (long)e * sB : 0)) : nullptr;
  const int obase = EXPERT ? offs[e] : 0;

  __shared__ alignas(16) unsigned char Ab[8192];
  __shared__ alignas(16) unsigned char Bb[8192];
  __shared__ alignas(16) unsigned char Bb2[FUSED ? 8192 : 16];
  __shared__ int s_tok[128];
  __shared__ float s_w[128];

  if (EXPERT && tid < 128) {
    int r = rt * 128 + tid;
    int rc = (r < M) ? r : (M - 1);
    s_tok[tid] = tokl[e * TKN + rc];
    if (EPI == EPI_DOWN) s_w[tid] = (r < M) ? wls[e * TKN + r] : 0.f;
  }
  if (EXPERT) __syncthreads();

  const int arowl = tid >> 1;
  const int ahalf = tid & 1;
  long arow;
  if (EPI == EPI_DOWN) {
    int r = rt * 128 + arowl;
    arow = (long)obase + ((r < M) ? r : (M - 1));
  } else if (EXPERT) {
    arow = s_tok[arowl];
  } else {
    arow = rt * 128 + arowl;
  }
  const float* aptr = A + arow * (long)lda + koff + ahalf * 16;
  int wa[4];
#pragma unroll
  for (int j = 0; j < 4; j++)
    wa[j] = arowl * 64 + ((j ^ ((arowl ^ (arowl >> 3)) & 3)) << 4) + ahalf * 8;

  const int kg = tid >> 5, ng = tid & 31;
  const float* bptr  = Bp + (long)(koff + kg * 4) * ldb + colblk + ng * 4;
  const float* bptr2 = FUSED ? (Bp2 + (long)(koff + kg * 4) * ldb + colblk + ng * 4) : nullptr;
  int wb[4];
#pragma unroll
  for (int i = 0; i < 4; i++) {
    int c = ng * 4 + i;
    wb[i] = c * 64 + ((((kg & 3) ^ ((c ^ (c >> 3)) & 3))) << 4) + (kg >> 2) * 8;
  }

  const int wid = tid >> 6, wm = wid >> 1, wn = wid & 1;
  const int g = lane >> 4, l15 = lane & 15;
  int ra[4], rb[4];
#pragma unroll
  for (int m = 0; m < 4; m++) {
    int r = wm * 64 + m * 16 + l15;
    ra[m] = r * 64 + ((g ^ ((r ^ (r >> 3)) & 3)) << 4);
  }
#pragma unroll
  for (int n = 0; n < 4; n++) {
    int c = wn * 64 + n * 16 + l15;
    rb[n] = c * 64 + ((g ^ ((c ^ (c >> 3)) & 3)) << 4);
  }

  f32x4 acc[4][4] = {};
  f32x4 acc2[4][4] = {};

  const int KT = K >> 5;
  float4 ta0[4], tb0[4], tc0[4], ta1[4], tb1[4], tc1[4];

  auto load_tile = [&](float4* ra_, float4* rb_, float4* rc_, int kt) {
    const float4* a4 = reinterpret_cast<const float4*>(aptr + kt * 32);
    ra_[0] = a4[0]; ra_[1] = a4[1]; ra_[2] = a4[2]; ra_[3] = a4[3];
    const float* bb = bptr + (long)kt * 32 * ldb;
    rb_[0] = *reinterpret_cast<const float4*>(bb);
    rb_[1] = *reinterpret_cast<const float4*>(bb + ldb);
    rb_[2] = *reinterpret_cast<const float4*>(bb + 2 * ldb);
    rb_[3] = *reinterpret_cast<const float4*>(bb + 3 * ldb);
    if (FUSED) {
      const float* cc = bptr2 + (long)kt * 32 * ldb;
      rc_[0] = *reinterpret_cast<const float4*>(cc);
      rc_[1] = *reinterpret_cast<const float4*>(cc + ldb);
      rc_[2] = *reinterpret_cast<const float4*>(cc + 2 * ldb);
      rc_[3] = *reinterpret_cast<const float4*>(cc + 3 * ldb);
    }
  };

  auto store_tile = [&](const float4* ra_, const float4* rb_, const float4* rc_) {
#pragma unroll
    for (int j = 0; j < 4; j++)
      *reinterpret_cast<uint2*>(Ab + wa[j]) =
          make_uint2(pk2(ra_[j].x, ra_[j].y), pk2(ra_[j].z, ra_[j].w));
    *reinterpret_cast<uint2*>(Bb + wb[0]) = make_uint2(pk2(rb_[0].x, rb_[1].x), pk2(rb_[2].x, rb_[3].x));
    *reinterpret_cast<uint2*>(Bb + wb[1]) = make_uint2(pk2(rb_[0].y, rb_[1].y), pk2(rb_[2].y, rb_[3].y));
    *reinterpret_cast<uint2*>(Bb + wb[2]) = make_uint2(pk2(rb_[0].z, rb_[1].z), pk2(rb_[2].z, rb_[3].z));
    *reinterpret_cast<uint2*>(Bb + wb[3]) = make_uint2(pk2(rb_[0].w, rb_[1].w), pk2(rb_[2].w, rb_[3].w));
    if (FUSED) {
      *reinterpret_cast<uint2*>(Bb2 + wb[0]) = make_uint2(pk2(rc_[0].x, rc_[1].x), pk2(rc_[2].x, rc_[3].x));
      *reinterpret_cast<uint2*>(Bb2 + wb[1]) = make_uint2(pk2(rc_[0].y, rc_[1].y), pk2(rc_[2].y, rc_[3].y));
      *reinterpret_cast<uint2*>(Bb2 + wb[2]) = make_uint2(pk2(rc_[0].z, rc_[1].z), pk2(rc_[2].z, rc_[3].z));
      *reinterpret_cast<uint2*>(Bb2 + wb[3]) = make_uint2(pk2(rc_[0].w, rc_[1].w), pk2(rc_[2].w, rc_[3].w));
    }
  };

  auto mfma_step = [&]() {
    bf16x8 av[4], bvg[4], bvu[4];
#pragma unroll
    for (int m = 0; m < 4; m++) av[m] = *reinterpret_cast<const bf16x8*>(Ab + ra[m]);
#pragma unroll
    for (int n = 0; n < 4; n++) {
      bvg[n] = *reinterpret_cast<const bf16x8*>(Bb + rb[n]);
      if (FUSED) bvu[n] = *reinterpret_cast<const bf16x8*>(Bb2 + rb[n]);
    }
#pragma unroll
    for (int m = 0; m < 4; m++)
#pragma unroll
      for (int n = 0; n < 4; n++) {
        acc[m][n] = __builtin_amdgcn_mfma_f32_16x16x32_bf16(av[m], bvg[n], acc[m][n], 0, 0, 0);
        if (FUSED)
          acc2[m][n] = __builtin_amdgcn_mfma_f32_16x16x32_bf16(av[m], bvu[n], acc2[m][n], 0, 0, 0);
      }
  };

  load_tile(ta0, tb0, tc0, 0);
#pragma unroll 1
  for (int kt = 0; kt < KT; kt += 2) {
    load_tile(ta1, tb1, tc1, kt + 1);
    store_tile(ta0, tb0, tc0);
    block_sync_fb();
    mfma_step();
    block_sync_fb();
    int k2 = (kt + 2 < KT) ? kt + 2 : 0;
    load_tile(ta0, tb0, tc0, k2);
    store_tile(ta1, tb1, tc1);
    block_sync_fb();
    mfma_step();
    block_sync_fb();
  }

#pragma unroll
  for (int m = 0; m < 4; m++) {
#pragma unroll
    for (int n = 0; n < 4; n++) {
      int col = colblk + wn * 64 + n * 16 + l15;
      f32x4 a = acc[m][n];
      f32x4 a2 = acc2[m][n];
#pragma unroll
      for (int q = 0; q < 4; q++) {
        int rl = wm * 64 + m * 16 + (g << 2) + q;
        int grow = rt * 128 + rl;
        float v = a[q];
        if (EPI == EPI_GU) {
          if (!EXPERT || grow < M) {
            float hv = (v / (1.f + __expf(-v))) * a2[q];
            O[(long)(obase + grow) * ldo + col] = hv;
          }
        } else if (EPI == EPI_DOWN) {
          if (grow < M)
            atomicAdd(&O[(long)s_tok[rl] * ldo + col], s_w[rl] * v);
        } else {
          atomicAdd(&O[(long)grow * ldo + col], sig[grow] * v);
        }
      }
    }
  }
}

// ---------------------------------------------------------------------------
extern "C" void kernel_launch(void* const* d_in, const int* in_sizes, int n_in,
                              void* d_out, int out_size, void* d_ws, size_t ws_size,
                              hipStream_t stream)
{
  (void)in_sizes; (void)n_in; (void)out_size;
  const float* x   = (const float*)d_in[0];
  const float* gw  = (const float*)d_in[1];
  const float* Wg  = (const float*)d_in[2];
  const float* Wu  = (const float*)d_in[3];
  const float* Wd  = (const float*)d_in[4];
  const float* Wsg = (const float*)d_in[5];
  const float* Wsu = (const float*)d_in[6];
  const float* Wsd = (const float*)d_in[7];
  const float* sgw = (const float*)d_in[8];

  float* out    = (float*)d_out;
  float* logits = out + (long)TKN * DMODEL;

  char* w    = (char*)d_ws;
  int*  cnt  = (int*)w;
  int*  offs = (int*)(w + 64);
  float* sig = (float*)(w + 1024);
  int*  tokl = (int*)(w + 16384);
  float* wls = (float*)(w + 81920);

  hipMemsetAsync(out, 0, (size_t)TKN * DMODEL * 4, stream);
  hipMemsetAsync(cnt, 0, 64, stream);

  router_k<<<dim3(TKN / 4), 256, 0, stream>>>(x, gw, sgw, logits, sig, cnt, tokl, wls);
  scan_k<<<1, 64, 0, stream>>>(cnt, offs);

  const size_t NEED = 241172480ull;   // 230 MB (proven to fit in R2-R4)
  if (ws_size >= NEED) {
    char* xbf     = w + 262144;            // 8 MB frag-packed x rows (stride 4096 B)
    char* h       = w + 8650752;           // 23 MB bf16 (ex ldK=44 / sh ldK=176, reused)
    char* panGUex = w + 33554432;          // 8 x 11534336 = 92.3 MB (g/u interleaved)
    char* panWd   = w + 125829120;         // 8 x 5767168 = 46.1 MB
    char* panGUsh = w + 171966464;         // 46.1 MB (g/u interleaved)
    char* panWsd  = w + 218103808;         // 23.1 MB -> ends 241172480
    const long sPanGU = 11534336;
    const long sPanWd = 5767168;

    cvt_x_k<<<dim3(2048), 256, 0, stream>>>(x, xbf);
    // expert gate+up interleaved panel: 22 phys col-tiles x 64 kt x 8 experts
    cvt_gu_k<<<dim3(22, 64, 8), 256, 0, stream>>>(Wg, Wu, (long)DMODEL * FEXP, FEXP, panGUex, sPanGU);
    cvt_w_k<<<dim3(16, 44, 8), 256, 0, stream>>>(Wd, (long)FEXP * DMODEL, DMODEL, panWd, sPanWd);
    cvt_gu_k<<<dim3(88, 64, 1), 256, 0, stream>>>(Wsg, Wsu, 0, FSH, panGUsh, 0);
    cvt_w_k<<<dim3(16, 176, 1), 256, 0, stream>>>(Wsd, 0, DMODEL, panWsd, 0);

    // expert fused gate+up -> h (bf16, ldK=44). e=wg&7, rt=(wg>>3)&15, ct=wg>>7 (<22)
    gemm2_k<EPI_GU, true, 1><<<dim3(8 * 16 * 22), 256, 0, stream>>>(
        xbf, 4096, panGUex, sPanGU, 64, 22, h, 44, cnt, offs, tokl, wls, nullptr);
    // expert down -> out (atomic fp32)
    gemm2_k<EPI_DOWN, true, 1><<<dim3(8 * 16 * 16), 256, 0, stream>>>(
        h, 2816, panWd, sPanWd, 44, 16, out, 0, cnt, offs, tokl, wls, nullptr);
    // shared fused gate+up -> h (bf16, ldK=176), rt-fastest
    gemm2_k<EPI_GU, false, 1><<<dim3(16 * 88), 256, 0, stream>>>(
        xbf, 4096, panGUsh, 0, 64, 88, h, 176, nullptr, nullptr, nullptr, nullptr, nullptr);
    // shared down, split-K=4 -> out (atomic fp32)
    gemm2_k<EPI_SDOWN, false, 4><<<dim3(16 * 16 * 4), 256, 0, stream>>>(
        h, 11264, panWsd, 0, 176, 16, out, 0, nullptr, nullptr, nullptr, nullptr, sig);
  } else {
    // fallback: R1 path (fp32 reg-staged GEMMs)
    float* h = (float*)(w + (1 << 20));
    gemm_fb_k<EPI_GU, true, 1><<<dim3(FEXP / 128, 128), 256, 0, stream>>>(
        x, DMODEL, Wg, Wu, (long)DMODEL * FEXP, FEXP, DMODEL, h, FEXP, cnt, offs, tokl, wls, nullptr);
    gemm_fb_k<EPI_DOWN, true, 1><<<dim3(DMODEL / 128, 128), 256, 0, stream>>>(
        h, FEXP, Wd, nullptr, (long)FEXP * DMODEL, DMODEL, FEXP, out, DMODEL, cnt, offs, tokl, wls, nullptr);
    gemm_fb_k<EPI_GU, false, 1><<<dim3(FSH / 128, TKN / 128), 256, 0, stream>>>(
        x, DMODEL, Wsg, Wsu, 0, FSH, DMODEL, h, FSH, nullptr, nullptr, nullptr, nullptr, nullptr);
    gemm_fb_k<EPI_SDOWN, false, 4><<<dim3(DMODEL / 128, (TKN / 128) * 4), 256, 0, stream>>>(
        h, FSH, Wsd, nullptr, 0, DMODEL, FSH, out, DMODEL, nullptr, nullptr, nullptr, nullptr, sig);
  }
}

// Round 8
// 676.622 us; speedup vs baseline: 1.8469x; 1.0031x over previous
//
#include <hip/hip_runtime.h>
#include <hip/hip_bf16.h>

typedef __attribute__((ext_vector_type(8))) __bf16 bf16x8;
typedef __attribute__((ext_vector_type(4))) float f32x4;

#define TKN 2048
#define DMODEL 2048
#define NEXP 8
#define FEXP 1408
#define FSH 5632

__device__ __forceinline__ unsigned short f2bf(float f) {
  unsigned u = __float_as_uint(f);
  u += 0x7FFFu + ((u >> 16) & 1u);          // round-to-nearest-even
  return (unsigned short)(u >> 16);
}
__device__ __forceinline__ unsigned pk2(float a, float b) {
  return (unsigned)f2bf(a) | ((unsigned)f2bf(b) << 16);
}

// global -> LDS direct copy, 16B per lane. LDS dest must be wave-uniform.
__device__ __forceinline__ void gll16(const void* g, void* l) {
  __builtin_amdgcn_global_load_lds(
      (const __attribute__((address_space(1))) unsigned*)g,
      (__attribute__((address_space(3))) unsigned*)l, 16, 0, 0);
}

enum { EPI_GU = 0, EPI_DOWN = 1, EPI_SDOWN = 2 };

// ---------------------------------------------------------------------------
// Router (fp32-exact logits path) + top-4 + per-expert token lists.
// ---------------------------------------------------------------------------
__global__ __launch_bounds__(256)
void router_k(const float* __restrict__ x, const float* __restrict__ gw,
              const float* __restrict__ sgw, float* __restrict__ logits,
              float* __restrict__ sig, int* __restrict__ cnt,
              int* __restrict__ tokl, float* __restrict__ wls)
{
  const int wv = threadIdx.x >> 6, lane = threadIdx.x & 63;
  const int t = blockIdx.x * 4 + wv;
  const float* xr = x + (long)t * DMODEL;
  float xv[32];
#pragma unroll
  for (int j = 0; j < 32; j++) xv[j] = xr[lane + (j << 6)];

  float lg[8];
#pragma unroll
  for (int e = 0; e < 8; e++) {
    const float* gr = gw + (long)e * DMODEL;
    float acc = 0.f;
#pragma unroll
    for (int j = 0; j < 32; j++) acc += xv[j] * gr[lane + (j << 6)];
#pragma unroll
    for (int s = 1; s < 64; s <<= 1) acc += __shfl_xor(acc, s, 64);
    lg[e] = acc;
  }
  float sgacc = 0.f;
#pragma unroll
  for (int j = 0; j < 32; j++) sgacc += xv[j] * sgw[lane + (j << 6)];
#pragma unroll
  for (int s = 1; s < 64; s <<= 1) sgacc += __shfl_xor(sgacc, s, 64);

  if (lane == 0) {
    float mx = lg[0];
#pragma unroll
    for (int e = 1; e < 8; e++) mx = fmaxf(mx, lg[e]);
    float p[8], se = 0.f;
#pragma unroll
    for (int e = 0; e < 8; e++) { p[e] = expf(lg[e] - mx); se += p[e]; }
    float inv = 1.f / se;
#pragma unroll
    for (int e = 0; e < 8; e++) { p[e] *= inv; logits[t * 8 + e] = lg[e]; }
    sig[t] = 1.f / (1.f + expf(-sgacc));
#pragma unroll
    for (int k = 0; k < 4; k++) {
      int bi = 0; float bv = p[0];
#pragma unroll
      for (int e = 1; e < 8; e++) if (p[e] > bv) { bv = p[e]; bi = e; }
      p[bi] = -1.f;
      int pos = atomicAdd(&cnt[bi], 1);
      tokl[bi * TKN + pos] = t;
      wls[bi * TKN + pos] = bv;
    }
  }
}

__global__ void scan_k(const int* __restrict__ cnt, int* __restrict__ offs) {
  if (threadIdx.x == 0) {
    int s = 0;
    for (int e = 0; e < 8; e++) { offs[e] = s; s += cnt[e]; }
    offs[8] = s;
  }
}

// ---------------------------------------------------------------------------
// x fp32 [2048][2048] -> fragment-packed bf16 rows: per row, unit u=kt*4+j
// (16B) holds k = {kt*32+j*4+0..3, kt*32+16+j*4+0..3}. Row stride 4096 B.
// ---------------------------------------------------------------------------
__global__ __launch_bounds__(256)
void cvt_x_k(const float* __restrict__ x, char* __restrict__ xbf)
{
  long id = (long)blockIdx.x * 256 + threadIdx.x;   // 524288 total
  int row = id >> 8, u = id & 255, kt = u >> 2, j = u & 3;
  const float* p = x + (long)row * 2048 + kt * 32 + j * 4;
  float4 a = *(const float4*)p;
  float4 b = *(const float4*)(p + 16);
  uint4 o;
  o.x = pk2(a.x, a.y); o.y = pk2(a.z, a.w);
  o.z = pk2(b.x, b.y); o.w = pk2(b.z, b.w);
  *(uint4*)(xbf + id * 16) = o;
}

// ---------------------------------------------------------------------------
// Plain weight fp32 [K][N] -> bf16 panel of 8KB tiles, tile (ct,kt) at
// ((ct*KT)+kt)*8192. Position u = c*4+up holds frag unit g = up^((c>>1)&3)
// (T2 swizzle pre-baked). Frag unit g of col c = B[kt*32+g*4+{0..3}][c] then
// B[kt*32+16+g*4+{0..3}][c].
// ---------------------------------------------------------------------------
__global__ __launch_bounds__(256)
void cvt_w_k(const float* __restrict__ W, long sB, int N,
             char* __restrict__ panel, long panStride)
{
  const int ct = blockIdx.x, kt = blockIdx.y, e = blockIdx.z, KT = gridDim.y;
  const float* Wp = W + (long)e * sB + (long)(kt * 32) * N + ct * 128;
  __shared__ float t[32][128];
  const int r = threadIdx.x >> 3, q = threadIdx.x & 7;
  const float* rp = Wp + (long)r * N + q * 16;
  float4 f0 = *(const float4*)(rp + 0);
  float4 f1 = *(const float4*)(rp + 4);
  float4 f2 = *(const float4*)(rp + 8);
  float4 f3 = *(const float4*)(rp + 12);
  *(float4*)&t[r][q * 16 + 0]  = f0;
  *(float4*)&t[r][q * 16 + 4]  = f1;
  *(float4*)&t[r][q * 16 + 8]  = f2;
  *(float4*)&t[r][q * 16 + 12] = f3;
  __syncthreads();
  char* outp = panel + e * panStride + ((long)ct * KT + kt) * 8192;
#pragma unroll
  for (int uu = 0; uu < 2; uu++) {
    int u = threadIdx.x + uu * 256;
    int c = u >> 2;
    int g = (u & 3) ^ ((c >> 1) & 3);
    uint4 o;
    o.x = pk2(t[g * 4 + 0][c], t[g * 4 + 1][c]);
    o.y = pk2(t[g * 4 + 2][c], t[g * 4 + 3][c]);
    o.z = pk2(t[16 + g * 4 + 0][c], t[16 + g * 4 + 1][c]);
    o.w = pk2(t[16 + g * 4 + 2][c], t[16 + g * 4 + 3][c]);
    *(uint4*)(outp + u * 16) = o;
  }
}

// ---------------------------------------------------------------------------
// GU combined panel: interleaves Wg/Wu columns at 32-col granularity.
// Physical 128-col tile ct covers LOGICAL cols [ct*64, ct*64+64):
//   phys p: matrix = (p>>5)&1 (0=gate,1=up), logical col = ct*64+((p>>6)<<5)+(p&31).
// Same 8KB-tile packing + T2 swizzle as cvt_w_k.
// ---------------------------------------------------------------------------
__global__ __launch_bounds__(256)
void cvt_gu_k(const float* __restrict__ Wg, const float* __restrict__ Wu,
              long sB, int N, char* __restrict__ panel, long panStride)
{
  const int ct = blockIdx.x, kt = blockIdx.y, e = blockIdx.z, KT = gridDim.y;
  __shared__ float t[32][128];
  const int r = threadIdx.x >> 3, q = threadIdx.x & 7;
  const float* src = ((q >> 1) & 1) ? Wu : Wg;
  const int scol = ct * 64 + ((q >> 2) << 5) + ((q & 1) << 4);
  const float* rp = src + (long)e * sB + (long)(kt * 32 + r) * N + scol;
  float4 f0 = *(const float4*)(rp + 0);
  float4 f1 = *(const float4*)(rp + 4);
  float4 f2 = *(const float4*)(rp + 8);
  float4 f3 = *(const float4*)(rp + 12);
  *(float4*)&t[r][q * 16 + 0]  = f0;
  *(float4*)&t[r][q * 16 + 4]  = f1;
  *(float4*)&t[r][q * 16 + 8]  = f2;
  *(float4*)&t[r][q * 16 + 12] = f3;
  __syncthreads();
  char* outp = panel + e * panStride + ((long)ct * KT + kt) * 8192;
#pragma unroll
  for (int uu = 0; uu < 2; uu++) {
    int u = threadIdx.x + uu * 256;
    int c = u >> 2;
    int g = (u & 3) ^ ((c >> 1) & 3);
    uint4 o;
    o.x = pk2(t[g * 4 + 0][c], t[g * 4 + 1][c]);
    o.y = pk2(t[g * 4 + 2][c], t[g * 4 + 3][c]);
    o.z = pk2(t[16 + g * 4 + 0][c], t[16 + g * 4 + 1][c]);
    o.w = pk2(t[16 + g * 4 + 2][c], t[16 + g * 4 + 3][c]);
    *(uint4*)(outp + u * 16) = o;
  }
}

// ---------------------------------------------------------------------------
// bf16 MFMA GEMM, 128x128 tile, BK=32, 4 waves, depth-2 pipeline (3 LDS
// buffers, counted vmcnt(4)), XCD-pinned decode, T2 unit-XOR swizzle.
// EPI_GU consumes the interleaved g/u panel: acc[m][n] (n<2) = gate,
// acc[m][n+2] = up for the SAME logical cols -> h = silu(g)*u.
// ---------------------------------------------------------------------------
template<int EPI, bool EXPERT, int KSPLIT>
__global__ __launch_bounds__(256, 2)
void gemm2_k(const char* __restrict__ Abf, long strA,
             const char* __restrict__ Bp, long sBpan, int KTtot, int NCT,
             void* __restrict__ O, int ldKo,
             const int* __restrict__ cnt, const int* __restrict__ offs,
             const int* __restrict__ tokl, const float* __restrict__ wls,
             const float* __restrict__ sig)
{
  const int tid = threadIdx.x, lane = tid & 63, w = tid >> 6;
  const int wg = blockIdx.x;

  int e = 0, rt, ct, kc = 0, M = TKN;
  if (EXPERT) {
    e = wg & 7; int q = wg >> 3; rt = q & 15; ct = q >> 4;
    M = cnt[e];
    if (rt * 128 >= M) return;
  } else {
    rt = wg & 15; int q = wg >> 4; ct = q % NCT; kc = q / NCT;
  }
  const int KT = KTtot / KSPLIT;
  const int kt0 = kc * KT;
  const int obase = EXPERT ? offs[e] : 0;

  __shared__ int s_tok[128];
  __shared__ float s_w[128];
  __shared__ alignas(16) char Ab[3][8192];
  __shared__ alignas(16) char Bb[3][8192];

  if (EXPERT) {
    if (tid < 128) {
      int r = rt * 128 + tid;
      int rc = (r < M) ? r : (M - 1);
      s_tok[tid] = tokl[e * TKN + rc];
      if (EPI == EPI_DOWN) s_w[tid] = (r < M) ? wls[e * TKN + r] : 0.f;
    }
    __syncthreads();
  }

  // ---- staging addresses. A: wave w, issue i covers rows w*32+i*16+(lane>>2)
  // T2: lane (local row lr, unit u) fetches global frag unit u ^ ((lr>>1)&3).
  const int lrow0 = w * 32 + (lane >> 2);
  const int lrow1 = lrow0 + 16;
  auto rowbyte = [&](int rl) -> long {
    long gr;
    if (EPI == EPI_DOWN) { int r = rt * 128 + rl; gr = obase + ((r < M) ? r : (M - 1)); }
    else if (EXPERT)     { gr = s_tok[rl]; }
    else                 { gr = rt * 128 + rl; }
    return gr * strA;
  };
  const int au0 = (lane & 3) ^ ((lrow0 >> 1) & 3);
  const int au1 = (lane & 3) ^ ((lrow1 >> 1) & 3);
  const char* gA0 = Abf + rowbyte(lrow0) + (long)kt0 * 64 + au0 * 16;
  const char* gA1 = Abf + rowbyte(lrow1) + (long)kt0 * 64 + au1 * 16;
  const long bbase = (EXPERT ? (long)e * sBpan : 0) + ((long)ct * KTtot + kt0) * 8192
                     + w * 2048 + (long)lane * 16;
  const char* gB = Bp + bbase;

  auto stage = [&](int bf, int kt) {
    long ao = (long)kt * 64, bo = (long)kt * 8192;
    gll16(gA0 + ao, &Ab[bf][w * 2048]);
    gll16(gA1 + ao, &Ab[bf][w * 2048 + 1024]);
    gll16(gB + bo, &Bb[bf][w * 2048]);
    gll16(gB + bo + 1024, &Bb[bf][w * 2048 + 1024]);
  };

  // ---- fragment read offsets (T2: unit = g ^ ((row>>1)&3))
  const int wm = w >> 1, wn = w & 1, g = lane >> 4, l15 = lane & 15;
  int raOff[4], rbOff[4];
#pragma unroll
  for (int m = 0; m < 4; m++) {
    int row = wm * 64 + m * 16 + l15;
    raOff[m] = row * 64 + ((g ^ ((row >> 1) & 3)) << 4);
  }
#pragma unroll
  for (int n = 0; n < 4; n++) {
    int col = wn * 64 + n * 16 + l15;
    rbOff[n] = col * 64 + ((g ^ ((col >> 1) & 3)) << 4);
  }

  f32x4 acc[4][4] = {};

  // ---- depth-2 pipeline prologue: tiles 0 and 1 in flight
  stage(0, 0);
  stage(1, 1);

  int rd = 0;
#pragma unroll 1
  for (int kt = 0; kt < KT; ++kt) {
    // wait for tile kt only (tile kt+1's 4 loads stay in flight), T4-counted
    if (kt + 1 < KT) asm volatile("s_waitcnt vmcnt(4)" ::: "memory");
    else             asm volatile("s_waitcnt vmcnt(0)" ::: "memory");
    __builtin_amdgcn_s_barrier();
    __builtin_amdgcn_sched_barrier(0);

    bf16x8 av[4], bv[4];
#pragma unroll
    for (int m = 0; m < 4; m++) av[m] = *(const bf16x8*)&Ab[rd][raOff[m]];
#pragma unroll
    for (int n = 0; n < 4; n++) bv[n] = *(const bf16x8*)&Bb[rd][rbOff[n]];

    // stage tile kt+2 into the buffer read in iteration kt-1: (rd+2)%3
    int wr = rd + 2; if (wr >= 3) wr -= 3;
    if (kt + 2 < KT) stage(wr, kt + 2);

    __builtin_amdgcn_s_setprio(1);
#pragma unroll
    for (int m = 0; m < 4; m++)
#pragma unroll
      for (int n = 0; n < 4; n++)
        acc[m][n] = __builtin_amdgcn_mfma_f32_16x16x32_bf16(av[m], bv[n], acc[m][n], 0, 0, 0);
    __builtin_amdgcn_s_setprio(0);
    __builtin_amdgcn_sched_barrier(0);
    rd = (rd == 2) ? 0 : rd + 1;
  }

  // ---- epilogue. C/D frag: col = lane&15, row = (lane>>4)*4 + reg  [m89]
  if constexpr (EPI == EPI_GU) {
#pragma unroll
    for (int m = 0; m < 4; m++) {
#pragma unroll
      for (int n = 0; n < 2; n++) {
        int lc = ct * 64 + wn * 32 + n * 16 + l15;   // logical gu column
        f32x4 ga = acc[m][n];
        f32x4 ua = acc[m][n + 2];
#pragma unroll
        for (int q = 0; q < 4; q++) {
          int rl = wm * 64 + m * 16 + (g << 2) + q;
          int grow = rt * 128 + rl;
          if (!EXPERT || grow < M) {
            float gv = ga[q];
            float hv = (gv / (1.f + __expf(-gv))) * ua[q];
            long byteoff = (long)(obase + grow) * ((long)ldKo * 64)
                         + (lc >> 5) * 64 + ((lc >> 2) & 3) * 16
                         + ((lc & 16) >> 1) + (lc & 3) * 2;
            *(unsigned short*)((char*)O + byteoff) = f2bf(hv);
          }
        }
      }
    }
  } else {
#pragma unroll
    for (int m = 0; m < 4; m++) {
#pragma unroll
      for (int n = 0; n < 4; n++) {
        int col = ct * 128 + wn * 64 + n * 16 + l15;
        f32x4 a = acc[m][n];
#pragma unroll
        for (int q = 0; q < 4; q++) {
          int rl = wm * 64 + m * 16 + (g << 2) + q;
          int grow = rt * 128 + rl;
          float v = a[q];
          if constexpr (EPI == EPI_DOWN) {
            if (grow < M)
              atomicAdd((float*)O + (long)s_tok[rl] * DMODEL + col, s_w[rl] * v);
          } else {
            atomicAdd((float*)O + (long)grow * DMODEL + col, sig[grow] * v);
          }
        }
      }
    }
  }
}

// ---------------------------------------------------------------------------
// FALLBACK (ws too small): R1 reg-staged GEMM, fp32 sources.
// ---------------------------------------------------------------------------
__device__ __forceinline__ void block_sync_fb() {
  __builtin_amdgcn_sched_barrier(0);
  asm volatile("s_waitcnt lgkmcnt(0)" ::: "memory");
  __builtin_amdgcn_s_barrier();
  __builtin_amdgcn_sched_barrier(0);
}

template<int EPI, bool EXPERT, int KSPLIT>
__global__ __launch_bounds__(256, 2)
void gemm_fb_k(const float* __restrict__ A, int lda,
               const float* __restrict__ B, const float* __restrict__ B2,
               long sB, int ldb, int Ktot,
               float* __restrict__ O, int ldo,
               const int* __restrict__ cnt, const int* __restrict__ offs,
               const int* __restrict__ tokl, const float* __restrict__ wls,
               const float* __restrict__ sig)
{
  constexpr bool FUSED = (EPI == EPI_GU);
  const int tid = threadIdx.x;
  const int lane = tid & 63;

  int e = 0, rt, kc = 0, M = TKN;
  if (EXPERT) {
    e = blockIdx.y >> 4; rt = blockIdx.y & 15;
    M = cnt[e];
    if (rt * 128 >= M) return;
  } else {
    rt = blockIdx.y & 15; kc = blockIdx.y >> 4;
  }
  const int K = Ktot / KSPLIT;
  const int koff = kc * K;
  const int colblk = blockIdx.x * 128;
  const float* Bp  = B + (EXPERT ? (long)e * sB : 0);
  const float* Bp2 = FUSED ? (B2 + (EXPERT ? (long)e * sB : 0)) : nullptr;
  const int obase = EXPERT ? offs[e] : 0;

  __shared__ alignas(16) unsigned char Ab[8192];
  __shared__ alignas(16) unsigned char Bb[8192];
  __shared__ alignas(16) unsigned char Bb2[FUSED ? 8192 : 16];
  __shared__ int s_tok[128];
  __shared__ float s_w[128];

  if (EXPERT && tid < 128) {
    int r = rt * 128 + tid;
    int rc = (r < M) ? r : (M - 1);
    s_tok[tid] = tokl[e * TKN + rc];
    if (EPI == EPI_DOWN) s_w[tid] = (r < M) ? wls[e * TKN + r] : 0.f;
  }
  if (EXPERT) __syncthreads();

  const int arowl = tid >> 1;
  const int ahalf = tid & 1;
  long arow;
  if (EPI == EPI_DOWN) {
    int r = rt * 128 + arowl;
    arow = (long)obase + ((r < M) ? r : (M - 1));
  } else if (EXPERT) {
    arow = s_tok[arowl];
  } else {
    arow = rt * 128 + arowl;
  }
  const float* aptr = A + arow * (long)lda + koff + ahalf * 16;
  int wa[4];
#pragma unroll
  for (int j = 0; j < 4; j++)
    wa[j] = arowl * 64 + ((j ^ ((arowl ^ (arowl >> 3)) & 3)) << 4) + ahalf * 8;

  const int kg = tid >> 5, ng = tid & 31;
  const float* bptr  = Bp + (long)(koff + kg * 4) * ldb + colblk + ng * 4;
  const float* bptr2 = FUSED ? (Bp2 + (long)(koff + kg * 4) * ldb + colblk + ng * 4) : nullptr;
  int wb[4];
#pragma unroll
  for (int i = 0; i < 4; i++) {
    int c = ng * 4 + i;
    wb[i] = c * 64 + ((((kg & 3) ^ ((c ^ (c >> 3)) & 3))) << 4) + (kg >> 2) * 8;
  }

  const int wid = tid >> 6, wm = wid >> 1, wn = wid & 1;
  const int g = lane >> 4, l15 = lane & 15;
  int ra[4], rb[4];
#pragma unroll
  for (int m = 0; m < 4; m++) {
    int r = wm * 64 + m * 16 + l15;
    ra[m] = r * 64 + ((g ^ ((r ^ (r >> 3)) & 3)) << 4);
  }
#pragma unroll
  for (int n = 0; n < 4; n++) {
    int c = wn * 64 + n * 16 + l15;
    rb[n] = c * 64 + ((g ^ ((c ^ (c >> 3)) & 3)) << 4);
  }

  f32x4 acc[4][4] = {};
  f32x4 acc2[4][4] = {};

  const int KT = K >> 5;
  float4 ta0[4], tb0[4], tc0[4], ta1[4], tb1[4], tc1[4];

  auto load_tile = [&](float4* ra_, float4* rb_, float4* rc_, int kt) {
    const float4* a4 = reinterpret_cast<const float4*>(aptr + kt * 32);
    ra_[0] = a4[0]; ra_[1] = a4[1]; ra_[2] = a4[2]; ra_[3] = a4[3];
    const float* bb = bptr + (long)kt * 32 * ldb;
    rb_[0] = *reinterpret_cast<const float4*>(bb);
    rb_[1] = *reinterpret_cast<const float4*>(bb + ldb);
    rb_[2] = *reinterpret_cast<const float4*>(bb + 2 * ldb);
    rb_[3] = *reinterpret_cast<const float4*>(bb + 3 * ldb);
    if (FUSED) {
      const float* cc = bptr2 + (long)kt * 32 * ldb;
      rc_[0] = *reinterpret_cast<const float4*>(cc);
      rc_[1] = *reinterpret_cast<const float4*>(cc + ldb);
      rc_[2] = *reinterpret_cast<const float4*>(cc + 2 * ldb);
      rc_[3] = *reinterpret_cast<const float4*>(cc + 3 * ldb);
    }
  };

  auto store_tile = [&](const float4* ra_, const float4* rb_, const float4* rc_) {
#pragma unroll
    for (int j = 0; j < 4; j++)
      *reinterpret_cast<uint2*>(Ab + wa[j]) =
          make_uint2(pk2(ra_[j].x, ra_[j].y), pk2(ra_[j].z, ra_[j].w));
    *reinterpret_cast<uint2*>(Bb + wb[0]) = make_uint2(pk2(rb_[0].x, rb_[1].x), pk2(rb_[2].x, rb_[3].x));
    *reinterpret_cast<uint2*>(Bb + wb[1]) = make_uint2(pk2(rb_[0].y, rb_[1].y), pk2(rb_[2].y, rb_[3].y));
    *reinterpret_cast<uint2*>(Bb + wb[2]) = make_uint2(pk2(rb_[0].z, rb_[1].z), pk2(rb_[2].z, rb_[3].z));
    *reinterpret_cast<uint2*>(Bb + wb[3]) = make_uint2(pk2(rb_[0].w, rb_[1].w), pk2(rb_[2].w, rb_[3].w));
    if (FUSED) {
      *reinterpret_cast<uint2*>(Bb2 + wb[0]) = make_uint2(pk2(rc_[0].x, rc_[1].x), pk2(rc_[2].x, rc_[3].x));
      *reinterpret_cast<uint2*>(Bb2 + wb[1]) = make_uint2(pk2(rc_[0].y, rc_[1].y), pk2(rc_[2].y, rc_[3].y));
      *reinterpret_cast<uint2*>(Bb2 + wb[2]) = make_uint2(pk2(rc_[0].z, rc_[1].z), pk2(rc_[2].z, rc_[3].z));
      *reinterpret_cast<uint2*>(Bb2 + wb[3]) = make_uint2(pk2(rc_[0].w, rc_[1].w), pk2(rc_[2].w, rc_[3].w));
    }
  };

  auto mfma_step = [&]() {
    bf16x8 av[4], bvg[4], bvu[4];
#pragma unroll
    for (int m = 0; m < 4; m++) av[m] = *reinterpret_cast<const bf16x8*>(Ab + ra[m]);
#pragma unroll
    for (int n = 0; n < 4; n++) {
      bvg[n] = *reinterpret_cast<const bf16x8*>(Bb + rb[n]);
      if (FUSED) bvu[n] = *reinterpret_cast<const bf16x8*>(Bb2 + rb[n]);
    }
#pragma unroll
    for (int m = 0; m < 4; m++)
#pragma unroll
      for (int n = 0; n < 4; n++) {
        acc[m][n] = __builtin_amdgcn_mfma_f32_16x16x32_bf16(av[m], bvg[n], acc[m][n], 0, 0, 0);
        if (FUSED)
          acc2[m][n] = __builtin_amdgcn_mfma_f32_16x16x32_bf16(av[m], bvu[n], acc2[m][n], 0, 0, 0);
      }
  };

  load_tile(ta0, tb0, tc0, 0);
#pragma unroll 1
  for (int kt = 0; kt < KT; kt += 2) {
    load_tile(ta1, tb1, tc1, kt + 1);
    store_tile(ta0, tb0, tc0);
    block_sync_fb();
    mfma_step();
    block_sync_fb();
    int k2 = (kt + 2 < KT) ? kt + 2 : 0;
    load_tile(ta0, tb0, tc0, k2);
    store_tile(ta1, tb1, tc1);
    block_sync_fb();
    mfma_step();
    block_sync_fb();
  }

#pragma unroll
  for (int m = 0; m < 4; m++) {
#pragma unroll
    for (int n = 0; n < 4; n++) {
      int col = colblk + wn * 64 + n * 16 + l15;
      f32x4 a = acc[m][n];
      f32x4 a2 = acc2[m][n];
#pragma unroll
      for (int q = 0; q < 4; q++) {
        int rl = wm * 64 + m * 16 + (g << 2) + q;
        int grow = rt * 128 + rl;
        float v = a[q];
        if (EPI == EPI_GU) {
          if (!EXPERT || grow < M) {
            float hv = (v / (1.f + __expf(-v))) * a2[q];
            O[(long)(obase + grow) * ldo + col] = hv;
          }
        } else if (EPI == EPI_DOWN) {
          if (grow < M)
            atomicAdd(&O[(long)s_tok[rl] * ldo + col], s_w[rl] * v);
        } else {
          atomicAdd(&O[(long)grow * ldo + col], sig[grow] * v);
        }
      }
    }
  }
}

// ---------------------------------------------------------------------------
extern "C" void kernel_launch(void* const* d_in, const int* in_sizes, int n_in,
                              void* d_out, int out_size, void* d_ws, size_t ws_size,
                              hipStream_t stream)
{
  (void)in_sizes; (void)n_in; (void)out_size;
  const float* x   = (const float*)d_in[0];
  const float* gw  = (const float*)d_in[1];
  const float* Wg  = (const float*)d_in[2];
  const float* Wu  = (const float*)d_in[3];
  const float* Wd  = (const float*)d_in[4];
  const float* Wsg = (const float*)d_in[5];
  const float* Wsu = (const float*)d_in[6];
  const float* Wsd = (const float*)d_in[7];
  const float* sgw = (const float*)d_in[8];

  float* out    = (float*)d_out;
  float* logits = out + (long)TKN * DMODEL;

  char* w    = (char*)d_ws;
  int*  cnt  = (int*)w;
  int*  offs = (int*)(w + 64);
  float* sig = (float*)(w + 1024);
  int*  tokl = (int*)(w + 16384);
  float* wls = (float*)(w + 81920);

  hipMemsetAsync(out, 0, (size_t)TKN * DMODEL * 4, stream);
  hipMemsetAsync(cnt, 0, 64, stream);

  router_k<<<dim3(TKN / 4), 256, 0, stream>>>(x, gw, sgw, logits, sig, cnt, tokl, wls);
  scan_k<<<1, 64, 0, stream>>>(cnt, offs);

  const size_t NEED = 241172480ull;   // 230 MB (proven to fit in R2-R4)
  if (ws_size >= NEED) {
    char* xbf     = w + 262144;            // 8 MB frag-packed x rows (stride 4096 B)
    char* h       = w + 8650752;           // 23 MB bf16 (ex ldK=44 / sh ldK=176, reused)
    char* panGUex = w + 33554432;          // 8 x 11534336 = 92.3 MB (g/u interleaved)
    char* panWd   = w + 125829120;         // 8 x 5767168 = 46.1 MB
    char* panGUsh = w + 171966464;         // 46.1 MB (g/u interleaved)
    char* panWsd  = w + 218103808;         // 23.1 MB -> ends 241172480
    const long sPanGU = 11534336;
    const long sPanWd = 5767168;

    cvt_x_k<<<dim3(2048), 256, 0, stream>>>(x, xbf);
    // expert gate+up interleaved panel: 22 phys col-tiles x 64 kt x 8 experts
    cvt_gu_k<<<dim3(22, 64, 8), 256, 0, stream>>>(Wg, Wu, (long)DMODEL * FEXP, FEXP, panGUex, sPanGU);
    cvt_w_k<<<dim3(16, 44, 8), 256, 0, stream>>>(Wd, (long)FEXP * DMODEL, DMODEL, panWd, sPanWd);
    cvt_gu_k<<<dim3(88, 64, 1), 256, 0, stream>>>(Wsg, Wsu, 0, FSH, panGUsh, 0);
    cvt_w_k<<<dim3(16, 176, 1), 256, 0, stream>>>(Wsd, 0, DMODEL, panWsd, 0);

    // expert fused gate+up -> h (bf16, ldK=44). e=wg&7, rt=(wg>>3)&15, ct=wg>>7 (<22)
    gemm2_k<EPI_GU, true, 1><<<dim3(8 * 16 * 22), 256, 0, stream>>>(
        xbf, 4096, panGUex, sPanGU, 64, 22, h, 44, cnt, offs, tokl, wls, nullptr);
    // expert down -> out (atomic fp32)
    gemm2_k<EPI_DOWN, true, 1><<<dim3(8 * 16 * 16), 256, 0, stream>>>(
        h, 2816, panWd, sPanWd, 44, 16, out, 0, cnt, offs, tokl, wls, nullptr);
    // shared fused gate+up -> h (bf16, ldK=176), rt-fastest
    gemm2_k<EPI_GU, false, 1><<<dim3(16 * 88), 256, 0, stream>>>(
        xbf, 4096, panGUsh, 0, 64, 88, h, 176, nullptr, nullptr, nullptr, nullptr, nullptr);
    // shared down, split-K=4 -> out (atomic fp32)
    gemm2_k<EPI_SDOWN, false, 4><<<dim3(16 * 16 * 4), 256, 0, stream>>>(
        h, 11264, panWsd, 0, 176, 16, out, 0, nullptr, nullptr, nullptr, nullptr, sig);
  } else {
    // fallback: R1 path (fp32 reg-staged GEMMs)
    float* h = (float*)(w + (1 << 20));
    gemm_fb_k<EPI_GU, true, 1><<<dim3(FEXP / 128, 128), 256, 0, stream>>>(
        x, DMODEL, Wg, Wu, (long)DMODEL * FEXP, FEXP, DMODEL, h, FEXP, cnt, offs, tokl, wls, nullptr);
    gemm_fb_k<EPI_DOWN, true, 1><<<dim3(DMODEL / 128, 128), 256, 0, stream>>>(
        h, FEXP, Wd, nullptr, (long)FEXP * DMODEL, DMODEL, FEXP, out, DMODEL, cnt, offs, tokl, wls, nullptr);
    gemm_fb_k<EPI_GU, false, 1><<<dim3(FSH / 128, TKN / 128), 256, 0, stream>>>(
        x, DMODEL, Wsg, Wsu, 0, FSH, DMODEL, h, FSH, nullptr, nullptr, nullptr, nullptr, nullptr);
    gemm_fb_k<EPI_SDOWN, false, 4><<<dim3(DMODEL / 128, (TKN / 128) * 4), 256, 0, stream>>>(
        h, FSH, Wsd, nullptr, 0, DMODEL, FSH, out, DMODEL, nullptr, nullptr, nullptr, nullptr, sig);
  }
}